// Round 5
// baseline (1137.062 us; speedup 1.0000x reference)
//
#include <hip/hip_runtime.h>
#include <hip/hip_bf16.h>
#include <math.h>

constexpr int Dd  = 768;
constexpr int NH  = 12;
constexpr int DHd = 64;
constexpr int Bn  = 8;
constexpr int TVn = 512;
constexpr int TSn = 128;
constexpr int NST = 8;
constexpr int An  = 16;
constexpr int DPn = 3072;
constexpr int GSn = 2304;
constexpr int Mtot = 14464;   // 128 (s=0) + 8*7*16*16 candidate rows; 113*128
constexpr int NLT = 6;        // logit n-tiles at 128-wide tiling (768/128)

typedef unsigned short us;
using short8   = __attribute__((ext_vector_type(8))) short;
using floatx16 = __attribute__((ext_vector_type(16))) float;

__device__ inline us f2bf(float x) {
  union { float f; unsigned u; } a; a.f = x;
  return (us)((a.u + 0x7fffu + ((a.u >> 16) & 1u)) >> 16);
}
__device__ inline float bf2f(us h) {
  union { unsigned u; float f; } a; a.u = ((unsigned)h) << 16;
  return a.f;
}

// ---------------------------------------------------------------------------
// splits (float4-vectorized)
// ---------------------------------------------------------------------------
__global__ void split_k(const float* __restrict__ x, us* __restrict__ h,
                        us* __restrict__ l, int n4) {
  for (int i = blockIdx.x * 256 + threadIdx.x; i < n4; i += gridDim.x * 256) {
    float4 v = ((const float4*)x)[i];
    float vv[4] = {v.x, v.y, v.z, v.w};
    union { us u[4]; uint2 w; } hh, ll;
#pragma unroll
    for (int t = 0; t < 4; t++) {
      us hb = f2bf(vv[t]);
      hh.u[t] = hb;
      ll.u[t] = f2bf(vv[t] - bf2f(hb));
    }
    ((uint2*)h)[i] = hh.w;
    ((uint2*)l)[i] = ll.w;
  }
}

__global__ void split4_k(const float* s0, us* h0, us* l0, int n0,
                         const float* s1, us* h1, us* l1, int n1,
                         const float* s2, us* h2, us* l2, int n2,
                         const float* s3, us* h3, us* l3, int n3) {
  const float* s; us* h; us* l; int n;
  switch (blockIdx.y) {
    case 0: s = s0; h = h0; l = l0; n = n0; break;
    case 1: s = s1; h = h1; l = l1; n = n1; break;
    case 2: s = s2; h = h2; l = l2; n = n2; break;
    default: s = s3; h = h3; l = l3; n = n3; break;
  }
  int n4 = n >> 2;
  for (int i = blockIdx.x * 256 + threadIdx.x; i < n4; i += gridDim.x * 256) {
    float4 v = ((const float4*)s)[i];
    float vv[4] = {v.x, v.y, v.z, v.w};
    union { us u[4]; uint2 w; } hh, ll;
#pragma unroll
    for (int t = 0; t < 4; t++) {
      us hb = f2bf(vv[t]);
      hh.u[t] = hb;
      ll.u[t] = f2bf(vv[t] - bf2f(hb));
    }
    ((uint2*)h)[i] = hh.w;
    ((uint2*)l)[i] = ll.w;
  }
}

__device__ inline short8 lds8(const us* p) {
  const uint2* q = (const uint2*)p;
  uint2 a = q[0], b = q[1];
  union { unsigned u[4]; short8 v; } t;
  t.u[0] = a.x; t.u[1] = a.y; t.u[2] = b.x; t.u[3] = b.y;
  return t.v;
}

// ---------------------------------------------------------------------------
// bf16x3 MFMA NT GEMM — 64x64 tile, 4 waves, 3 acc chains, dbuf LDS,
// 1 barrier/iter, dist-1 prefetch. LDS tiles are [64][32] (pad-free) with a
// 16B-slot XOR swizzle (phys_slot = slot ^ (row&3)):
//  - write side: previously stride 18 dwords (even) + even col offsets put
//    ALL write dwords on even banks (2x serialization = the measured 9.4M
//    SQ_LDS_BANK_CONFLICT). Swizzle spreads rows across all 8 bank groups.
//  - read side: half-wave slot pairs map to disjoint group sets -> 8
//    dwords/bank (balanced). Bit-identical numerics.
// ---------------------------------------------------------------------------
__global__ __launch_bounds__(256) void mfma_nt(
    const us* __restrict__ Ah, const us* __restrict__ Al, int lda,
    const us* __restrict__ Bh, const us* __restrict__ Bl,
    const float* __restrict__ bias, const float* __restrict__ bias2, int nsplit,
    float* __restrict__ Cf, int ldc,
    us* __restrict__ Ch, us* __restrict__ Cl, int ldch,
    int K, int relu) {
  __shared__ us Ash[2][64][32], Asl[2][64][32], Bsh[2][64][32], Bsl[2][64][32];
  const int tid = threadIdx.x;
  const int bm = blockIdx.y * 64, bn = blockIdx.x * 64;
  const int wave = tid >> 6, lane = tid & 63;
  const int mh = (wave & 1) * 32, nh = (wave >> 1) * 32;
  const int l31 = lane & 31, hi5 = lane >> 5;
  const int srow = tid >> 2, slot = tid & 3, skc = slot * 8;
  const int sp = ((slot ^ (srow & 3)) << 3);          // swizzled store col
  const int rc = l31 & 3;                             // read-row swizzle key
  const us* pAh = Ah + (size_t)(bm + srow) * lda + skc;
  const us* pAl = Al + (size_t)(bm + srow) * lda + skc;
  const us* pBh = Bh + (size_t)(bn + srow) * K + skc;
  const us* pBl = Bl + (size_t)(bn + srow) * K + skc;

  floatx16 acc_hh, acc_hl, acc_lh;
#pragma unroll
  for (int i = 0; i < 16; i++) { acc_hh[i] = 0.f; acc_hl[i] = 0.f; acc_lh[i] = 0.f; }

  uint4 a_h = *(const uint4*)pAh;
  uint4 a_l = *(const uint4*)pAl;
  uint4 b_h = *(const uint4*)pBh;
  uint4 b_l = *(const uint4*)pBl;
  const int iters = K >> 5;
  int p = 0;
  for (int it = 0; it < iters; ++it) {
    *(uint2*)&Ash[p][srow][sp]     = make_uint2(a_h.x, a_h.y);
    *(uint2*)&Ash[p][srow][sp + 4] = make_uint2(a_h.z, a_h.w);
    *(uint2*)&Asl[p][srow][sp]     = make_uint2(a_l.x, a_l.y);
    *(uint2*)&Asl[p][srow][sp + 4] = make_uint2(a_l.z, a_l.w);
    *(uint2*)&Bsh[p][srow][sp]     = make_uint2(b_h.x, b_h.y);
    *(uint2*)&Bsh[p][srow][sp + 4] = make_uint2(b_h.z, b_h.w);
    *(uint2*)&Bsl[p][srow][sp]     = make_uint2(b_l.x, b_l.y);
    *(uint2*)&Bsl[p][srow][sp + 4] = make_uint2(b_l.z, b_l.w);
    __syncthreads();
    int knext = (it + 1 < iters) ? (it + 1) * 32 : 0;
    a_h = *(const uint4*)(pAh + knext);
    a_l = *(const uint4*)(pAl + knext);
    b_h = *(const uint4*)(pBh + knext);
    b_l = *(const uint4*)(pBl + knext);
#pragma unroll
    for (int ks = 0; ks < 32; ks += 16) {
      int col = ((((ks >> 3) + hi5) ^ rc) << 3);
      short8 fa_h = lds8(&Ash[p][mh + l31][col]);
      short8 fa_l = lds8(&Asl[p][mh + l31][col]);
      short8 fb_h = lds8(&Bsh[p][nh + l31][col]);
      short8 fb_l = lds8(&Bsl[p][nh + l31][col]);
      acc_hh = __builtin_amdgcn_mfma_f32_32x32x16_bf16(fa_h, fb_h, acc_hh, 0, 0, 0);
      acc_hl = __builtin_amdgcn_mfma_f32_32x32x16_bf16(fa_h, fb_l, acc_hl, 0, 0, 0);
      acc_lh = __builtin_amdgcn_mfma_f32_32x32x16_bf16(fa_l, fb_h, acc_lh, 0, 0, 0);
    }
    p ^= 1;
  }
  int n = bn + nh + l31;
  float bv = (n < nsplit) ? bias[n] : bias2[n - nsplit];
#pragma unroll
  for (int r = 0; r < 16; r++) {
    int m = bm + mh + (r & 3) + 8 * (r >> 2) + 4 * hi5;
    float v = acc_hh[r] + acc_hl[r] + acc_lh[r] + bv;
    if (relu) v = fmaxf(v, 0.f);
    if (Cf) Cf[(size_t)m * ldc + n] = v;
    if (Ch) {
      us hb = f2bf(v);
      Ch[(size_t)m * ldch + n] = hb;
      Cl[(size_t)m * ldch + n] = f2bf(v - bf2f(hb));
    }
  }
}

// ---------------------------------------------------------------------------
// Batched variant: up to 3 sub-GEMMs share one launch (y-tile ranges).
// Same swizzled-LDS body.
// ---------------------------------------------------------------------------
struct Sub {
  const us* Ah; const us* Al; const us* Bh; const us* Bl;
  const float* bias; float* Cf; us* Ch; us* Cl;
  int lda, ldc, ldch, Nt;
};

__global__ __launch_bounds__(256) void mfma_ntb(Sub s0, Sub s1, Sub s2,
                                                int c1, int c2, int K, int relu) {
  Sub s; int yt = blockIdx.y;
  if (yt < c1) { s = s0; }
  else if (yt < c2) { s = s1; yt -= c1; }
  else { s = s2; yt -= c2; }
  if ((int)blockIdx.x >= s.Nt) return;
  __shared__ us Ash[2][64][32], Asl[2][64][32], Bsh[2][64][32], Bsl[2][64][32];
  const int tid = threadIdx.x;
  const int bm = yt * 64, bn = blockIdx.x * 64;
  const int wave = tid >> 6, lane = tid & 63;
  const int mh = (wave & 1) * 32, nh = (wave >> 1) * 32;
  const int l31 = lane & 31, hi5 = lane >> 5;
  const int srow = tid >> 2, slot = tid & 3, skc = slot * 8;
  const int sp = ((slot ^ (srow & 3)) << 3);
  const int rc = l31 & 3;
  const us* pAh = s.Ah + (size_t)(bm + srow) * s.lda + skc;
  const us* pAl = s.Al + (size_t)(bm + srow) * s.lda + skc;
  const us* pBh = s.Bh + (size_t)(bn + srow) * K + skc;
  const us* pBl = s.Bl + (size_t)(bn + srow) * K + skc;

  floatx16 acc_hh, acc_hl, acc_lh;
#pragma unroll
  for (int i = 0; i < 16; i++) { acc_hh[i] = 0.f; acc_hl[i] = 0.f; acc_lh[i] = 0.f; }

  uint4 a_h = *(const uint4*)pAh;
  uint4 a_l = *(const uint4*)pAl;
  uint4 b_h = *(const uint4*)pBh;
  uint4 b_l = *(const uint4*)pBl;
  const int iters = K >> 5;
  int p = 0;
  for (int it = 0; it < iters; ++it) {
    *(uint2*)&Ash[p][srow][sp]     = make_uint2(a_h.x, a_h.y);
    *(uint2*)&Ash[p][srow][sp + 4] = make_uint2(a_h.z, a_h.w);
    *(uint2*)&Asl[p][srow][sp]     = make_uint2(a_l.x, a_l.y);
    *(uint2*)&Asl[p][srow][sp + 4] = make_uint2(a_l.z, a_l.w);
    *(uint2*)&Bsh[p][srow][sp]     = make_uint2(b_h.x, b_h.y);
    *(uint2*)&Bsh[p][srow][sp + 4] = make_uint2(b_h.z, b_h.w);
    *(uint2*)&Bsl[p][srow][sp]     = make_uint2(b_l.x, b_l.y);
    *(uint2*)&Bsl[p][srow][sp + 4] = make_uint2(b_l.z, b_l.w);
    __syncthreads();
    int knext = (it + 1 < iters) ? (it + 1) * 32 : 0;
    a_h = *(const uint4*)(pAh + knext);
    a_l = *(const uint4*)(pAl + knext);
    b_h = *(const uint4*)(pBh + knext);
    b_l = *(const uint4*)(pBl + knext);
#pragma unroll
    for (int ks = 0; ks < 32; ks += 16) {
      int col = ((((ks >> 3) + hi5) ^ rc) << 3);
      short8 fa_h = lds8(&Ash[p][mh + l31][col]);
      short8 fa_l = lds8(&Asl[p][mh + l31][col]);
      short8 fb_h = lds8(&Bsh[p][nh + l31][col]);
      short8 fb_l = lds8(&Bsl[p][nh + l31][col]);
      acc_hh = __builtin_amdgcn_mfma_f32_32x32x16_bf16(fa_h, fb_h, acc_hh, 0, 0, 0);
      acc_hl = __builtin_amdgcn_mfma_f32_32x32x16_bf16(fa_h, fb_l, acc_hl, 0, 0, 0);
      acc_lh = __builtin_amdgcn_mfma_f32_32x32x16_bf16(fa_l, fb_h, acc_lh, 0, 0, 0);
    }
    p ^= 1;
  }
  int n = bn + nh + l31;
  float bv = s.bias[n];
#pragma unroll
  for (int r = 0; r < 16; r++) {
    int m = bm + mh + (r & 3) + 8 * (r >> 2) + 4 * hi5;
    float v = acc_hh[r] + acc_hl[r] + acc_lh[r] + bv;
    if (relu) v = fmaxf(v, 0.f);
    if (s.Cf) s.Cf[(size_t)m * s.ldc + n] = v;
    if (s.Ch) {
      us hb = f2bf(v);
      s.Ch[(size_t)m * s.ldch + n] = hb;
      s.Cl[(size_t)m * s.ldch + n] = f2bf(v - bf2f(hb));
    }
  }
}

// ---------------------------------------------------------------------------
// logit GEMM, 128x128 tile (grid 6x113=678 blocks), swizzled LDS. Cross
// chains share one accumulator (R1-verified). Epilogue: relu(acc+b1[n])*w2[n],
// reduce over 128-col n-tile -> Lpart[ntile][m].
// ---------------------------------------------------------------------------
__global__ __launch_bounds__(256, 2) void mfma_logit128(
    const us* __restrict__ Ah, const us* __restrict__ Al,
    const us* __restrict__ Bh, const us* __restrict__ Bl,
    const float* __restrict__ bias1, const float* __restrict__ w2,
    float* __restrict__ Lpart) {
  __shared__ us Ash[2][128][32], Asl[2][128][32], Bsh[2][128][32], Bsl[2][128][32];
  __shared__ float lpart[128];
  const int K = Dd;
  const int tid = threadIdx.x;
  const int bm = blockIdx.y * 128, bn = blockIdx.x * 128;
  const int wave = tid >> 6, lane = tid & 63;
  const int mh = (wave & 1) * 64, nh = (wave >> 1) * 64;
  const int l31 = lane & 31, hi5 = lane >> 5;
  const int srow = tid >> 2, slot = tid & 3, skc = slot * 8;
  const int sp = ((slot ^ (srow & 3)) << 3);
  const int rc = l31 & 3;
  const us* pAh = Ah + (size_t)(bm + srow) * K + skc;
  const us* pAl = Al + (size_t)(bm + srow) * K + skc;
  const us* pBh = Bh + (size_t)(bn + srow) * K + skc;
  const us* pBl = Bl + (size_t)(bn + srow) * K + skc;
  const size_t strA = (size_t)64 * K, strB = (size_t)64 * K;
  if (tid < 128) lpart[tid] = 0.f;

  floatx16 acc_hh[2][2], acc_x[2][2];
#pragma unroll
  for (int i = 0; i < 2; i++)
#pragma unroll
    for (int j = 0; j < 2; j++)
#pragma unroll
      for (int r = 0; r < 16; r++) { acc_hh[i][j][r] = 0.f; acc_x[i][j][r] = 0.f; }

  uint4 ah0 = *(const uint4*)pAh,          ah1 = *(const uint4*)(pAh + strA);
  uint4 al0 = *(const uint4*)pAl,          al1 = *(const uint4*)(pAl + strA);
  uint4 bh0 = *(const uint4*)pBh,          bh1 = *(const uint4*)(pBh + strB);
  uint4 bl0 = *(const uint4*)pBl,          bl1 = *(const uint4*)(pBl + strB);
  const int iters = K >> 5;
  int p = 0;
  for (int it = 0; it < iters; ++it) {
    *(uint2*)&Ash[p][srow][sp]          = make_uint2(ah0.x, ah0.y);
    *(uint2*)&Ash[p][srow][sp + 4]      = make_uint2(ah0.z, ah0.w);
    *(uint2*)&Ash[p][srow + 64][sp]     = make_uint2(ah1.x, ah1.y);
    *(uint2*)&Ash[p][srow + 64][sp + 4] = make_uint2(ah1.z, ah1.w);
    *(uint2*)&Asl[p][srow][sp]          = make_uint2(al0.x, al0.y);
    *(uint2*)&Asl[p][srow][sp + 4]      = make_uint2(al0.z, al0.w);
    *(uint2*)&Asl[p][srow + 64][sp]     = make_uint2(al1.x, al1.y);
    *(uint2*)&Asl[p][srow + 64][sp + 4] = make_uint2(al1.z, al1.w);
    *(uint2*)&Bsh[p][srow][sp]          = make_uint2(bh0.x, bh0.y);
    *(uint2*)&Bsh[p][srow][sp + 4]      = make_uint2(bh0.z, bh0.w);
    *(uint2*)&Bsh[p][srow + 64][sp]     = make_uint2(bh1.x, bh1.y);
    *(uint2*)&Bsh[p][srow + 64][sp + 4] = make_uint2(bh1.z, bh1.w);
    *(uint2*)&Bsl[p][srow][sp]          = make_uint2(bl0.x, bl0.y);
    *(uint2*)&Bsl[p][srow][sp + 4]      = make_uint2(bl0.z, bl0.w);
    *(uint2*)&Bsl[p][srow + 64][sp]     = make_uint2(bl1.x, bl1.y);
    *(uint2*)&Bsl[p][srow + 64][sp + 4] = make_uint2(bl1.z, bl1.w);
    __syncthreads();
    int knext = (it + 1 < iters) ? (it + 1) * 32 : 0;
    ah0 = *(const uint4*)(pAh + knext);
    ah1 = *(const uint4*)(pAh + strA + knext);
    al0 = *(const uint4*)(pAl + knext);
    al1 = *(const uint4*)(pAl + strA + knext);
    bh0 = *(const uint4*)(pBh + knext);
    bh1 = *(const uint4*)(pBh + strB + knext);
    bl0 = *(const uint4*)(pBl + knext);
    bl1 = *(const uint4*)(pBl + strB + knext);
#pragma unroll
    for (int ks = 0; ks < 32; ks += 16) {
      int col = ((((ks >> 3) + hi5) ^ rc) << 3);
      short8 fah[2], fal[2], fbh[2], fbl[2];
#pragma unroll
      for (int f = 0; f < 2; f++) {
        fah[f] = lds8(&Ash[p][mh + f * 32 + l31][col]);
        fal[f] = lds8(&Asl[p][mh + f * 32 + l31][col]);
        fbh[f] = lds8(&Bsh[p][nh + f * 32 + l31][col]);
        fbl[f] = lds8(&Bsl[p][nh + f * 32 + l31][col]);
      }
#pragma unroll
      for (int fm = 0; fm < 2; fm++)
#pragma unroll
        for (int fn = 0; fn < 2; fn++) {
          acc_hh[fm][fn] = __builtin_amdgcn_mfma_f32_32x32x16_bf16(fah[fm], fbh[fn], acc_hh[fm][fn], 0, 0, 0);
          acc_x[fm][fn]  = __builtin_amdgcn_mfma_f32_32x32x16_bf16(fah[fm], fbl[fn], acc_x[fm][fn], 0, 0, 0);
          acc_x[fm][fn]  = __builtin_amdgcn_mfma_f32_32x32x16_bf16(fal[fm], fbh[fn], acc_x[fm][fn], 0, 0, 0);
        }
    }
    p ^= 1;
  }
  float b1[2], wn[2];
#pragma unroll
  for (int fn = 0; fn < 2; fn++) {
    int n = bn + nh + fn * 32 + l31;
    b1[fn] = bias1[n];
    wn[fn] = w2[n];
  }
#pragma unroll
  for (int fm = 0; fm < 2; fm++) {
#pragma unroll
    for (int r = 0; r < 16; r++) {
      int mloc = mh + fm * 32 + (r & 3) + 8 * (r >> 2) + 4 * hi5;
      float v = 0.f;
#pragma unroll
      for (int fn = 0; fn < 2; fn++) {
        float vv = acc_hh[fm][fn][r] + acc_x[fm][fn][r] + b1[fn];
        v += fmaxf(vv, 0.f) * wn[fn];
      }
      v += __shfl_xor(v, 1);
      v += __shfl_xor(v, 2);
      v += __shfl_xor(v, 4);
      v += __shfl_xor(v, 8);
      v += __shfl_xor(v, 16);
      if (l31 == 0) atomicAdd(&lpart[mloc], v);
    }
  }
  __syncthreads();
  if (tid < 128) Lpart[(size_t)blockIdx.x * Mtot + bm + tid] = lpart[tid];
}

// ---------------------------------------------------------------------------
// scalar f32 NT GEMM (tiny M: question, gh0)
// ---------------------------------------------------------------------------
__global__ __launch_bounds__(256) void gemm_s(const float* __restrict__ A,
                                              const float* __restrict__ Bw,
                                              const float* __restrict__ bias,
                                              float* __restrict__ C,
                                              int M, int N, int K,
                                              int lda, int ldc, int relu) {
  __shared__ float As[16][65];
  __shared__ float Bs[16][65];
  int bm = blockIdx.y * 64, bn = blockIdx.x * 64;
  int tid = threadIdx.x;
  int tx = tid & 15, ty = tid >> 4;
  float acc[4][4] = {};
  for (int k0 = 0; k0 < K; k0 += 16) {
#pragma unroll
    for (int i = 0; i < 4; i++) {
      int l = tid * 4 + i;
      int row = l >> 4, kk = l & 15;
      float v = 0.f;
      if (bm + row < M) v = A[(size_t)(bm + row) * lda + k0 + kk];
      As[kk][row] = v;
    }
#pragma unroll
    for (int i = 0; i < 4; i++) {
      int l = tid * 4 + i;
      int row = l >> 4, kk = l & 15;
      float v = 0.f;
      if (bn + row < N) v = Bw[(size_t)(bn + row) * K + k0 + kk];
      Bs[kk][row] = v;
    }
    __syncthreads();
#pragma unroll
    for (int kk = 0; kk < 16; kk++) {
      float a4[4], b4[4];
#pragma unroll
      for (int i = 0; i < 4; i++) a4[i] = As[kk][ty * 4 + i];
#pragma unroll
      for (int j = 0; j < 4; j++) b4[j] = Bs[kk][tx * 4 + j];
#pragma unroll
      for (int i = 0; i < 4; i++)
#pragma unroll
        for (int j = 0; j < 4; j++) acc[i][j] += a4[i] * b4[j];
    }
    __syncthreads();
  }
#pragma unroll
  for (int i = 0; i < 4; i++) {
    int m = bm + ty * 4 + i;
    if (m >= M) continue;
#pragma unroll
    for (int j = 0; j < 4; j++) {
      int n = bn + tx * 4 + j;
      if (n >= N) continue;
      float v = acc[i][j] + bias[n];
      if (relu) v = fmaxf(v, 0.f);
      C[(size_t)m * ldc + n] = v;
    }
  }
}

// ---------------------------------------------------------------------------
// attention (f32), float4-vectorized LDS
// ---------------------------------------------------------------------------
__global__ __launch_bounds__(256) void att_qk(const float* __restrict__ qp,
                                              const float* __restrict__ kp,
                                              float* __restrict__ Sout,
                                              int Tq, int Tk, int kdiv, int ldk,
                                              float scale) {
  int g = blockIdx.x;
  int h = g % NH;
  int qrow0 = (g / NH) * Tq;
  int krow0 = (g / (NH * kdiv)) * Tk;
  int q0 = blockIdx.y * 32;
  int k0 = blockIdx.z * 64;
  __shared__ float Qs[32][68];
  __shared__ float KsT[64][72];   // transposed: [d][k]
  int tid = threadIdx.x;
  {
    int row = tid >> 3, db = (tid & 7) * 8;
    int qr = q0 + row;
    float4 v0 = {0, 0, 0, 0}, v1 = {0, 0, 0, 0};
    if (qr < Tq) {
      const float* p = qp + (size_t)(qrow0 + qr) * Dd + h * DHd + db;
      v0 = *(const float4*)p;
      v1 = *(const float4*)(p + 4);
    }
    *(float4*)&Qs[row][db] = v0;
    *(float4*)&Qs[row][db + 4] = v1;
  }
#pragma unroll
  for (int half = 0; half < 2; half++) {
    int row = (tid >> 3) + half * 32, db = (tid & 7) * 8;
    int kr = k0 + row;
    float4 v0 = {0, 0, 0, 0}, v1 = {0, 0, 0, 0};
    if (kr < Tk) {
      const float* p = kp + (size_t)(krow0 + kr) * ldk + h * DHd + db;
      v0 = *(const float4*)p;
      v1 = *(const float4*)(p + 4);
    }
    KsT[db + 0][row] = v0.x; KsT[db + 1][row] = v0.y;
    KsT[db + 2][row] = v0.z; KsT[db + 3][row] = v0.w;
    KsT[db + 4][row] = v1.x; KsT[db + 5][row] = v1.y;
    KsT[db + 6][row] = v1.z; KsT[db + 7][row] = v1.w;
  }
  __syncthreads();
  int q = tid >> 3, kg = tid & 7;
  float acc[8] = {};
  for (int d = 0; d < DHd; d++) {
    float qv = Qs[q][d];
    float4 k0v = *(const float4*)&KsT[d][kg * 8];
    float4 k1v = *(const float4*)&KsT[d][kg * 8 + 4];
    acc[0] += qv * k0v.x; acc[1] += qv * k0v.y;
    acc[2] += qv * k0v.z; acc[3] += qv * k0v.w;
    acc[4] += qv * k1v.x; acc[5] += qv * k1v.y;
    acc[6] += qv * k1v.z; acc[7] += qv * k1v.w;
  }
  if (q0 + q < Tq) {
    size_t basep = ((size_t)g * Tq + q0 + q) * Tk + k0 + kg * 8;
#pragma unroll
    for (int j = 0; j < 8; j++) Sout[basep + j] = acc[j] * scale;
  }
}

// P@V with fused bf16-split output (Outh/Outl)
__global__ __launch_bounds__(256) void att_pv(const float* __restrict__ P,
                                              const float* __restrict__ vp,
                                              us* __restrict__ Outh,
                                              us* __restrict__ Outl,
                                              int Tq, int Tk, int kdiv, int ldv) {
  int g = blockIdx.x;
  int h = g % NH;
  int qrow0 = (g / NH) * Tq;
  int krow0 = (g / (NH * kdiv)) * Tk;
  int q0 = blockIdx.y * 32;
  __shared__ float Ps[32][68];
  __shared__ float Vs[64][72];
  int tid = threadIdx.x;
  int q = tid >> 3, dg = tid & 7;
  float acc[8] = {};
  for (int k0 = 0; k0 < Tk; k0 += 64) {
    {
      int row = tid >> 3, cb = (tid & 7) * 8;
      int qr = q0 + row;
      float4 v0 = {0, 0, 0, 0}, v1 = {0, 0, 0, 0};
      if (qr < Tq) {
        const float* p = P + ((size_t)g * Tq + qr) * Tk + k0 + cb;
        v0 = *(const float4*)p;
        v1 = *(const float4*)(p + 4);
      }
      *(float4*)&Ps[row][cb] = v0;
      *(float4*)&Ps[row][cb + 4] = v1;
    }
#pragma unroll
    for (int half = 0; half < 2; half++) {
      int row = (tid >> 3) + half * 32, db = (tid & 7) * 8;
      const float* p = vp + (size_t)(krow0 + k0 + row) * ldv + h * DHd + db;
      *(float4*)&Vs[row][db] = *(const float4*)p;
      *(float4*)&Vs[row][db + 4] = *(const float4*)(p + 4);
    }
    __syncthreads();
#pragma unroll 4
    for (int kk4 = 0; kk4 < 16; kk4++) {
      float4 pv = *(const float4*)&Ps[q][kk4 * 4];
      float pe[4] = {pv.x, pv.y, pv.z, pv.w};
#pragma unroll
      for (int e = 0; e < 4; e++) {
        int kk = kk4 * 4 + e;
        float4 v0 = *(const float4*)&Vs[kk][dg * 8];
        float4 v1 = *(const float4*)&Vs[kk][dg * 8 + 4];
        acc[0] += pe[e] * v0.x; acc[1] += pe[e] * v0.y;
        acc[2] += pe[e] * v0.z; acc[3] += pe[e] * v0.w;
        acc[4] += pe[e] * v1.x; acc[5] += pe[e] * v1.y;
        acc[6] += pe[e] * v1.z; acc[7] += pe[e] * v1.w;
      }
    }
    __syncthreads();
  }
  if (q0 + q < Tq) {
    size_t basep = (size_t)(qrow0 + q0 + q) * Dd + h * DHd + dg * 8;
    union { us u[8]; uint4 v; } ph, pl;
#pragma unroll
    for (int j = 0; j < 8; j++) {
      us hb = f2bf(acc[j]);
      ph.u[j] = hb;
      pl.u[j] = f2bf(acc[j] - bf2f(hb));
    }
    *(uint4*)&Outh[basep] = ph.v;
    *(uint4*)&Outl[basep] = pl.v;
  }
}

__global__ __launch_bounds__(256) void softmax_rows(float* __restrict__ X, int len) {
  int row = blockIdx.x;
  float* p = X + (size_t)row * len;
  int tid = threadIdx.x;
  __shared__ float red[4];
  __shared__ float red2[4];
  float lmax = -1e30f;
  for (int j = tid; j < len; j += 256) lmax = fmaxf(lmax, p[j]);
  for (int off = 32; off; off >>= 1) lmax = fmaxf(lmax, __shfl_down(lmax, off));
  if ((tid & 63) == 0) red[tid >> 6] = lmax;
  __syncthreads();
  if (tid == 0) red[0] = fmaxf(fmaxf(red[0], red[1]), fmaxf(red[2], red[3]));
  __syncthreads();
  float m = red[0];
  float lsum = 0.f;
  for (int j = tid; j < len; j += 256) {
    float e = expf(p[j] - m);
    p[j] = e;
    lsum += e;
  }
  for (int off = 32; off; off >>= 1) lsum += __shfl_down(lsum, off);
  if ((tid & 63) == 0) red2[tid >> 6] = lsum;
  __syncthreads();
  if (tid == 0) red2[0] = red2[0] + red2[1] + red2[2] + red2[3];
  __syncthreads();
  float inv = 1.f / red2[0];
  for (int j = tid; j < len; j += 256) p[j] *= inv;
}

// fused head-mean + qv = W @ vatt -> cat slice [0,D)
__global__ __launch_bounds__(256) void qv2_k(const float* __restrict__ S2,
                                             const float* __restrict__ vatt,
                                             us* __restrict__ ch, us* __restrict__ cl) {
  int row = blockIdx.x;
  int b = row / (NST * An);
  int bs = row / An;
  int a = row % An;
  __shared__ float wm[TSn];
  int tid = threadIdx.x;
  if (tid < TSn) {
    float acc = 0.f;
    for (int h = 0; h < NH; h++)
      acc += S2[(((size_t)bs * NH + h) * An + a) * TSn + tid];
    wm[tid] = acc * (1.f / NH);
  }
  __syncthreads();
  for (int j = tid; j < Dd; j += 256) {
    float acc = 0.f;
    for (int k = 0; k < TSn; k++)
      acc += wm[k] * vatt[((size_t)b * TSn + k) * Dd + j];
    size_t o = (size_t)row * DPn + j;
    us hb = f2bf(acc);
    ch[o] = hb;
    cl[o] = f2bf(acc - bf2f(hb));
  }
}

// cat slices [2D,3D) = qf[b] + at[row]  and  [3D,4D) = ab2 tmp bit-copy
__global__ void cat_fill(const float* __restrict__ qf, const float* __restrict__ at,
                         const us* __restrict__ ab2h, const us* __restrict__ ab2l,
                         us* __restrict__ ch, us* __restrict__ cl) {
  int idx = blockIdx.x * 256 + threadIdx.x;
  if (idx >= Bn * NST * An * Dd) return;
  int b = idx / (NST * An * Dd);
  int row = idx / Dd;
  int j = idx - row * Dd;
  float v = qf[b * Dd + j] + at[idx];
  size_t o = (size_t)row * DPn + 2 * Dd + j;
  us hb = f2bf(v);
  ch[o] = hb;
  cl[o] = f2bf(v - bf2f(hb));
  size_t o3 = (size_t)row * DPn + 3 * Dd + j;
  ch[o3] = ab2h[idx];
  cl[o3] = ab2l[idx];
}

// ---------------------------------------------------------------------------
// GRU combine for ALL candidate rows. gABall [1024 x 4608]: cols [0,2304) =
// x-gates (wih), cols [2304,4608) = h-gates (whh). Pre-split bf16 output.
// Row layout: [0,128): s=0 rows (b,a). [128,Mtot): 128+(((b*7+s-1)*16+a)*16+c).
// ---------------------------------------------------------------------------
__global__ void combine_all(const float* __restrict__ gABall,
                            const float* __restrict__ gh0,
                            const float* __restrict__ inps,
                            const float* __restrict__ state0,
                            us* __restrict__ Hh, us* __restrict__ Hl) {
  const int D4 = Dd / 4;
  const int LDG = 4608;
  int idx = blockIdx.x * 256 + threadIdx.x;
  if (idx >= Mtot * D4) return;
  int row = idx / D4, j = (idx - row * D4) * 4;
  const float* gp;
  const float* ghp;
  const float* stp;
  if (row < 128) {
    int b = row >> 4, a = row & 15;
    gp = gABall + ((size_t)(b * NST) * An + a) * LDG;
    ghp = gh0;
    stp = state0;
  } else {
    int r = row - 128;
    int c = r & 15; r >>= 4;
    int a = r & 15; r >>= 4;
    int sm1 = r % 7, b = r / 7;
    size_t prev = (size_t)(b * NST + sm1) * An + c;
    gp = gABall + ((size_t)(b * NST + sm1 + 1) * An + a) * LDG;
    ghp = gABall + prev * LDG + GSn;
    stp = inps + prev * Dd;
  }
  float4 ir4 = *(const float4*)(gp + j);
  float4 iz4 = *(const float4*)(gp + Dd + j);
  float4 in4 = *(const float4*)(gp + 2 * Dd + j);
  float4 hr4 = *(const float4*)(ghp + j);
  float4 hz4 = *(const float4*)(ghp + Dd + j);
  float4 hn4 = *(const float4*)(ghp + 2 * Dd + j);
  float4 st4 = *(const float4*)(stp + j);
  float ir[4] = {ir4.x, ir4.y, ir4.z, ir4.w};
  float iz[4] = {iz4.x, iz4.y, iz4.z, iz4.w};
  float in_[4] = {in4.x, in4.y, in4.z, in4.w};
  float hr[4] = {hr4.x, hr4.y, hr4.z, hr4.w};
  float hz[4] = {hz4.x, hz4.y, hz4.z, hz4.w};
  float hn[4] = {hn4.x, hn4.y, hn4.z, hn4.w};
  float st[4] = {st4.x, st4.y, st4.z, st4.w};
  union { us u[4]; uint2 w; } oh, ol;
#pragma unroll
  for (int t = 0; t < 4; t++) {
    float rg = 1.f / (1.f + expf(-(ir[t] + hr[t])));
    float zg = 1.f / (1.f + expf(-(iz[t] + hz[t])));
    float ng = tanhf(in_[t] + rg * hn[t]);
    float v = (1.f - zg) * ng + zg * st[t];
    us hb = f2bf(v);
    oh.u[t] = hb;
    ol.u[t] = f2bf(v - bf2f(hb));
  }
  *(uint2*)&Hh[(size_t)row * Dd + j] = oh.w;
  *(uint2*)&Hl[(size_t)row * Dd + j] = ol.w;
}

// ---------------------------------------------------------------------------
// pick: walk the argmax chain over logit partials (NLT n-tiles).
// ---------------------------------------------------------------------------
__global__ __launch_bounds__(64) void pick_k(const float* __restrict__ Lpart,
                                             const float* __restrict__ b2v,
                                             float* __restrict__ out) {
  int b = blockIdx.x;
  int lane = threadIdx.x;
  int c = 0;
  float b2 = b2v[0];
  for (int s = 0; s < NST; s++) {
    int row;
    if (s == 0) row = b * 16 + (lane & 15);
    else row = 128 + (((b * 7 + (s - 1)) * 16 + (lane & 15)) * 16 + c);
    float v = 0.f;
#pragma unroll
    for (int t = 0; t < NLT; t++) v += Lpart[(size_t)t * Mtot + row];
    v += b2;
    if (lane < 16) out[(size_t)(b * NST + s) * An + lane] = v;
    float bv = (lane < 16) ? v : -1e30f;
    int bi = (lane < 16) ? lane : 999;
#pragma unroll
    for (int off = 1; off < 16; off <<= 1) {
      float ov = __shfl_xor(bv, off);
      int oi = __shfl_xor(bi, off);
      if (ov > bv || (ov == bv && oi < bi)) { bv = ov; bi = oi; }
    }
    c = __shfl(bi, 0);
  }
}

// ---------------------------------------------------------------------------
static inline void mm2(const us* Ah, const us* Al, int lda, const us* Bh, const us* Bl,
                       const float* bias, const float* bias2, int nsplit,
                       float* Cf, int ldc, us* Ch, us* Cl, int ldch,
                       int M, int N, int K, int relu, hipStream_t st) {
  dim3 g(N / 64, M / 64);
  mfma_nt<<<g, 256, 0, st>>>(Ah, Al, lda, Bh, Bl, bias, bias2, nsplit,
                             Cf, ldc, Ch, Cl, ldch, K, relu);
}
static inline void mm(const us* Ah, const us* Al, int lda, const us* Bh, const us* Bl,
                      const float* bias, float* Cf, int ldc, us* Ch, us* Cl, int ldch,
                      int M, int N, int K, int relu, hipStream_t st) {
  mm2(Ah, Al, lda, Bh, Bl, bias, bias, 1 << 30, Cf, ldc, Ch, Cl, ldch, M, N, K, relu, st);
}
static inline void sgemm(const float* A, const float* W, const float* bias, float* C,
                         int M, int N, int K, int lda, int ldc, int relu, hipStream_t st) {
  dim3 g((N + 63) / 64, (M + 63) / 64);
  gemm_s<<<g, 256, 0, st>>>(A, W, bias, C, M, N, K, lda, ldc, relu);
}
static inline void split(const float* x, us* h, us* l, int n, hipStream_t st) {
  int n4 = n >> 2;
  int blocks = (n4 + 255) / 256;
  if (blocks > 2048) blocks = 2048;
  split_k<<<blocks, 256, 0, st>>>(x, h, l, n4);
}
static inline Sub mksub(const us* Ah, const us* Al, const us* Bh, const us* Bl,
                        const float* bias, float* Cf, us* Ch, us* Cl,
                        int lda, int ldc, int ldch, int Nt) {
  Sub s; s.Ah = Ah; s.Al = Al; s.Bh = Bh; s.Bl = Bl; s.bias = bias;
  s.Cf = Cf; s.Ch = Ch; s.Cl = Cl; s.lda = lda; s.ldc = ldc; s.ldch = ldch; s.Nt = Nt;
  return s;
}

extern "C" void kernel_launch(void* const* d_in, const int* in_sizes, int n_in,
                              void* d_out, int out_size, void* d_ws, size_t ws_size,
                              hipStream_t stream) {
  const float* video     = (const float*)d_in[0];
  const float* script    = (const float*)d_in[1];
  const float* question  = (const float*)d_in[2];
  const float* a_texts   = (const float*)d_in[3];
  const float* a_buttons = (const float*)d_in[4];
  const float* v_w1 = (const float*)d_in[5];
  const float* v_b1 = (const float*)d_in[6];
  const float* v_w2 = (const float*)d_in[7];
  const float* v_b2 = (const float*)d_in[8];
  const float* t_w1 = (const float*)d_in[9];
  const float* t_b1 = (const float*)d_in[10];
  const float* t_w2 = (const float*)d_in[11];
  const float* t_b2 = (const float*)d_in[12];
  const float* pre_w1 = (const float*)d_in[13];
  const float* pre_b1 = (const float*)d_in[14];
  const float* pre_w2 = (const float*)d_in[15];
  const float* pre_b2 = (const float*)d_in[16];
  const float* s2v_win  = (const float*)d_in[17];
  const float* s2v_bin  = (const float*)d_in[18];
  const float* s2v_wout = (const float*)d_in[19];
  const float* s2v_bout = (const float*)d_in[20];
  const float* qa_win  = (const float*)d_in[21];
  const float* qa_bin  = (const float*)d_in[22];
  const float* qa_wout = (const float*)d_in[23];
  const float* qa_bout = (const float*)d_in[24];
  const float* gru_wih = (const float*)d_in[25];
  const float* gru_whh = (const float*)d_in[26];
  const float* gru_bih = (const float*)d_in[27];
  const float* gru_bhh = (const float*)d_in[28];
  const float* proj_w1 = (const float*)d_in[29];
  const float* proj_b1 = (const float*)d_in[30];
  const float* proj_w2 = (const float*)d_in[31];
  const float* proj_b2 = (const float*)d_in[32];
  const float* state0  = (const float*)d_in[33];
  (void)in_sizes; (void)n_in; (void)out_size; (void)ws_size;

  constexpr int W589  = 768 * 768;
  constexpr int W1769 = 2304 * 768;
  constexpr int W9437 = 3072 * 3072;
  constexpr int W2359 = 768 * 3072;
  constexpr int SMe   = 1024 * 768;
  constexpr int BIGe  = 4096 * 768;

  char* base = (char*)d_ws;
  char* RW1 = base;                   // 9,437,184 : phase-A weights -> gABall(head)
  char* RW2 = RW1 + 9437184;          // 9,437,184 : s2v/qa/pre_w2 weights -> gABall(tail)
  char* R1  = RW2 + 9437184;          // 28,311,552
  char* R2  = R1 + 28311552;          // 12,582,912
  char* X   = R2 + 12582912;          // 25,165,824
  char* P   = X + 25165824;           // abin + Hh/Hl tail overlap
  char* P2  = P + 6815744;            // persistents

  // RW1
  us* vw1h = (us*)RW1;        us* vw1l = vw1h + W589;
  us* vw2h = vw1l + W589;     us* vw2l = vw2h + W589;
  us* tw1h = vw2l + W589;     us* tw1l = tw1h + W589;
  us* tw2h = tw1l + W589;     us* tw2l = tw2h + W589;
  // RW2
  us* s2vwh = (us*)RW2;       us* s2vwl = s2vwh + W1769;
  us* s2voh = s2vwl + W1769;  us* s2vol = s2voh + W589;
  us* qawh  = (us*)RW2;       us* qawl  = qawh + W1769;
  us* qaoh  = qawl + W1769;   us* qaol  = qaoh + W589;
  us* pw2h  = (us*)RW2;       us* pw2l  = pw2h + W2359;
  float* gABall = (float*)RW1;          // [1024 x 4608] f32, spans RW1+RW2
  // R1: video path (phase A), then kvproj/qproj, then kv2/qp2/S2, then weights
  us* vidh = (us*)R1;         us* vidl = vidh + BIGe;      // R1[0..12.6MB)
  us* hidh = vidl + BIGe;     us* hidl = hidh + BIGe;      // R1[12.6..25.2MB)
  float* kvproj = (float*)R1;                              // 4096x1536 f32
  float* qproj  = kvproj + (size_t)4096 * 1536;            // R1+25.2MB, 3MB
  float* kv2 = (float*)R1;
  float* qp2 = (float*)(R1 + 6291456);
  float* S2  = (float*)(R1 + 9437184);
  us* pw1h = (us*)R1;         us* pw1l = pw1h + W9437;     // spans into R2
  us* gwALLh = (us*)R1;                                    // [4608x768]
  us* gwALLl = (us*)(R1 + 7077888);
  us* pjw1h  = (us*)(R1 + 14155776); us* pjw1l = pjw1h + W589;
  // R2
  us* vh = (us*)R2;           us* vl = vh + BIGe;
  us* aoh = (us*)(R2 + 3145728); us* aol = aoh + SMe;
  us* Hh = (us*)R2;           us* Hl = Hh + (size_t)Mtot * Dd;  // spans R2+X+P
  // X: phase-A script/ab temporaries (dead before S1), then S1/cat/preh
  us* inTh  = (us*)X;             us* inTl  = inTh + 2 * SMe;    // X[0..6.3MB)
  us* hid2h = (us*)(X + 6291456); us* hid2l = hid2h + 2 * SMe;   // X[6.3..12.6MB)
  us* abh1h = (us*)(X + 12582912); us* abh1l = abh1h + SMe;      // X[12.6..15.7MB)
  float* S1 = (float*)X;
  us* cath = (us*)X;          us* catl = cath + (size_t)1024 * DPn;
  us* prehh = (us*)(X + 12582912); us* prehl = prehh + (size_t)1024 * DPn;
  // P (overwritten by Hl tail after abin dead)
  us* abinh = (us*)P;         us* abinl = abinh + SMe;
  // P2 persistents
  us* sc2h   = (us*)P2;                       // 2048x768 split (script|a_texts)
  us* sc2l   = sc2h + 2 * SMe;
  float* scat_f = (float*)(P2 + 6291456);     // 2048x768 f32
  float* vatt   = (float*)(P2 + 12582912);
  float* inps_f = (float*)(P2 + 15728640);
  us* inpsh = (us*)(P2 + 18874368); us* inpsl = inpsh + SMe;
  float* qf    = (float*)(P2 + 22020096);
  float* qhid  = (float*)(P2 + 22044672);
  float* gh0   = (float*)(P2 + 22069248);
  float* Lpart = (float*)(P2 + 22085632);     // NLT x 14464 f32
  float* at_f  = scat_f + (size_t)1024 * Dd;  // rows 1024..2047
  us* sch = sc2h;  us* scl = sc2l;            // rows 0..1023
  // ab2 temp borrows inpsh slot (inps written only at pre2, after cat_fill)
  us* ab2h  = (us*)(P2 + 18874368); us* ab2l  = ab2h + SMe;

  // ---- phase A: weight splits + input splits ----
  split4_k<<<dim3(1024, 4), 256, 0, stream>>>(v_w1, vw1h, vw1l, W589,
                                              v_w2, vw2h, vw2l, W589,
                                              t_w1, tw1h, tw1l, W589,
                                              t_w2, tw2h, tw2l, W589);
  split(video, vidh, vidl, BIGe, stream);
  split4_k<<<dim3(1024, 3), 256, 0, stream>>>(script, inTh, inTl, SMe,
                                              a_texts, inTh + SMe, inTl + SMe, SMe,
                                              a_buttons, abinh, abinl, SMe,
                                              nullptr, nullptr, nullptr, 0);
  // B1: video-mm1 (64yt) + scat-mm1 (32yt) + ab-mm1 (16yt), all N=768 K=768 relu
  {
    Sub sv = mksub(vidh, vidl, vw1h, vw1l, v_b1, nullptr, hidh, hidl, Dd, 0, Dd, 12);
    Sub ss = mksub(inTh, inTl, tw1h, tw1l, t_b1, nullptr, hid2h, hid2l, Dd, 0, Dd, 12);
    Sub sa = mksub(abinh, abinl, vw1h, vw1l, v_b1, nullptr, abh1h, abh1l, Dd, 0, Dd, 12);
    mfma_ntb<<<dim3(12, 112), 256, 0, stream>>>(sv, ss, sa, 64, 96, Dd, 1);
  }
  sgemm(question, t_w1, t_b1, qhid, Bn, Dd, Dd, Dd, Dd, 1, stream);
  sgemm(qhid, t_w2, t_b2, qf, Bn, Dd, Dd, Dd, Dd, 0, stream);
  // B2: video-mm2 + scat-mm2 (+f32) + ab-mm2
  {
    Sub sv = mksub(hidh, hidl, vw2h, vw2l, v_b2, nullptr, vh, vl, Dd, 0, Dd, 12);
    Sub ss = mksub(hid2h, hid2l, tw2h, tw2l, t_b2, scat_f, sc2h, sc2l, Dd, Dd, Dd, 12);
    Sub sa = mksub(abh1h, abh1l, vw2h, vw2l, v_b2, nullptr, ab2h, ab2l, Dd, 0, Dd, 12);
    mfma_ntb<<<dim3(12, 112), 256, 0, stream>>>(sv, ss, sa, 64, 96, Dd, 0);
  }

  // ---- s2v attention (K/V merged: N=1536) ----
  split4_k<<<dim3(1024, 2), 256, 0, stream>>>(s2v_win, s2vwh, s2vwl, W1769,
                                              s2v_wout, s2voh, s2vol, W589,
                                              nullptr, nullptr, nullptr, 0,
                                              nullptr, nullptr, nullptr, 0);
  // B3: kvproj (64yt, Nt24) + qproj (16yt, Nt12)
  {
    Sub sk = mksub(vh, vl, s2vwh + (size_t)Dd * Dd, s2vwl + (size_t)Dd * Dd,
                   s2v_bin + Dd, kvproj, nullptr, nullptr, Dd, 1536, 0, 24);
    Sub sq = mksub(sch, scl, s2vwh, s2vwl, s2v_bin, qproj, nullptr, nullptr,
                   Dd, Dd, 0, 12);
    mfma_ntb<<<dim3(24, 80), 256, 0, stream>>>(sk, sq, sq, 64, 80, Dd, 0);
  }
  att_qk<<<dim3(Bn * NH, TSn / 32, TVn / 64), 256, 0, stream>>>(qproj, kvproj, S1,
                                                                TSn, TVn, 1, 1536, 0.125f);
  softmax_rows<<<Bn * NH * TSn, 256, 0, stream>>>(S1, TVn);
  att_pv<<<dim3(Bn * NH, TSn / 32), 256, 0, stream>>>(S1, kvproj + Dd, aoh, aol,
                                                      TSn, TVn, 1, 1536);

  // ---- phase B: cat assembly + qa attention ----
  split(qa_win, qawh, qawl, W1769, stream);          // overwrites s2vw (dead)
  cat_fill<<<(1024 * Dd + 255) / 256, 256, 0, stream>>>(qf, at_f, ab2h, ab2l,
                                                        cath, catl);
  // B4: vatt-out (16yt) + qp2 (16yt) + kv2 (16yt, Nt24)
  {
    Sub svat = mksub(aoh, aol, s2voh, s2vol, s2v_bout, vatt, nullptr, nullptr,
                     Dd, Dd, 0, 12);
    Sub sqp = mksub(cath + 2 * Dd, catl + 2 * Dd, qawh, qawl, qa_bin,
                    qp2, nullptr, nullptr, DPn, Dd, 0, 12);
    Sub skv = mksub(sch, scl, qawh + (size_t)Dd * Dd, qawl + (size_t)Dd * Dd,
                    qa_bin + Dd, kv2, nullptr, nullptr, Dd, 1536, 0, 24);
    mfma_ntb<<<dim3(24, 48), 256, 0, stream>>>(svat, sqp, skv, 16, 32, Dd, 0);
  }
  split(qa_wout, qaoh, qaol, W589, stream);          // overwrites s2vo (dead)
  att_qk<<<dim3(Bn * NST * NH, 1, TSn / 64), 256, 0, stream>>>(qp2, kv2, S2,
                                                               An, TSn, NST, 1536, 0.125f);
  softmax_rows<<<Bn * NST * NH * An, 256, 0, stream>>>(S2, TSn);
  att_pv<<<dim3(Bn * NST * NH, 1), 256, 0, stream>>>(S2, kv2 + Dd, aoh, aol,
                                                     An, TSn, NST, 1536);
  mm(aoh, aol, Dd, qaoh, qaol, qa_bout, nullptr, 0, cath + Dd, catl + Dd, DPn,
     1024, Dd, Dd, 0, stream);
  qv2_k<<<1024, 256, 0, stream>>>(S2, vatt, cath, catl);

  // ---- pre-MLP + merged GRU gates ----
  split(pre_w1, pw1h, pw1l, W9437, stream);
  mm(cath, catl, DPn, pw1h, pw1l, pre_b1, nullptr, 0, prehh, prehl, DPn,
     1024, DPn, DPn, 1, stream);
  split4_k<<<dim3(1024, 4), 256, 0, stream>>>(pre_w2, pw2h, pw2l, W2359,
                                              gru_wih, gwALLh, gwALLl, W1769,
                                              gru_whh, gwALLh + W1769, gwALLl + W1769, W1769,
                                              proj_w1, pjw1h, pjw1l, W589);
  mm(prehh, prehl, DPn, pw2h, pw2l, pre_b2, inps_f, Dd, inpsh, inpsl, Dd,
     1024, Dd, DPn, 0, stream);
  mm2(inpsh, inpsl, Dd, gwALLh, gwALLl, gru_bih, gru_bhh, GSn,
      gABall, 4608, nullptr, nullptr, 0, 1024, 4608, Dd, 0, stream);
  sgemm(state0, gru_whh, gru_bhh, gh0, 1, GSn, Dd, Dd, GSn, 0, stream);

  // ---- candidate enumeration + logits + argmax chain ----
  combine_all<<<(Mtot * (Dd / 4) + 255) / 256, 256, 0, stream>>>(gABall, gh0, inps_f,
                                                                 state0, Hh, Hl);
  mfma_logit128<<<dim3(NLT, Mtot / 128), 256, 0, stream>>>(Hh, Hl, pjw1h, pjw1l,
                                                           proj_b1, proj_w2, Lpart);
  pick_k<<<Bn, 64, 0, stream>>>(Lpart, proj_b2, (float*)d_out);
}

// Round 6
// 1111.194 us; speedup vs baseline: 1.0233x; 1.0233x over previous
//
#include <hip/hip_runtime.h>
#include <hip/hip_bf16.h>
#include <math.h>

constexpr int Dd  = 768;
constexpr int NH  = 12;
constexpr int DHd = 64;
constexpr int Bn  = 8;
constexpr int TVn = 512;
constexpr int TSn = 128;
constexpr int NST = 8;
constexpr int An  = 16;
constexpr int DPn = 3072;
constexpr int GSn = 2304;
constexpr int Mtot = 14464;   // 128 (s=0) + 8*7*16*16 candidate rows; 113*128
constexpr int NLT = 6;        // logit n-tiles at 128-wide tiling (768/128)

typedef unsigned short us;
using short8   = __attribute__((ext_vector_type(8))) short;
using floatx16 = __attribute__((ext_vector_type(16))) float;

typedef __attribute__((address_space(1))) const unsigned char glb_b;
typedef __attribute__((address_space(3))) unsigned char lds_b;

// async global->LDS DMA, 16B per lane, dest = lptr + lane*16 (HW-linear)
__device__ inline void gload16(const void* g, void* l) {
  __builtin_amdgcn_global_load_lds((glb_b*)g, (lds_b*)l, 16, 0, 0);
}

__device__ inline us f2bf(float x) {
  union { float f; unsigned u; } a; a.f = x;
  return (us)((a.u + 0x7fffu + ((a.u >> 16) & 1u)) >> 16);
}
__device__ inline float bf2f(us h) {
  union { unsigned u; float f; } a; a.u = ((unsigned)h) << 16;
  return a.f;
}

// ---------------------------------------------------------------------------
// splits (float4-vectorized)
// ---------------------------------------------------------------------------
__global__ void split_k(const float* __restrict__ x, us* __restrict__ h,
                        us* __restrict__ l, int n4) {
  for (int i = blockIdx.x * 256 + threadIdx.x; i < n4; i += gridDim.x * 256) {
    float4 v = ((const float4*)x)[i];
    float vv[4] = {v.x, v.y, v.z, v.w};
    union { us u[4]; uint2 w; } hh, ll;
#pragma unroll
    for (int t = 0; t < 4; t++) {
      us hb = f2bf(vv[t]);
      hh.u[t] = hb;
      ll.u[t] = f2bf(vv[t] - bf2f(hb));
    }
    ((uint2*)h)[i] = hh.w;
    ((uint2*)l)[i] = ll.w;
  }
}

__global__ void split4_k(const float* s0, us* h0, us* l0, int n0,
                         const float* s1, us* h1, us* l1, int n1,
                         const float* s2, us* h2, us* l2, int n2,
                         const float* s3, us* h3, us* l3, int n3) {
  const float* s; us* h; us* l; int n;
  switch (blockIdx.y) {
    case 0: s = s0; h = h0; l = l0; n = n0; break;
    case 1: s = s1; h = h1; l = l1; n = n1; break;
    case 2: s = s2; h = h2; l = l2; n = n2; break;
    default: s = s3; h = h3; l = l3; n = n3; break;
  }
  int n4 = n >> 2;
  for (int i = blockIdx.x * 256 + threadIdx.x; i < n4; i += gridDim.x * 256) {
    float4 v = ((const float4*)s)[i];
    float vv[4] = {v.x, v.y, v.z, v.w};
    union { us u[4]; uint2 w; } hh, ll;
#pragma unroll
    for (int t = 0; t < 4; t++) {
      us hb = f2bf(vv[t]);
      hh.u[t] = hb;
      ll.u[t] = f2bf(vv[t] - bf2f(hb));
    }
    ((uint2*)h)[i] = hh.w;
    ((uint2*)l)[i] = ll.w;
  }
}

__device__ inline short8 lds8(const us* p) {
  const uint2* q = (const uint2*)p;
  uint2 a = q[0], b = q[1];
  union { unsigned u[4]; short8 v; } t;
  t.u[0] = a.x; t.u[1] = a.y; t.u[2] = b.x; t.u[3] = b.y;
  return t.v;
}

// ---------------------------------------------------------------------------
// bf16x3 MFMA NT GEMM — 64x64 tile, 4 waves, 3 acc chains, dbuf LDS,
// 1 barrier/iter. Staging via global_load_lds (16B/lane DMA, no VGPR
// round-trip, conflict-free linear writes). Pad-free [64][32] rows with
// slot-swizzle phys = slot ^ ((row>>1)&3): bank-group = 4*(row&1) +
// (slot^((row>>1)&3)) is bijective over 8-row stripes -> conflict-free
// ds_read_b128. Swizzle realized on the GLOBAL source address (lane l
// loads slot (l&3)^((l>>3)&3) of its row); LDS dest stays linear.
// ---------------------------------------------------------------------------
__global__ __launch_bounds__(256) void mfma_nt(
    const us* __restrict__ Ah, const us* __restrict__ Al, int lda,
    const us* __restrict__ Bh, const us* __restrict__ Bl,
    const float* __restrict__ bias, const float* __restrict__ bias2, int nsplit,
    float* __restrict__ Cf, int ldc,
    us* __restrict__ Ch, us* __restrict__ Cl, int ldch,
    int K, int relu) {
  __shared__ us Ash[2][64][32], Asl[2][64][32], Bsh[2][64][32], Bsl[2][64][32];
  const int tid = threadIdx.x;
  const int bm = blockIdx.y * 64, bn = blockIdx.x * 64;
  const int wave = tid >> 6, lane = tid & 63;
  const int mh = (wave & 1) * 32, nh = (wave >> 1) * 32;
  const int l31 = lane & 31, hi5 = lane >> 5;
  const int srow = tid >> 2;
  const int scol = (((tid & 3) ^ ((tid >> 3) & 3)) << 3);   // swizzled src col
  const int rc2 = (l31 >> 1) & 3;                           // read swizzle key
  const int wb = wave * 16;
  const us* pAh = Ah + (size_t)(bm + srow) * lda + scol;
  const us* pAl = Al + (size_t)(bm + srow) * lda + scol;
  const us* pBh = Bh + (size_t)(bn + srow) * K + scol;
  const us* pBl = Bl + (size_t)(bn + srow) * K + scol;

  floatx16 acc_hh, acc_hl, acc_lh;
#pragma unroll
  for (int i = 0; i < 16; i++) { acc_hh[i] = 0.f; acc_hl[i] = 0.f; acc_lh[i] = 0.f; }

  const int iters = K >> 5;
  gload16(pAh, &Ash[0][wb][0]);
  gload16(pAl, &Asl[0][wb][0]);
  gload16(pBh, &Bsh[0][wb][0]);
  gload16(pBl, &Bsl[0][wb][0]);
  int p = 0;
  for (int it = 0; it < iters; ++it) {
    __syncthreads();                       // drains DMA: buf[p] resident
    if (it + 1 < iters) {
      int ko = (it + 1) * 32;
      gload16(pAh + ko, &Ash[p ^ 1][wb][0]);
      gload16(pAl + ko, &Asl[p ^ 1][wb][0]);
      gload16(pBh + ko, &Bsh[p ^ 1][wb][0]);
      gload16(pBl + ko, &Bsl[p ^ 1][wb][0]);
    }
#pragma unroll
    for (int ks = 0; ks < 32; ks += 16) {
      int col = ((((ks >> 3) + hi5) ^ rc2) << 3);
      short8 fa_h = lds8(&Ash[p][mh + l31][col]);
      short8 fa_l = lds8(&Asl[p][mh + l31][col]);
      short8 fb_h = lds8(&Bsh[p][nh + l31][col]);
      short8 fb_l = lds8(&Bsl[p][nh + l31][col]);
      acc_hh = __builtin_amdgcn_mfma_f32_32x32x16_bf16(fa_h, fb_h, acc_hh, 0, 0, 0);
      acc_hl = __builtin_amdgcn_mfma_f32_32x32x16_bf16(fa_h, fb_l, acc_hl, 0, 0, 0);
      acc_lh = __builtin_amdgcn_mfma_f32_32x32x16_bf16(fa_l, fb_h, acc_lh, 0, 0, 0);
    }
    p ^= 1;
  }
  int n = bn + nh + l31;
  float bv = (n < nsplit) ? bias[n] : bias2[n - nsplit];
#pragma unroll
  for (int r = 0; r < 16; r++) {
    int m = bm + mh + (r & 3) + 8 * (r >> 2) + 4 * hi5;
    float v = acc_hh[r] + acc_hl[r] + acc_lh[r] + bv;
    if (relu) v = fmaxf(v, 0.f);
    if (Cf) Cf[(size_t)m * ldc + n] = v;
    if (Ch) {
      us hb = f2bf(v);
      Ch[(size_t)m * ldch + n] = hb;
      Cl[(size_t)m * ldch + n] = f2bf(v - bf2f(hb));
    }
  }
}

// ---------------------------------------------------------------------------
// Batched variant: up to 3 sub-GEMMs share one launch (y-tile ranges).
// Same gload_lds/swizzle body.
// ---------------------------------------------------------------------------
struct Sub {
  const us* Ah; const us* Al; const us* Bh; const us* Bl;
  const float* bias; float* Cf; us* Ch; us* Cl;
  int lda, ldc, ldch, Nt;
};

__global__ __launch_bounds__(256) void mfma_ntb(Sub s0, Sub s1, Sub s2,
                                                int c1, int c2, int K, int relu) {
  Sub s; int yt = blockIdx.y;
  if (yt < c1) { s = s0; }
  else if (yt < c2) { s = s1; yt -= c1; }
  else { s = s2; yt -= c2; }
  if ((int)blockIdx.x >= s.Nt) return;
  __shared__ us Ash[2][64][32], Asl[2][64][32], Bsh[2][64][32], Bsl[2][64][32];
  const int tid = threadIdx.x;
  const int bm = yt * 64, bn = blockIdx.x * 64;
  const int wave = tid >> 6, lane = tid & 63;
  const int mh = (wave & 1) * 32, nh = (wave >> 1) * 32;
  const int l31 = lane & 31, hi5 = lane >> 5;
  const int srow = tid >> 2;
  const int scol = (((tid & 3) ^ ((tid >> 3) & 3)) << 3);
  const int rc2 = (l31 >> 1) & 3;
  const int wb = wave * 16;
  const us* pAh = s.Ah + (size_t)(bm + srow) * s.lda + scol;
  const us* pAl = s.Al + (size_t)(bm + srow) * s.lda + scol;
  const us* pBh = s.Bh + (size_t)(bn + srow) * K + scol;
  const us* pBl = s.Bl + (size_t)(bn + srow) * K + scol;

  floatx16 acc_hh, acc_hl, acc_lh;
#pragma unroll
  for (int i = 0; i < 16; i++) { acc_hh[i] = 0.f; acc_hl[i] = 0.f; acc_lh[i] = 0.f; }

  const int iters = K >> 5;
  gload16(pAh, &Ash[0][wb][0]);
  gload16(pAl, &Asl[0][wb][0]);
  gload16(pBh, &Bsh[0][wb][0]);
  gload16(pBl, &Bsl[0][wb][0]);
  int p = 0;
  for (int it = 0; it < iters; ++it) {
    __syncthreads();
    if (it + 1 < iters) {
      int ko = (it + 1) * 32;
      gload16(pAh + ko, &Ash[p ^ 1][wb][0]);
      gload16(pAl + ko, &Asl[p ^ 1][wb][0]);
      gload16(pBh + ko, &Bsh[p ^ 1][wb][0]);
      gload16(pBl + ko, &Bsl[p ^ 1][wb][0]);
    }
#pragma unroll
    for (int ks = 0; ks < 32; ks += 16) {
      int col = ((((ks >> 3) + hi5) ^ rc2) << 3);
      short8 fa_h = lds8(&Ash[p][mh + l31][col]);
      short8 fa_l = lds8(&Asl[p][mh + l31][col]);
      short8 fb_h = lds8(&Bsh[p][nh + l31][col]);
      short8 fb_l = lds8(&Bsl[p][nh + l31][col]);
      acc_hh = __builtin_amdgcn_mfma_f32_32x32x16_bf16(fa_h, fb_h, acc_hh, 0, 0, 0);
      acc_hl = __builtin_amdgcn_mfma_f32_32x32x16_bf16(fa_h, fb_l, acc_hl, 0, 0, 0);
      acc_lh = __builtin_amdgcn_mfma_f32_32x32x16_bf16(fa_l, fb_h, acc_lh, 0, 0, 0);
    }
    p ^= 1;
  }
  int n = bn + nh + l31;
  float bv = s.bias[n];
#pragma unroll
  for (int r = 0; r < 16; r++) {
    int m = bm + mh + (r & 3) + 8 * (r >> 2) + 4 * hi5;
    float v = acc_hh[r] + acc_hl[r] + acc_lh[r] + bv;
    if (relu) v = fmaxf(v, 0.f);
    if (s.Cf) s.Cf[(size_t)m * s.ldc + n] = v;
    if (s.Ch) {
      us hb = f2bf(v);
      s.Ch[(size_t)m * s.ldch + n] = hb;
      s.Cl[(size_t)m * s.ldch + n] = f2bf(v - bf2f(hb));
    }
  }
}

// ---------------------------------------------------------------------------
// logit GEMM, 128x128 tile (grid 6x113=678 blocks), gload_lds staging.
// Cross chains share one accumulator (R1-verified). Epilogue:
// relu(acc+b1[n])*w2[n], reduce over 128-col n-tile -> Lpart[ntile][m].
// LDS 64.5 KB -> 2 blocks/CU.
// ---------------------------------------------------------------------------
__global__ __launch_bounds__(256, 2) void mfma_logit128(
    const us* __restrict__ Ah, const us* __restrict__ Al,
    const us* __restrict__ Bh, const us* __restrict__ Bl,
    const float* __restrict__ bias1, const float* __restrict__ w2,
    float* __restrict__ Lpart) {
  __shared__ us Ash[2][128][32], Asl[2][128][32], Bsh[2][128][32], Bsl[2][128][32];
  __shared__ float lpart[128];
  const int K = Dd;
  const int tid = threadIdx.x;
  const int bm = blockIdx.y * 128, bn = blockIdx.x * 128;
  const int wave = tid >> 6, lane = tid & 63;
  const int mh = (wave & 1) * 64, nh = (wave >> 1) * 64;
  const int l31 = lane & 31, hi5 = lane >> 5;
  const int srow = tid >> 2;
  const int scol = (((tid & 3) ^ ((tid >> 3) & 3)) << 3);
  const int rc2 = (l31 >> 1) & 3;
  const int wb = wave * 16;
  const us* pAh = Ah + (size_t)(bm + srow) * K + scol;
  const us* pAl = Al + (size_t)(bm + srow) * K + scol;
  const us* pBh = Bh + (size_t)(bn + srow) * K + scol;
  const us* pBl = Bl + (size_t)(bn + srow) * K + scol;
  const size_t strA = (size_t)64 * K, strB = (size_t)64 * K;
  if (tid < 128) lpart[tid] = 0.f;

  floatx16 acc_hh[2][2], acc_x[2][2];
#pragma unroll
  for (int i = 0; i < 2; i++)
#pragma unroll
    for (int j = 0; j < 2; j++)
#pragma unroll
      for (int r = 0; r < 16; r++) { acc_hh[i][j][r] = 0.f; acc_x[i][j][r] = 0.f; }

  const int iters = K >> 5;
  gload16(pAh,        &Ash[0][wb][0]);
  gload16(pAh + strA, &Ash[0][wb + 64][0]);
  gload16(pAl,        &Asl[0][wb][0]);
  gload16(pAl + strA, &Asl[0][wb + 64][0]);
  gload16(pBh,        &Bsh[0][wb][0]);
  gload16(pBh + strB, &Bsh[0][wb + 64][0]);
  gload16(pBl,        &Bsl[0][wb][0]);
  gload16(pBl + strB, &Bsl[0][wb + 64][0]);
  int p = 0;
  for (int it = 0; it < iters; ++it) {
    __syncthreads();
    if (it + 1 < iters) {
      int ko = (it + 1) * 32;
      gload16(pAh + ko,        &Ash[p ^ 1][wb][0]);
      gload16(pAh + strA + ko, &Ash[p ^ 1][wb + 64][0]);
      gload16(pAl + ko,        &Asl[p ^ 1][wb][0]);
      gload16(pAl + strA + ko, &Asl[p ^ 1][wb + 64][0]);
      gload16(pBh + ko,        &Bsh[p ^ 1][wb][0]);
      gload16(pBh + strB + ko, &Bsh[p ^ 1][wb + 64][0]);
      gload16(pBl + ko,        &Bsl[p ^ 1][wb][0]);
      gload16(pBl + strB + ko, &Bsl[p ^ 1][wb + 64][0]);
    }
#pragma unroll
    for (int ks = 0; ks < 32; ks += 16) {
      int col = ((((ks >> 3) + hi5) ^ rc2) << 3);
      short8 fah[2], fal[2], fbh[2], fbl[2];
#pragma unroll
      for (int f = 0; f < 2; f++) {
        fah[f] = lds8(&Ash[p][mh + f * 32 + l31][col]);
        fal[f] = lds8(&Asl[p][mh + f * 32 + l31][col]);
        fbh[f] = lds8(&Bsh[p][nh + f * 32 + l31][col]);
        fbl[f] = lds8(&Bsl[p][nh + f * 32 + l31][col]);
      }
#pragma unroll
      for (int fm = 0; fm < 2; fm++)
#pragma unroll
        for (int fn = 0; fn < 2; fn++) {
          acc_hh[fm][fn] = __builtin_amdgcn_mfma_f32_32x32x16_bf16(fah[fm], fbh[fn], acc_hh[fm][fn], 0, 0, 0);
          acc_x[fm][fn]  = __builtin_amdgcn_mfma_f32_32x32x16_bf16(fah[fm], fbl[fn], acc_x[fm][fn], 0, 0, 0);
          acc_x[fm][fn]  = __builtin_amdgcn_mfma_f32_32x32x16_bf16(fal[fm], fbh[fn], acc_x[fm][fn], 0, 0, 0);
        }
    }
    p ^= 1;
  }
  float b1[2], wn[2];
#pragma unroll
  for (int fn = 0; fn < 2; fn++) {
    int n = bn + nh + fn * 32 + l31;
    b1[fn] = bias1[n];
    wn[fn] = w2[n];
  }
#pragma unroll
  for (int fm = 0; fm < 2; fm++) {
#pragma unroll
    for (int r = 0; r < 16; r++) {
      int mloc = mh + fm * 32 + (r & 3) + 8 * (r >> 2) + 4 * hi5;
      float v = 0.f;
#pragma unroll
      for (int fn = 0; fn < 2; fn++) {
        float vv = acc_hh[fm][fn][r] + acc_x[fm][fn][r] + b1[fn];
        v += fmaxf(vv, 0.f) * wn[fn];
      }
      v += __shfl_xor(v, 1);
      v += __shfl_xor(v, 2);
      v += __shfl_xor(v, 4);
      v += __shfl_xor(v, 8);
      v += __shfl_xor(v, 16);
      if (l31 == 0) atomicAdd(&lpart[mloc], v);
    }
  }
  __syncthreads();
  if (tid < 128) Lpart[(size_t)blockIdx.x * Mtot + bm + tid] = lpart[tid];
}

// ---------------------------------------------------------------------------
// scalar f32 NT GEMM (tiny M: question, gh0)
// ---------------------------------------------------------------------------
__global__ __launch_bounds__(256) void gemm_s(const float* __restrict__ A,
                                              const float* __restrict__ Bw,
                                              const float* __restrict__ bias,
                                              float* __restrict__ C,
                                              int M, int N, int K,
                                              int lda, int ldc, int relu) {
  __shared__ float As[16][65];
  __shared__ float Bs[16][65];
  int bm = blockIdx.y * 64, bn = blockIdx.x * 64;
  int tid = threadIdx.x;
  int tx = tid & 15, ty = tid >> 4;
  float acc[4][4] = {};
  for (int k0 = 0; k0 < K; k0 += 16) {
#pragma unroll
    for (int i = 0; i < 4; i++) {
      int l = tid * 4 + i;
      int row = l >> 4, kk = l & 15;
      float v = 0.f;
      if (bm + row < M) v = A[(size_t)(bm + row) * lda + k0 + kk];
      As[kk][row] = v;
    }
#pragma unroll
    for (int i = 0; i < 4; i++) {
      int l = tid * 4 + i;
      int row = l >> 4, kk = l & 15;
      float v = 0.f;
      if (bn + row < N) v = Bw[(size_t)(bn + row) * K + k0 + kk];
      Bs[kk][row] = v;
    }
    __syncthreads();
#pragma unroll
    for (int kk = 0; kk < 16; kk++) {
      float a4[4], b4[4];
#pragma unroll
      for (int i = 0; i < 4; i++) a4[i] = As[kk][ty * 4 + i];
#pragma unroll
      for (int j = 0; j < 4; j++) b4[j] = Bs[kk][tx * 4 + j];
#pragma unroll
      for (int i = 0; i < 4; i++)
#pragma unroll
        for (int j = 0; j < 4; j++) acc[i][j] += a4[i] * b4[j];
    }
    __syncthreads();
  }
#pragma unroll
  for (int i = 0; i < 4; i++) {
    int m = bm + ty * 4 + i;
    if (m >= M) continue;
#pragma unroll
    for (int j = 0; j < 4; j++) {
      int n = bn + tx * 4 + j;
      if (n >= N) continue;
      float v = acc[i][j] + bias[n];
      if (relu) v = fmaxf(v, 0.f);
      C[(size_t)m * ldc + n] = v;
    }
  }
}

// ---------------------------------------------------------------------------
// attention (f32), float4-vectorized LDS
// ---------------------------------------------------------------------------
__global__ __launch_bounds__(256) void att_qk(const float* __restrict__ qp,
                                              const float* __restrict__ kp,
                                              float* __restrict__ Sout,
                                              int Tq, int Tk, int kdiv, int ldk,
                                              float scale) {
  int g = blockIdx.x;
  int h = g % NH;
  int qrow0 = (g / NH) * Tq;
  int krow0 = (g / (NH * kdiv)) * Tk;
  int q0 = blockIdx.y * 32;
  int k0 = blockIdx.z * 64;
  __shared__ float Qs[32][68];
  __shared__ float KsT[64][72];   // transposed: [d][k]
  int tid = threadIdx.x;
  {
    int row = tid >> 3, db = (tid & 7) * 8;
    int qr = q0 + row;
    float4 v0 = {0, 0, 0, 0}, v1 = {0, 0, 0, 0};
    if (qr < Tq) {
      const float* p = qp + (size_t)(qrow0 + qr) * Dd + h * DHd + db;
      v0 = *(const float4*)p;
      v1 = *(const float4*)(p + 4);
    }
    *(float4*)&Qs[row][db] = v0;
    *(float4*)&Qs[row][db + 4] = v1;
  }
#pragma unroll
  for (int half = 0; half < 2; half++) {
    int row = (tid >> 3) + half * 32, db = (tid & 7) * 8;
    int kr = k0 + row;
    float4 v0 = {0, 0, 0, 0}, v1 = {0, 0, 0, 0};
    if (kr < Tk) {
      const float* p = kp + (size_t)(krow0 + kr) * ldk + h * DHd + db;
      v0 = *(const float4*)p;
      v1 = *(const float4*)(p + 4);
    }
    KsT[db + 0][row] = v0.x; KsT[db + 1][row] = v0.y;
    KsT[db + 2][row] = v0.z; KsT[db + 3][row] = v0.w;
    KsT[db + 4][row] = v1.x; KsT[db + 5][row] = v1.y;
    KsT[db + 6][row] = v1.z; KsT[db + 7][row] = v1.w;
  }
  __syncthreads();
  int q = tid >> 3, kg = tid & 7;
  float acc[8] = {};
  for (int d = 0; d < DHd; d++) {
    float qv = Qs[q][d];
    float4 k0v = *(const float4*)&KsT[d][kg * 8];
    float4 k1v = *(const float4*)&KsT[d][kg * 8 + 4];
    acc[0] += qv * k0v.x; acc[1] += qv * k0v.y;
    acc[2] += qv * k0v.z; acc[3] += qv * k0v.w;
    acc[4] += qv * k1v.x; acc[5] += qv * k1v.y;
    acc[6] += qv * k1v.z; acc[7] += qv * k1v.w;
  }
  if (q0 + q < Tq) {
    size_t basep = ((size_t)g * Tq + q0 + q) * Tk + k0 + kg * 8;
#pragma unroll
    for (int j = 0; j < 8; j++) Sout[basep + j] = acc[j] * scale;
  }
}

// P@V with fused bf16-split output (Outh/Outl)
__global__ __launch_bounds__(256) void att_pv(const float* __restrict__ P,
                                              const float* __restrict__ vp,
                                              us* __restrict__ Outh,
                                              us* __restrict__ Outl,
                                              int Tq, int Tk, int kdiv, int ldv) {
  int g = blockIdx.x;
  int h = g % NH;
  int qrow0 = (g / NH) * Tq;
  int krow0 = (g / (NH * kdiv)) * Tk;
  int q0 = blockIdx.y * 32;
  __shared__ float Ps[32][68];
  __shared__ float Vs[64][72];
  int tid = threadIdx.x;
  int q = tid >> 3, dg = tid & 7;
  float acc[8] = {};
  for (int k0 = 0; k0 < Tk; k0 += 64) {
    {
      int row = tid >> 3, cb = (tid & 7) * 8;
      int qr = q0 + row;
      float4 v0 = {0, 0, 0, 0}, v1 = {0, 0, 0, 0};
      if (qr < Tq) {
        const float* p = P + ((size_t)g * Tq + qr) * Tk + k0 + cb;
        v0 = *(const float4*)p;
        v1 = *(const float4*)(p + 4);
      }
      *(float4*)&Ps[row][cb] = v0;
      *(float4*)&Ps[row][cb + 4] = v1;
    }
#pragma unroll
    for (int half = 0; half < 2; half++) {
      int row = (tid >> 3) + half * 32, db = (tid & 7) * 8;
      const float* p = vp + (size_t)(krow0 + k0 + row) * ldv + h * DHd + db;
      *(float4*)&Vs[row][db] = *(const float4*)p;
      *(float4*)&Vs[row][db + 4] = *(const float4*)(p + 4);
    }
    __syncthreads();
#pragma unroll 4
    for (int kk4 = 0; kk4 < 16; kk4++) {
      float4 pv = *(const float4*)&Ps[q][kk4 * 4];
      float pe[4] = {pv.x, pv.y, pv.z, pv.w};
#pragma unroll
      for (int e = 0; e < 4; e++) {
        int kk = kk4 * 4 + e;
        float4 v0 = *(const float4*)&Vs[kk][dg * 8];
        float4 v1 = *(const float4*)&Vs[kk][dg * 8 + 4];
        acc[0] += pe[e] * v0.x; acc[1] += pe[e] * v0.y;
        acc[2] += pe[e] * v0.z; acc[3] += pe[e] * v0.w;
        acc[4] += pe[e] * v1.x; acc[5] += pe[e] * v1.y;
        acc[6] += pe[e] * v1.z; acc[7] += pe[e] * v1.w;
      }
    }
    __syncthreads();
  }
  if (q0 + q < Tq) {
    size_t basep = (size_t)(qrow0 + q0 + q) * Dd + h * DHd + dg * 8;
    union { us u[8]; uint4 v; } ph, pl;
#pragma unroll
    for (int j = 0; j < 8; j++) {
      us hb = f2bf(acc[j]);
      ph.u[j] = hb;
      pl.u[j] = f2bf(acc[j] - bf2f(hb));
    }
    *(uint4*)&Outh[basep] = ph.v;
    *(uint4*)&Outl[basep] = pl.v;
  }
}

__global__ __launch_bounds__(256) void softmax_rows(float* __restrict__ X, int len) {
  int row = blockIdx.x;
  float* p = X + (size_t)row * len;
  int tid = threadIdx.x;
  __shared__ float red[4];
  __shared__ float red2[4];
  float lmax = -1e30f;
  for (int j = tid; j < len; j += 256) lmax = fmaxf(lmax, p[j]);
  for (int off = 32; off; off >>= 1) lmax = fmaxf(lmax, __shfl_down(lmax, off));
  if ((tid & 63) == 0) red[tid >> 6] = lmax;
  __syncthreads();
  if (tid == 0) red[0] = fmaxf(fmaxf(red[0], red[1]), fmaxf(red[2], red[3]));
  __syncthreads();
  float m = red[0];
  float lsum = 0.f;
  for (int j = tid; j < len; j += 256) {
    float e = expf(p[j] - m);
    p[j] = e;
    lsum += e;
  }
  for (int off = 32; off; off >>= 1) lsum += __shfl_down(lsum, off);
  if ((tid & 63) == 0) red2[tid >> 6] = lsum;
  __syncthreads();
  if (tid == 0) red2[0] = red2[0] + red2[1] + red2[2] + red2[3];
  __syncthreads();
  float inv = 1.f / red2[0];
  for (int j = tid; j < len; j += 256) p[j] *= inv;
}

// fused head-mean + qv = W @ vatt -> cat slice [0,D)
__global__ __launch_bounds__(256) void qv2_k(const float* __restrict__ S2,
                                             const float* __restrict__ vatt,
                                             us* __restrict__ ch, us* __restrict__ cl) {
  int row = blockIdx.x;
  int b = row / (NST * An);
  int bs = row / An;
  int a = row % An;
  __shared__ float wm[TSn];
  int tid = threadIdx.x;
  if (tid < TSn) {
    float acc = 0.f;
    for (int h = 0; h < NH; h++)
      acc += S2[(((size_t)bs * NH + h) * An + a) * TSn + tid];
    wm[tid] = acc * (1.f / NH);
  }
  __syncthreads();
  for (int j = tid; j < Dd; j += 256) {
    float acc = 0.f;
    for (int k = 0; k < TSn; k++)
      acc += wm[k] * vatt[((size_t)b * TSn + k) * Dd + j];
    size_t o = (size_t)row * DPn + j;
    us hb = f2bf(acc);
    ch[o] = hb;
    cl[o] = f2bf(acc - bf2f(hb));
  }
}

// cat slices [2D,3D) = qf[b] + at[row]  and  [3D,4D) = ab2 tmp bit-copy
__global__ void cat_fill(const float* __restrict__ qf, const float* __restrict__ at,
                         const us* __restrict__ ab2h, const us* __restrict__ ab2l,
                         us* __restrict__ ch, us* __restrict__ cl) {
  int idx = blockIdx.x * 256 + threadIdx.x;
  if (idx >= Bn * NST * An * Dd) return;
  int b = idx / (NST * An * Dd);
  int row = idx / Dd;
  int j = idx - row * Dd;
  float v = qf[b * Dd + j] + at[idx];
  size_t o = (size_t)row * DPn + 2 * Dd + j;
  us hb = f2bf(v);
  ch[o] = hb;
  cl[o] = f2bf(v - bf2f(hb));
  size_t o3 = (size_t)row * DPn + 3 * Dd + j;
  ch[o3] = ab2h[idx];
  cl[o3] = ab2l[idx];
}

// ---------------------------------------------------------------------------
// GRU combine for ALL candidate rows. gABall [1024 x 4608]: cols [0,2304) =
// x-gates (wih), cols [2304,4608) = h-gates (whh). Pre-split bf16 output.
// Row layout: [0,128): s=0 rows (b,a). [128,Mtot): 128+(((b*7+s-1)*16+a)*16+c).
// ---------------------------------------------------------------------------
__global__ void combine_all(const float* __restrict__ gABall,
                            const float* __restrict__ gh0,
                            const float* __restrict__ inps,
                            const float* __restrict__ state0,
                            us* __restrict__ Hh, us* __restrict__ Hl) {
  const int D4 = Dd / 4;
  const int LDG = 4608;
  int idx = blockIdx.x * 256 + threadIdx.x;
  if (idx >= Mtot * D4) return;
  int row = idx / D4, j = (idx - row * D4) * 4;
  const float* gp;
  const float* ghp;
  const float* stp;
  if (row < 128) {
    int b = row >> 4, a = row & 15;
    gp = gABall + ((size_t)(b * NST) * An + a) * LDG;
    ghp = gh0;
    stp = state0;
  } else {
    int r = row - 128;
    int c = r & 15; r >>= 4;
    int a = r & 15; r >>= 4;
    int sm1 = r % 7, b = r / 7;
    size_t prev = (size_t)(b * NST + sm1) * An + c;
    gp = gABall + ((size_t)(b * NST + sm1 + 1) * An + a) * LDG;
    ghp = gABall + prev * LDG + GSn;
    stp = inps + prev * Dd;
  }
  float4 ir4 = *(const float4*)(gp + j);
  float4 iz4 = *(const float4*)(gp + Dd + j);
  float4 in4 = *(const float4*)(gp + 2 * Dd + j);
  float4 hr4 = *(const float4*)(ghp + j);
  float4 hz4 = *(const float4*)(ghp + Dd + j);
  float4 hn4 = *(const float4*)(ghp + 2 * Dd + j);
  float4 st4 = *(const float4*)(stp + j);
  float ir[4] = {ir4.x, ir4.y, ir4.z, ir4.w};
  float iz[4] = {iz4.x, iz4.y, iz4.z, iz4.w};
  float in_[4] = {in4.x, in4.y, in4.z, in4.w};
  float hr[4] = {hr4.x, hr4.y, hr4.z, hr4.w};
  float hz[4] = {hz4.x, hz4.y, hz4.z, hz4.w};
  float hn[4] = {hn4.x, hn4.y, hn4.z, hn4.w};
  float st[4] = {st4.x, st4.y, st4.z, st4.w};
  union { us u[4]; uint2 w; } oh, ol;
#pragma unroll
  for (int t = 0; t < 4; t++) {
    float rg = 1.f / (1.f + expf(-(ir[t] + hr[t])));
    float zg = 1.f / (1.f + expf(-(iz[t] + hz[t])));
    float ng = tanhf(in_[t] + rg * hn[t]);
    float v = (1.f - zg) * ng + zg * st[t];
    us hb = f2bf(v);
    oh.u[t] = hb;
    ol.u[t] = f2bf(v - bf2f(hb));
  }
  *(uint2*)&Hh[(size_t)row * Dd + j] = oh.w;
  *(uint2*)&Hl[(size_t)row * Dd + j] = ol.w;
}

// ---------------------------------------------------------------------------
// pick: walk the argmax chain over logit partials (NLT n-tiles).
// ---------------------------------------------------------------------------
__global__ __launch_bounds__(64) void pick_k(const float* __restrict__ Lpart,
                                             const float* __restrict__ b2v,
                                             float* __restrict__ out) {
  int b = blockIdx.x;
  int lane = threadIdx.x;
  int c = 0;
  float b2 = b2v[0];
  for (int s = 0; s < NST; s++) {
    int row;
    if (s == 0) row = b * 16 + (lane & 15);
    else row = 128 + (((b * 7 + (s - 1)) * 16 + (lane & 15)) * 16 + c);
    float v = 0.f;
#pragma unroll
    for (int t = 0; t < NLT; t++) v += Lpart[(size_t)t * Mtot + row];
    v += b2;
    if (lane < 16) out[(size_t)(b * NST + s) * An + lane] = v;
    float bv = (lane < 16) ? v : -1e30f;
    int bi = (lane < 16) ? lane : 999;
#pragma unroll
    for (int off = 1; off < 16; off <<= 1) {
      float ov = __shfl_xor(bv, off);
      int oi = __shfl_xor(bi, off);
      if (ov > bv || (ov == bv && oi < bi)) { bv = ov; bi = oi; }
    }
    c = __shfl(bi, 0);
  }
}

// ---------------------------------------------------------------------------
static inline void mm2(const us* Ah, const us* Al, int lda, const us* Bh, const us* Bl,
                       const float* bias, const float* bias2, int nsplit,
                       float* Cf, int ldc, us* Ch, us* Cl, int ldch,
                       int M, int N, int K, int relu, hipStream_t st) {
  dim3 g(N / 64, M / 64);
  mfma_nt<<<g, 256, 0, st>>>(Ah, Al, lda, Bh, Bl, bias, bias2, nsplit,
                             Cf, ldc, Ch, Cl, ldch, K, relu);
}
static inline void mm(const us* Ah, const us* Al, int lda, const us* Bh, const us* Bl,
                      const float* bias, float* Cf, int ldc, us* Ch, us* Cl, int ldch,
                      int M, int N, int K, int relu, hipStream_t st) {
  mm2(Ah, Al, lda, Bh, Bl, bias, bias, 1 << 30, Cf, ldc, Ch, Cl, ldch, M, N, K, relu, st);
}
static inline void sgemm(const float* A, const float* W, const float* bias, float* C,
                         int M, int N, int K, int lda, int ldc, int relu, hipStream_t st) {
  dim3 g((N + 63) / 64, (M + 63) / 64);
  gemm_s<<<g, 256, 0, st>>>(A, W, bias, C, M, N, K, lda, ldc, relu);
}
static inline void split(const float* x, us* h, us* l, int n, hipStream_t st) {
  int n4 = n >> 2;
  int blocks = (n4 + 255) / 256;
  if (blocks > 2048) blocks = 2048;
  split_k<<<blocks, 256, 0, st>>>(x, h, l, n4);
}
static inline Sub mksub(const us* Ah, const us* Al, const us* Bh, const us* Bl,
                        const float* bias, float* Cf, us* Ch, us* Cl,
                        int lda, int ldc, int ldch, int Nt) {
  Sub s; s.Ah = Ah; s.Al = Al; s.Bh = Bh; s.Bl = Bl; s.bias = bias;
  s.Cf = Cf; s.Ch = Ch; s.Cl = Cl; s.lda = lda; s.ldc = ldc; s.ldch = ldch; s.Nt = Nt;
  return s;
}

extern "C" void kernel_launch(void* const* d_in, const int* in_sizes, int n_in,
                              void* d_out, int out_size, void* d_ws, size_t ws_size,
                              hipStream_t stream) {
  const float* video     = (const float*)d_in[0];
  const float* script    = (const float*)d_in[1];
  const float* question  = (const float*)d_in[2];
  const float* a_texts   = (const float*)d_in[3];
  const float* a_buttons = (const float*)d_in[4];
  const float* v_w1 = (const float*)d_in[5];
  const float* v_b1 = (const float*)d_in[6];
  const float* v_w2 = (const float*)d_in[7];
  const float* v_b2 = (const float*)d_in[8];
  const float* t_w1 = (const float*)d_in[9];
  const float* t_b1 = (const float*)d_in[10];
  const float* t_w2 = (const float*)d_in[11];
  const float* t_b2 = (const float*)d_in[12];
  const float* pre_w1 = (const float*)d_in[13];
  const float* pre_b1 = (const float*)d_in[14];
  const float* pre_w2 = (const float*)d_in[15];
  const float* pre_b2 = (const float*)d_in[16];
  const float* s2v_win  = (const float*)d_in[17];
  const float* s2v_bin  = (const float*)d_in[18];
  const float* s2v_wout = (const float*)d_in[19];
  const float* s2v_bout = (const float*)d_in[20];
  const float* qa_win  = (const float*)d_in[21];
  const float* qa_bin  = (const float*)d_in[22];
  const float* qa_wout = (const float*)d_in[23];
  const float* qa_bout = (const float*)d_in[24];
  const float* gru_wih = (const float*)d_in[25];
  const float* gru_whh = (const float*)d_in[26];
  const float* gru_bih = (const float*)d_in[27];
  const float* gru_bhh = (const float*)d_in[28];
  const float* proj_w1 = (const float*)d_in[29];
  const float* proj_b1 = (const float*)d_in[30];
  const float* proj_w2 = (const float*)d_in[31];
  const float* proj_b2 = (const float*)d_in[32];
  const float* state0  = (const float*)d_in[33];
  (void)in_sizes; (void)n_in; (void)out_size; (void)ws_size;

  constexpr int W589  = 768 * 768;
  constexpr int W1769 = 2304 * 768;
  constexpr int W9437 = 3072 * 3072;
  constexpr int W2359 = 768 * 3072;
  constexpr int SMe   = 1024 * 768;
  constexpr int BIGe  = 4096 * 768;

  char* base = (char*)d_ws;
  char* RW1 = base;                   // 9,437,184 : phase-A weights -> gABall(head)
  char* RW2 = RW1 + 9437184;          // 9,437,184 : s2v/qa/pre_w2 weights -> gABall(tail)
  char* R1  = RW2 + 9437184;          // 28,311,552
  char* R2  = R1 + 28311552;          // 12,582,912
  char* X   = R2 + 12582912;          // 25,165,824
  char* P   = X + 25165824;           // abin + Hh/Hl tail overlap
  char* P2  = P + 6815744;            // persistents

  // RW1
  us* vw1h = (us*)RW1;        us* vw1l = vw1h + W589;
  us* vw2h = vw1l + W589;     us* vw2l = vw2h + W589;
  us* tw1h = vw2l + W589;     us* tw1l = tw1h + W589;
  us* tw2h = tw1l + W589;     us* tw2l = tw2h + W589;
  // RW2
  us* s2vwh = (us*)RW2;       us* s2vwl = s2vwh + W1769;
  us* s2voh = s2vwl + W1769;  us* s2vol = s2voh + W589;
  us* qawh  = (us*)RW2;       us* qawl  = qawh + W1769;
  us* qaoh  = qawl + W1769;   us* qaol  = qaoh + W589;
  us* pw2h  = (us*)RW2;       us* pw2l  = pw2h + W2359;
  float* gABall = (float*)RW1;          // [1024 x 4608] f32, spans RW1+RW2
  // R1: video path (phase A), then kvproj/qproj, then kv2/qp2/S2, then weights
  us* vidh = (us*)R1;         us* vidl = vidh + BIGe;      // R1[0..12.6MB)
  us* hidh = vidl + BIGe;     us* hidl = hidh + BIGe;      // R1[12.6..25.2MB)
  float* kvproj = (float*)R1;                              // 4096x1536 f32
  float* qproj  = kvproj + (size_t)4096 * 1536;            // R1+25.2MB, 3MB
  float* kv2 = (float*)R1;
  float* qp2 = (float*)(R1 + 6291456);
  float* S2  = (float*)(R1 + 9437184);
  us* pw1h = (us*)R1;         us* pw1l = pw1h + W9437;     // spans into R2
  us* gwALLh = (us*)R1;                                    // [4608x768]
  us* gwALLl = (us*)(R1 + 7077888);
  us* pjw1h  = (us*)(R1 + 14155776); us* pjw1l = pjw1h + W589;
  // R2
  us* vh = (us*)R2;           us* vl = vh + BIGe;
  us* aoh = (us*)(R2 + 3145728); us* aol = aoh + SMe;
  us* Hh = (us*)R2;           us* Hl = Hh + (size_t)Mtot * Dd;  // spans R2+X+P
  // X: phase-A script/ab temporaries (dead before S1), then S1/cat/preh
  us* inTh  = (us*)X;             us* inTl  = inTh + 2 * SMe;    // X[0..6.3MB)
  us* hid2h = (us*)(X + 6291456); us* hid2l = hid2h + 2 * SMe;   // X[6.3..12.6MB)
  us* abh1h = (us*)(X + 12582912); us* abh1l = abh1h + SMe;      // X[12.6..15.7MB)
  float* S1 = (float*)X;
  us* cath = (us*)X;          us* catl = cath + (size_t)1024 * DPn;
  us* prehh = (us*)(X + 12582912); us* prehl = prehh + (size_t)1024 * DPn;
  // P (overwritten by Hl tail after abin dead)
  us* abinh = (us*)P;         us* abinl = abinh + SMe;
  // P2 persistents
  us* sc2h   = (us*)P2;                       // 2048x768 split (script|a_texts)
  us* sc2l   = sc2h + 2 * SMe;
  float* scat_f = (float*)(P2 + 6291456);     // 2048x768 f32
  float* vatt   = (float*)(P2 + 12582912);
  float* inps_f = (float*)(P2 + 15728640);
  us* inpsh = (us*)(P2 + 18874368); us* inpsl = inpsh + SMe;
  float* qf    = (float*)(P2 + 22020096);
  float* qhid  = (float*)(P2 + 22044672);
  float* gh0   = (float*)(P2 + 22069248);
  float* Lpart = (float*)(P2 + 22085632);     // NLT x 14464 f32
  float* at_f  = scat_f + (size_t)1024 * Dd;  // rows 1024..2047
  us* sch = sc2h;  us* scl = sc2l;            // rows 0..1023
  // ab2 temp borrows inpsh slot (inps written only at pre2, after cat_fill)
  us* ab2h  = (us*)(P2 + 18874368); us* ab2l  = ab2h + SMe;

  // ---- phase A: weight splits + input splits ----
  split4_k<<<dim3(1024, 4), 256, 0, stream>>>(v_w1, vw1h, vw1l, W589,
                                              v_w2, vw2h, vw2l, W589,
                                              t_w1, tw1h, tw1l, W589,
                                              t_w2, tw2h, tw2l, W589);
  split(video, vidh, vidl, BIGe, stream);
  split4_k<<<dim3(1024, 3), 256, 0, stream>>>(script, inTh, inTl, SMe,
                                              a_texts, inTh + SMe, inTl + SMe, SMe,
                                              a_buttons, abinh, abinl, SMe,
                                              nullptr, nullptr, nullptr, 0);
  // B1: video-mm1 (64yt) + scat-mm1 (32yt) + ab-mm1 (16yt), all N=768 K=768 relu
  {
    Sub sv = mksub(vidh, vidl, vw1h, vw1l, v_b1, nullptr, hidh, hidl, Dd, 0, Dd, 12);
    Sub ss = mksub(inTh, inTl, tw1h, tw1l, t_b1, nullptr, hid2h, hid2l, Dd, 0, Dd, 12);
    Sub sa = mksub(abinh, abinl, vw1h, vw1l, v_b1, nullptr, abh1h, abh1l, Dd, 0, Dd, 12);
    mfma_ntb<<<dim3(12, 112), 256, 0, stream>>>(sv, ss, sa, 64, 96, Dd, 1);
  }
  sgemm(question, t_w1, t_b1, qhid, Bn, Dd, Dd, Dd, Dd, 1, stream);
  sgemm(qhid, t_w2, t_b2, qf, Bn, Dd, Dd, Dd, Dd, 0, stream);
  // B2: video-mm2 + scat-mm2 (+f32) + ab-mm2
  {
    Sub sv = mksub(hidh, hidl, vw2h, vw2l, v_b2, nullptr, vh, vl, Dd, 0, Dd, 12);
    Sub ss = mksub(hid2h, hid2l, tw2h, tw2l, t_b2, scat_f, sc2h, sc2l, Dd, Dd, Dd, 12);
    Sub sa = mksub(abh1h, abh1l, vw2h, vw2l, v_b2, nullptr, ab2h, ab2l, Dd, 0, Dd, 12);
    mfma_ntb<<<dim3(12, 112), 256, 0, stream>>>(sv, ss, sa, 64, 96, Dd, 0);
  }

  // ---- s2v attention (K/V merged: N=1536) ----
  split4_k<<<dim3(1024, 2), 256, 0, stream>>>(s2v_win, s2vwh, s2vwl, W1769,
                                              s2v_wout, s2voh, s2vol, W589,
                                              nullptr, nullptr, nullptr, 0,
                                              nullptr, nullptr, nullptr, 0);
  // B3: kvproj (64yt, Nt24) + qproj (16yt, Nt12)
  {
    Sub sk = mksub(vh, vl, s2vwh + (size_t)Dd * Dd, s2vwl + (size_t)Dd * Dd,
                   s2v_bin + Dd, kvproj, nullptr, nullptr, Dd, 1536, 0, 24);
    Sub sq = mksub(sch, scl, s2vwh, s2vwl, s2v_bin, qproj, nullptr, nullptr,
                   Dd, Dd, 0, 12);
    mfma_ntb<<<dim3(24, 80), 256, 0, stream>>>(sk, sq, sq, 64, 80, Dd, 0);
  }
  att_qk<<<dim3(Bn * NH, TSn / 32, TVn / 64), 256, 0, stream>>>(qproj, kvproj, S1,
                                                                TSn, TVn, 1, 1536, 0.125f);
  softmax_rows<<<Bn * NH * TSn, 256, 0, stream>>>(S1, TVn);
  att_pv<<<dim3(Bn * NH, TSn / 32), 256, 0, stream>>>(S1, kvproj + Dd, aoh, aol,
                                                      TSn, TVn, 1, 1536);

  // ---- phase B: cat assembly + qa attention ----
  split(qa_win, qawh, qawl, W1769, stream);          // overwrites s2vw (dead)
  cat_fill<<<(1024 * Dd + 255) / 256, 256, 0, stream>>>(qf, at_f, ab2h, ab2l,
                                                        cath, catl);
  // B4: vatt-out (16yt) + qp2 (16yt) + kv2 (16yt, Nt24)
  {
    Sub svat = mksub(aoh, aol, s2voh, s2vol, s2v_bout, vatt, nullptr, nullptr,
                     Dd, Dd, 0, 12);
    Sub sqp = mksub(cath + 2 * Dd, catl + 2 * Dd, qawh, qawl, qa_bin,
                    qp2, nullptr, nullptr, DPn, Dd, 0, 12);
    Sub skv = mksub(sch, scl, qawh + (size_t)Dd * Dd, qawl + (size_t)Dd * Dd,
                    qa_bin + Dd, kv2, nullptr, nullptr, Dd, 1536, 0, 24);
    mfma_ntb<<<dim3(24, 48), 256, 0, stream>>>(svat, sqp, skv, 16, 32, Dd, 0);
  }
  split(qa_wout, qaoh, qaol, W589, stream);          // overwrites s2vo (dead)
  att_qk<<<dim3(Bn * NST * NH, 1, TSn / 64), 256, 0, stream>>>(qp2, kv2, S2,
                                                               An, TSn, NST, 1536, 0.125f);
  softmax_rows<<<Bn * NST * NH * An, 256, 0, stream>>>(S2, TSn);
  att_pv<<<dim3(Bn * NST * NH, 1), 256, 0, stream>>>(S2, kv2 + Dd, aoh, aol,
                                                     An, TSn, NST, 1536);
  mm(aoh, aol, Dd, qaoh, qaol, qa_bout, nullptr, 0, cath + Dd, catl + Dd, DPn,
     1024, Dd, Dd, 0, stream);
  qv2_k<<<1024, 256, 0, stream>>>(S2, vatt, cath, catl);

  // ---- pre-MLP + merged GRU gates ----
  split(pre_w1, pw1h, pw1l, W9437, stream);
  mm(cath, catl, DPn, pw1h, pw1l, pre_b1, nullptr, 0, prehh, prehl, DPn,
     1024, DPn, DPn, 1, stream);
  split4_k<<<dim3(1024, 4), 256, 0, stream>>>(pre_w2, pw2h, pw2l, W2359,
                                              gru_wih, gwALLh, gwALLl, W1769,
                                              gru_whh, gwALLh + W1769, gwALLl + W1769, W1769,
                                              proj_w1, pjw1h, pjw1l, W589);
  mm(prehh, prehl, DPn, pw2h, pw2l, pre_b2, inps_f, Dd, inpsh, inpsl, Dd,
     1024, Dd, DPn, 0, stream);
  mm2(inpsh, inpsl, Dd, gwALLh, gwALLl, gru_bih, gru_bhh, GSn,
      gABall, 4608, nullptr, nullptr, 0, 1024, 4608, Dd, 0, stream);
  sgemm(state0, gru_whh, gru_bhh, gh0, 1, GSn, Dd, Dd, GSn, 0, stream);

  // ---- candidate enumeration + logits + argmax chain ----
  combine_all<<<(Mtot * (Dd / 4) + 255) / 256, 256, 0, stream>>>(gABall, gh0, inps_f,
                                                                 state0, Hh, Hl);
  mfma_logit128<<<dim3(NLT, Mtot / 128), 256, 0, stream>>>(Hh, Hl, pjw1h, pjw1l,
                                                           proj_b1, proj_w2, Lpart);
  pick_k<<<Bn, 64, 0, stream>>>(Lpart, proj_b2, (float*)d_out);
}

// Round 7
// 1092.091 us; speedup vs baseline: 1.0412x; 1.0175x over previous
//
#include <hip/hip_runtime.h>
#include <hip/hip_bf16.h>
#include <math.h>

constexpr int Dd  = 768;
constexpr int NH  = 12;
constexpr int DHd = 64;
constexpr int Bn  = 8;
constexpr int TVn = 512;
constexpr int TSn = 128;
constexpr int NST = 8;
constexpr int An  = 16;
constexpr int DPn = 3072;
constexpr int GSn = 2304;
constexpr int Mtot = 14464;   // 128 (s=0) + 8*7*16*16 candidate rows; 113*128
constexpr int NLT = 6;        // logit n-tiles at 128-wide tiling (768/128)

typedef unsigned short us;
using short8   = __attribute__((ext_vector_type(8))) short;
using floatx16 = __attribute__((ext_vector_type(16))) float;

typedef __attribute__((address_space(1))) const unsigned char glb_b;
typedef __attribute__((address_space(3))) unsigned char lds_b;

// async global->LDS DMA, 16B per lane, dest = lptr + lane*16 (HW-linear)
__device__ inline void gload16(const void* g, void* l) {
  __builtin_amdgcn_global_load_lds((glb_b*)g, (lds_b*)l, 16, 0, 0);
}

__device__ inline us f2bf(float x) {
  union { float f; unsigned u; } a; a.f = x;
  return (us)((a.u + 0x7fffu + ((a.u >> 16) & 1u)) >> 16);
}
__device__ inline float bf2f(us h) {
  union { unsigned u; float f; } a; a.u = ((unsigned)h) << 16;
  return a.f;
}

// ---------------------------------------------------------------------------
// splits (float4-vectorized)
// ---------------------------------------------------------------------------
__global__ void split_k(const float* __restrict__ x, us* __restrict__ h,
                        us* __restrict__ l, int n4) {
  for (int i = blockIdx.x * 256 + threadIdx.x; i < n4; i += gridDim.x * 256) {
    float4 v = ((const float4*)x)[i];
    float vv[4] = {v.x, v.y, v.z, v.w};
    union { us u[4]; uint2 w; } hh, ll;
#pragma unroll
    for (int t = 0; t < 4; t++) {
      us hb = f2bf(vv[t]);
      hh.u[t] = hb;
      ll.u[t] = f2bf(vv[t] - bf2f(hb));
    }
    ((uint2*)h)[i] = hh.w;
    ((uint2*)l)[i] = ll.w;
  }
}

__global__ void split4_k(const float* s0, us* h0, us* l0, int n0,
                         const float* s1, us* h1, us* l1, int n1,
                         const float* s2, us* h2, us* l2, int n2,
                         const float* s3, us* h3, us* l3, int n3) {
  const float* s; us* h; us* l; int n;
  switch (blockIdx.y) {
    case 0: s = s0; h = h0; l = l0; n = n0; break;
    case 1: s = s1; h = h1; l = l1; n = n1; break;
    case 2: s = s2; h = h2; l = l2; n = n2; break;
    default: s = s3; h = h3; l = l3; n = n3; break;
  }
  int n4 = n >> 2;
  for (int i = blockIdx.x * 256 + threadIdx.x; i < n4; i += gridDim.x * 256) {
    float4 v = ((const float4*)s)[i];
    float vv[4] = {v.x, v.y, v.z, v.w};
    union { us u[4]; uint2 w; } hh, ll;
#pragma unroll
    for (int t = 0; t < 4; t++) {
      us hb = f2bf(vv[t]);
      hh.u[t] = hb;
      ll.u[t] = f2bf(vv[t] - bf2f(hb));
    }
    ((uint2*)h)[i] = hh.w;
    ((uint2*)l)[i] = ll.w;
  }
}

__device__ inline short8 lds8(const us* p) {
  const uint2* q = (const uint2*)p;
  uint2 a = q[0], b = q[1];
  union { unsigned u[4]; short8 v; } t;
  t.u[0] = a.x; t.u[1] = a.y; t.u[2] = b.x; t.u[3] = b.y;
  return t.v;
}

// ---------------------------------------------------------------------------
// bf16x3 MFMA NT GEMM — 64x64 tile, 4 waves, 3 acc chains, dbuf LDS,
// 1 barrier/iter. Staging via global_load_lds (16B/lane DMA, no VGPR
// round-trip, conflict-free linear writes). Pad-free [64][32] rows with
// slot-swizzle phys = slot ^ ((row>>1)&3); swizzle realized on the GLOBAL
// source address, LDS dest linear.
// ---------------------------------------------------------------------------
__global__ __launch_bounds__(256) void mfma_nt(
    const us* __restrict__ Ah, const us* __restrict__ Al, int lda,
    const us* __restrict__ Bh, const us* __restrict__ Bl,
    const float* __restrict__ bias, const float* __restrict__ bias2, int nsplit,
    float* __restrict__ Cf, int ldc,
    us* __restrict__ Ch, us* __restrict__ Cl, int ldch,
    int K, int relu) {
  __shared__ us Ash[2][64][32], Asl[2][64][32], Bsh[2][64][32], Bsl[2][64][32];
  const int tid = threadIdx.x;
  const int bm = blockIdx.y * 64, bn = blockIdx.x * 64;
  const int wave = tid >> 6, lane = tid & 63;
  const int mh = (wave & 1) * 32, nh = (wave >> 1) * 32;
  const int l31 = lane & 31, hi5 = lane >> 5;
  const int srow = tid >> 2;
  const int scol = (((tid & 3) ^ ((tid >> 3) & 3)) << 3);   // swizzled src col
  const int rc2 = (l31 >> 1) & 3;                           // read swizzle key
  const int wb = wave * 16;
  const us* pAh = Ah + (size_t)(bm + srow) * lda + scol;
  const us* pAl = Al + (size_t)(bm + srow) * lda + scol;
  const us* pBh = Bh + (size_t)(bn + srow) * K + scol;
  const us* pBl = Bl + (size_t)(bn + srow) * K + scol;

  floatx16 acc_hh, acc_hl, acc_lh;
#pragma unroll
  for (int i = 0; i < 16; i++) { acc_hh[i] = 0.f; acc_hl[i] = 0.f; acc_lh[i] = 0.f; }

  const int iters = K >> 5;
  gload16(pAh, &Ash[0][wb][0]);
  gload16(pAl, &Asl[0][wb][0]);
  gload16(pBh, &Bsh[0][wb][0]);
  gload16(pBl, &Bsl[0][wb][0]);
  int p = 0;
  for (int it = 0; it < iters; ++it) {
    __syncthreads();                       // drains DMA: buf[p] resident
    if (it + 1 < iters) {
      int ko = (it + 1) * 32;
      gload16(pAh + ko, &Ash[p ^ 1][wb][0]);
      gload16(pAl + ko, &Asl[p ^ 1][wb][0]);
      gload16(pBh + ko, &Bsh[p ^ 1][wb][0]);
      gload16(pBl + ko, &Bsl[p ^ 1][wb][0]);
    }
#pragma unroll
    for (int ks = 0; ks < 32; ks += 16) {
      int col = ((((ks >> 3) + hi5) ^ rc2) << 3);
      short8 fa_h = lds8(&Ash[p][mh + l31][col]);
      short8 fa_l = lds8(&Asl[p][mh + l31][col]);
      short8 fb_h = lds8(&Bsh[p][nh + l31][col]);
      short8 fb_l = lds8(&Bsl[p][nh + l31][col]);
      acc_hh = __builtin_amdgcn_mfma_f32_32x32x16_bf16(fa_h, fb_h, acc_hh, 0, 0, 0);
      acc_hl = __builtin_amdgcn_mfma_f32_32x32x16_bf16(fa_h, fb_l, acc_hl, 0, 0, 0);
      acc_lh = __builtin_amdgcn_mfma_f32_32x32x16_bf16(fa_l, fb_h, acc_lh, 0, 0, 0);
    }
    p ^= 1;
  }
  int n = bn + nh + l31;
  float bv = (n < nsplit) ? bias[n] : bias2[n - nsplit];
#pragma unroll
  for (int r = 0; r < 16; r++) {
    int m = bm + mh + (r & 3) + 8 * (r >> 2) + 4 * hi5;
    float v = acc_hh[r] + acc_hl[r] + acc_lh[r] + bv;
    if (relu) v = fmaxf(v, 0.f);
    if (Cf) Cf[(size_t)m * ldc + n] = v;
    if (Ch) {
      us hb = f2bf(v);
      Ch[(size_t)m * ldch + n] = hb;
      Cl[(size_t)m * ldch + n] = f2bf(v - bf2f(hb));
    }
  }
}

// ---------------------------------------------------------------------------
// Batched variant: up to 3 sub-GEMMs share one launch (y-tile ranges).
// Same gload_lds/swizzle body.
// ---------------------------------------------------------------------------
struct Sub {
  const us* Ah; const us* Al; const us* Bh; const us* Bl;
  const float* bias; float* Cf; us* Ch; us* Cl;
  int lda, ldc, ldch, Nt;
};

__global__ __launch_bounds__(256) void mfma_ntb(Sub s0, Sub s1, Sub s2,
                                                int c1, int c2, int K, int relu) {
  Sub s; int yt = blockIdx.y;
  if (yt < c1) { s = s0; }
  else if (yt < c2) { s = s1; yt -= c1; }
  else { s = s2; yt -= c2; }
  if ((int)blockIdx.x >= s.Nt) return;
  __shared__ us Ash[2][64][32], Asl[2][64][32], Bsh[2][64][32], Bsl[2][64][32];
  const int tid = threadIdx.x;
  const int bm = yt * 64, bn = blockIdx.x * 64;
  const int wave = tid >> 6, lane = tid & 63;
  const int mh = (wave & 1) * 32, nh = (wave >> 1) * 32;
  const int l31 = lane & 31, hi5 = lane >> 5;
  const int srow = tid >> 2;
  const int scol = (((tid & 3) ^ ((tid >> 3) & 3)) << 3);
  const int rc2 = (l31 >> 1) & 3;
  const int wb = wave * 16;
  const us* pAh = s.Ah + (size_t)(bm + srow) * s.lda + scol;
  const us* pAl = s.Al + (size_t)(bm + srow) * s.lda + scol;
  const us* pBh = s.Bh + (size_t)(bn + srow) * K + scol;
  const us* pBl = s.Bl + (size_t)(bn + srow) * K + scol;

  floatx16 acc_hh, acc_hl, acc_lh;
#pragma unroll
  for (int i = 0; i < 16; i++) { acc_hh[i] = 0.f; acc_hl[i] = 0.f; acc_lh[i] = 0.f; }

  const int iters = K >> 5;
  gload16(pAh, &Ash[0][wb][0]);
  gload16(pAl, &Asl[0][wb][0]);
  gload16(pBh, &Bsh[0][wb][0]);
  gload16(pBl, &Bsl[0][wb][0]);
  int p = 0;
  for (int it = 0; it < iters; ++it) {
    __syncthreads();
    if (it + 1 < iters) {
      int ko = (it + 1) * 32;
      gload16(pAh + ko, &Ash[p ^ 1][wb][0]);
      gload16(pAl + ko, &Asl[p ^ 1][wb][0]);
      gload16(pBh + ko, &Bsh[p ^ 1][wb][0]);
      gload16(pBl + ko, &Bsl[p ^ 1][wb][0]);
    }
#pragma unroll
    for (int ks = 0; ks < 32; ks += 16) {
      int col = ((((ks >> 3) + hi5) ^ rc2) << 3);
      short8 fa_h = lds8(&Ash[p][mh + l31][col]);
      short8 fa_l = lds8(&Asl[p][mh + l31][col]);
      short8 fb_h = lds8(&Bsh[p][nh + l31][col]);
      short8 fb_l = lds8(&Bsl[p][nh + l31][col]);
      acc_hh = __builtin_amdgcn_mfma_f32_32x32x16_bf16(fa_h, fb_h, acc_hh, 0, 0, 0);
      acc_hl = __builtin_amdgcn_mfma_f32_32x32x16_bf16(fa_h, fb_l, acc_hl, 0, 0, 0);
      acc_lh = __builtin_amdgcn_mfma_f32_32x32x16_bf16(fa_l, fb_h, acc_lh, 0, 0, 0);
    }
    p ^= 1;
  }
  int n = bn + nh + l31;
  float bv = s.bias[n];
#pragma unroll
  for (int r = 0; r < 16; r++) {
    int m = bm + mh + (r & 3) + 8 * (r >> 2) + 4 * hi5;
    float v = acc_hh[r] + acc_hl[r] + acc_lh[r] + bv;
    if (relu) v = fmaxf(v, 0.f);
    if (s.Cf) s.Cf[(size_t)m * s.ldc + n] = v;
    if (s.Ch) {
      us hb = f2bf(v);
      s.Ch[(size_t)m * s.ldch + n] = hb;
      s.Cl[(size_t)m * s.ldch + n] = f2bf(v - bf2f(hb));
    }
  }
}

// ---------------------------------------------------------------------------
// logit GEMM, 128x128 tile (678 blocks), gload_lds staging. XCD-aware
// bijective chunked swizzle (m204): each XCD owns ~14 consecutive m-tiles
// WITH all 6 n-tiles -> A-slice fetched into one L2, reused 6x (R6 PMC:
// FETCH 141MB = 3.2x A size, dispatch round-robin spread same-A blocks
// across XCDs). Cross chains share one accumulator. Epilogue:
// relu(acc+b1[n])*w2[n] reduced over 128-col n-tile -> Lpart[ntile][m].
// ---------------------------------------------------------------------------
__global__ __launch_bounds__(256, 2) void mfma_logit128(
    const us* __restrict__ Ah, const us* __restrict__ Al,
    const us* __restrict__ Bh, const us* __restrict__ Bl,
    const float* __restrict__ bias1, const float* __restrict__ w2,
    float* __restrict__ Lpart) {
  __shared__ us Ash[2][128][32], Asl[2][128][32], Bsh[2][128][32], Bsl[2][128][32];
  __shared__ float lpart[128];
  const int K = Dd;
  const int tid = threadIdx.x;
  // XCD swizzle: hardware dispatch id -> chunked position
  const int nwg = NLT * (Mtot / 128);             // 678
  const int lin = blockIdx.y * NLT + blockIdx.x;  // hw dispatch order (x fastest)
  const int xcd = lin & 7, loc = lin >> 3;
  const int q = nwg / 8, r = nwg % 8;             // 84, 6
  const int pos = (xcd < r) ? xcd * (q + 1) + loc
                            : r * (q + 1) + (xcd - r) * q + loc;
  const int bxn = pos % NLT, bym = pos / NLT;
  const int bm = bym * 128, bn = bxn * 128;
  const int wave = tid >> 6, lane = tid & 63;
  const int mh = (wave & 1) * 64, nh = (wave >> 1) * 64;
  const int l31 = lane & 31, hi5 = lane >> 5;
  const int srow = tid >> 2;
  const int scol = (((tid & 3) ^ ((tid >> 3) & 3)) << 3);
  const int rc2 = (l31 >> 1) & 3;
  const int wb = wave * 16;
  const us* pAh = Ah + (size_t)(bm + srow) * K + scol;
  const us* pAl = Al + (size_t)(bm + srow) * K + scol;
  const us* pBh = Bh + (size_t)(bn + srow) * K + scol;
  const us* pBl = Bl + (size_t)(bn + srow) * K + scol;
  const size_t strA = (size_t)64 * K, strB = (size_t)64 * K;
  if (tid < 128) lpart[tid] = 0.f;

  floatx16 acc_hh[2][2], acc_x[2][2];
#pragma unroll
  for (int i = 0; i < 2; i++)
#pragma unroll
    for (int j = 0; j < 2; j++)
#pragma unroll
      for (int rr = 0; rr < 16; rr++) { acc_hh[i][j][rr] = 0.f; acc_x[i][j][rr] = 0.f; }

  const int iters = K >> 5;
  gload16(pAh,        &Ash[0][wb][0]);
  gload16(pAh + strA, &Ash[0][wb + 64][0]);
  gload16(pAl,        &Asl[0][wb][0]);
  gload16(pAl + strA, &Asl[0][wb + 64][0]);
  gload16(pBh,        &Bsh[0][wb][0]);
  gload16(pBh + strB, &Bsh[0][wb + 64][0]);
  gload16(pBl,        &Bsl[0][wb][0]);
  gload16(pBl + strB, &Bsl[0][wb + 64][0]);
  int p = 0;
  for (int it = 0; it < iters; ++it) {
    __syncthreads();
    if (it + 1 < iters) {
      int ko = (it + 1) * 32;
      gload16(pAh + ko,        &Ash[p ^ 1][wb][0]);
      gload16(pAh + strA + ko, &Ash[p ^ 1][wb + 64][0]);
      gload16(pAl + ko,        &Asl[p ^ 1][wb][0]);
      gload16(pAl + strA + ko, &Asl[p ^ 1][wb + 64][0]);
      gload16(pBh + ko,        &Bsh[p ^ 1][wb][0]);
      gload16(pBh + strB + ko, &Bsh[p ^ 1][wb + 64][0]);
      gload16(pBl + ko,        &Bsl[p ^ 1][wb][0]);
      gload16(pBl + strB + ko, &Bsl[p ^ 1][wb + 64][0]);
    }
#pragma unroll
    for (int ks = 0; ks < 32; ks += 16) {
      int col = ((((ks >> 3) + hi5) ^ rc2) << 3);
      short8 fah[2], fal[2], fbh[2], fbl[2];
#pragma unroll
      for (int f = 0; f < 2; f++) {
        fah[f] = lds8(&Ash[p][mh + f * 32 + l31][col]);
        fal[f] = lds8(&Asl[p][mh + f * 32 + l31][col]);
        fbh[f] = lds8(&Bsh[p][nh + f * 32 + l31][col]);
        fbl[f] = lds8(&Bsl[p][nh + f * 32 + l31][col]);
      }
#pragma unroll
      for (int fm = 0; fm < 2; fm++)
#pragma unroll
        for (int fn = 0; fn < 2; fn++) {
          acc_hh[fm][fn] = __builtin_amdgcn_mfma_f32_32x32x16_bf16(fah[fm], fbh[fn], acc_hh[fm][fn], 0, 0, 0);
          acc_x[fm][fn]  = __builtin_amdgcn_mfma_f32_32x32x16_bf16(fah[fm], fbl[fn], acc_x[fm][fn], 0, 0, 0);
          acc_x[fm][fn]  = __builtin_amdgcn_mfma_f32_32x32x16_bf16(fal[fm], fbh[fn], acc_x[fm][fn], 0, 0, 0);
        }
    }
    p ^= 1;
  }
  float b1[2], wn[2];
#pragma unroll
  for (int fn = 0; fn < 2; fn++) {
    int n = bn + nh + fn * 32 + l31;
    b1[fn] = bias1[n];
    wn[fn] = w2[n];
  }
#pragma unroll
  for (int fm = 0; fm < 2; fm++) {
#pragma unroll
    for (int rr = 0; rr < 16; rr++) {
      int mloc = mh + fm * 32 + (rr & 3) + 8 * (rr >> 2) + 4 * hi5;
      float v = 0.f;
#pragma unroll
      for (int fn = 0; fn < 2; fn++) {
        float vv = acc_hh[fm][fn][rr] + acc_x[fm][fn][rr] + b1[fn];
        v += fmaxf(vv, 0.f) * wn[fn];
      }
      v += __shfl_xor(v, 1);
      v += __shfl_xor(v, 2);
      v += __shfl_xor(v, 4);
      v += __shfl_xor(v, 8);
      v += __shfl_xor(v, 16);
      if (l31 == 0) atomicAdd(&lpart[mloc], v);
    }
  }
  __syncthreads();
  if (tid < 128) Lpart[(size_t)bxn * Mtot + bm + tid] = lpart[tid];
}

// ---------------------------------------------------------------------------
// scalar f32 NT GEMM (tiny M: question, gh0)
// ---------------------------------------------------------------------------
__global__ __launch_bounds__(256) void gemm_s(const float* __restrict__ A,
                                              const float* __restrict__ Bw,
                                              const float* __restrict__ bias,
                                              float* __restrict__ C,
                                              int M, int N, int K,
                                              int lda, int ldc, int relu) {
  __shared__ float As[16][65];
  __shared__ float Bs[16][65];
  int bm = blockIdx.y * 64, bn = blockIdx.x * 64;
  int tid = threadIdx.x;
  int tx = tid & 15, ty = tid >> 4;
  float acc[4][4] = {};
  for (int k0 = 0; k0 < K; k0 += 16) {
#pragma unroll
    for (int i = 0; i < 4; i++) {
      int l = tid * 4 + i;
      int row = l >> 4, kk = l & 15;
      float v = 0.f;
      if (bm + row < M) v = A[(size_t)(bm + row) * lda + k0 + kk];
      As[kk][row] = v;
    }
#pragma unroll
    for (int i = 0; i < 4; i++) {
      int l = tid * 4 + i;
      int row = l >> 4, kk = l & 15;
      float v = 0.f;
      if (bn + row < N) v = Bw[(size_t)(bn + row) * K + k0 + kk];
      Bs[kk][row] = v;
    }
    __syncthreads();
#pragma unroll
    for (int kk = 0; kk < 16; kk++) {
      float a4[4], b4[4];
#pragma unroll
      for (int i = 0; i < 4; i++) a4[i] = As[kk][ty * 4 + i];
#pragma unroll
      for (int j = 0; j < 4; j++) b4[j] = Bs[kk][tx * 4 + j];
#pragma unroll
      for (int i = 0; i < 4; i++)
#pragma unroll
        for (int j = 0; j < 4; j++) acc[i][j] += a4[i] * b4[j];
    }
    __syncthreads();
  }
#pragma unroll
  for (int i = 0; i < 4; i++) {
    int m = bm + ty * 4 + i;
    if (m >= M) continue;
#pragma unroll
    for (int j = 0; j < 4; j++) {
      int n = bn + tx * 4 + j;
      if (n >= N) continue;
      float v = acc[i][j] + bias[n];
      if (relu) v = fmaxf(v, 0.f);
      C[(size_t)m * ldc + n] = v;
    }
  }
}

// ---------------------------------------------------------------------------
// attention (f32), float4-vectorized LDS
// ---------------------------------------------------------------------------
__global__ __launch_bounds__(256) void att_qk(const float* __restrict__ qp,
                                              const float* __restrict__ kp,
                                              float* __restrict__ Sout,
                                              int Tq, int Tk, int kdiv, int ldk,
                                              float scale) {
  int g = blockIdx.x;
  int h = g % NH;
  int qrow0 = (g / NH) * Tq;
  int krow0 = (g / (NH * kdiv)) * Tk;
  int q0 = blockIdx.y * 32;
  int k0 = blockIdx.z * 64;
  __shared__ float Qs[32][68];
  __shared__ float KsT[64][72];   // transposed: [d][k]
  int tid = threadIdx.x;
  {
    int row = tid >> 3, db = (tid & 7) * 8;
    int qr = q0 + row;
    float4 v0 = {0, 0, 0, 0}, v1 = {0, 0, 0, 0};
    if (qr < Tq) {
      const float* p = qp + (size_t)(qrow0 + qr) * Dd + h * DHd + db;
      v0 = *(const float4*)p;
      v1 = *(const float4*)(p + 4);
    }
    *(float4*)&Qs[row][db] = v0;
    *(float4*)&Qs[row][db + 4] = v1;
  }
#pragma unroll
  for (int half = 0; half < 2; half++) {
    int row = (tid >> 3) + half * 32, db = (tid & 7) * 8;
    int kr = k0 + row;
    float4 v0 = {0, 0, 0, 0}, v1 = {0, 0, 0, 0};
    if (kr < Tk) {
      const float* p = kp + (size_t)(krow0 + kr) * ldk + h * DHd + db;
      v0 = *(const float4*)p;
      v1 = *(const float4*)(p + 4);
    }
    KsT[db + 0][row] = v0.x; KsT[db + 1][row] = v0.y;
    KsT[db + 2][row] = v0.z; KsT[db + 3][row] = v0.w;
    KsT[db + 4][row] = v1.x; KsT[db + 5][row] = v1.y;
    KsT[db + 6][row] = v1.z; KsT[db + 7][row] = v1.w;
  }
  __syncthreads();
  int q = tid >> 3, kg = tid & 7;
  float acc[8] = {};
  for (int d = 0; d < DHd; d++) {
    float qv = Qs[q][d];
    float4 k0v = *(const float4*)&KsT[d][kg * 8];
    float4 k1v = *(const float4*)&KsT[d][kg * 8 + 4];
    acc[0] += qv * k0v.x; acc[1] += qv * k0v.y;
    acc[2] += qv * k0v.z; acc[3] += qv * k0v.w;
    acc[4] += qv * k1v.x; acc[5] += qv * k1v.y;
    acc[6] += qv * k1v.z; acc[7] += qv * k1v.w;
  }
  if (q0 + q < Tq) {
    size_t basep = ((size_t)g * Tq + q0 + q) * Tk + k0 + kg * 8;
#pragma unroll
    for (int j = 0; j < 8; j++) Sout[basep + j] = acc[j] * scale;
  }
}

// P@V with fused bf16-split output (Outh/Outl)
__global__ __launch_bounds__(256) void att_pv(const float* __restrict__ P,
                                              const float* __restrict__ vp,
                                              us* __restrict__ Outh,
                                              us* __restrict__ Outl,
                                              int Tq, int Tk, int kdiv, int ldv) {
  int g = blockIdx.x;
  int h = g % NH;
  int qrow0 = (g / NH) * Tq;
  int krow0 = (g / (NH * kdiv)) * Tk;
  int q0 = blockIdx.y * 32;
  __shared__ float Ps[32][68];
  __shared__ float Vs[64][72];
  int tid = threadIdx.x;
  int q = tid >> 3, dg = tid & 7;
  float acc[8] = {};
  for (int k0 = 0; k0 < Tk; k0 += 64) {
    {
      int row = tid >> 3, cb = (tid & 7) * 8;
      int qr = q0 + row;
      float4 v0 = {0, 0, 0, 0}, v1 = {0, 0, 0, 0};
      if (qr < Tq) {
        const float* p = P + ((size_t)g * Tq + qr) * Tk + k0 + cb;
        v0 = *(const float4*)p;
        v1 = *(const float4*)(p + 4);
      }
      *(float4*)&Ps[row][cb] = v0;
      *(float4*)&Ps[row][cb + 4] = v1;
    }
#pragma unroll
    for (int half = 0; half < 2; half++) {
      int row = (tid >> 3) + half * 32, db = (tid & 7) * 8;
      const float* p = vp + (size_t)(krow0 + k0 + row) * ldv + h * DHd + db;
      *(float4*)&Vs[row][db] = *(const float4*)p;
      *(float4*)&Vs[row][db + 4] = *(const float4*)(p + 4);
    }
    __syncthreads();
#pragma unroll 4
    for (int kk4 = 0; kk4 < 16; kk4++) {
      float4 pv = *(const float4*)&Ps[q][kk4 * 4];
      float pe[4] = {pv.x, pv.y, pv.z, pv.w};
#pragma unroll
      for (int e = 0; e < 4; e++) {
        int kk = kk4 * 4 + e;
        float4 v0 = *(const float4*)&Vs[kk][dg * 8];
        float4 v1 = *(const float4*)&Vs[kk][dg * 8 + 4];
        acc[0] += pe[e] * v0.x; acc[1] += pe[e] * v0.y;
        acc[2] += pe[e] * v0.z; acc[3] += pe[e] * v0.w;
        acc[4] += pe[e] * v1.x; acc[5] += pe[e] * v1.y;
        acc[6] += pe[e] * v1.z; acc[7] += pe[e] * v1.w;
      }
    }
    __syncthreads();
  }
  if (q0 + q < Tq) {
    size_t basep = (size_t)(qrow0 + q0 + q) * Dd + h * DHd + dg * 8;
    union { us u[8]; uint4 v; } ph, pl;
#pragma unroll
    for (int j = 0; j < 8; j++) {
      us hb = f2bf(acc[j]);
      ph.u[j] = hb;
      pl.u[j] = f2bf(acc[j] - bf2f(hb));
    }
    *(uint4*)&Outh[basep] = ph.v;
    *(uint4*)&Outl[basep] = pl.v;
  }
}

__global__ __launch_bounds__(256) void softmax_rows(float* __restrict__ X, int len) {
  int row = blockIdx.x;
  float* p = X + (size_t)row * len;
  int tid = threadIdx.x;
  __shared__ float red[4];
  __shared__ float red2[4];
  float lmax = -1e30f;
  for (int j = tid; j < len; j += 256) lmax = fmaxf(lmax, p[j]);
  for (int off = 32; off; off >>= 1) lmax = fmaxf(lmax, __shfl_down(lmax, off));
  if ((tid & 63) == 0) red[tid >> 6] = lmax;
  __syncthreads();
  if (tid == 0) red[0] = fmaxf(fmaxf(red[0], red[1]), fmaxf(red[2], red[3]));
  __syncthreads();
  float m = red[0];
  float lsum = 0.f;
  for (int j = tid; j < len; j += 256) {
    float e = expf(p[j] - m);
    p[j] = e;
    lsum += e;
  }
  for (int off = 32; off; off >>= 1) lsum += __shfl_down(lsum, off);
  if ((tid & 63) == 0) red2[tid >> 6] = lsum;
  __syncthreads();
  if (tid == 0) red2[0] = red2[0] + red2[1] + red2[2] + red2[3];
  __syncthreads();
  float inv = 1.f / red2[0];
  for (int j = tid; j < len; j += 256) p[j] *= inv;
}

// fused head-mean + qv = W @ vatt -> cat slice [0,D)
__global__ __launch_bounds__(256) void qv2_k(const float* __restrict__ S2,
                                             const float* __restrict__ vatt,
                                             us* __restrict__ ch, us* __restrict__ cl) {
  int row = blockIdx.x;
  int b = row / (NST * An);
  int bs = row / An;
  int a = row % An;
  __shared__ float wm[TSn];
  int tid = threadIdx.x;
  if (tid < TSn) {
    float acc = 0.f;
    for (int h = 0; h < NH; h++)
      acc += S2[(((size_t)bs * NH + h) * An + a) * TSn + tid];
    wm[tid] = acc * (1.f / NH);
  }
  __syncthreads();
  for (int j = tid; j < Dd; j += 256) {
    float acc = 0.f;
    for (int k = 0; k < TSn; k++)
      acc += wm[k] * vatt[((size_t)b * TSn + k) * Dd + j];
    size_t o = (size_t)row * DPn + j;
    us hb = f2bf(acc);
    ch[o] = hb;
    cl[o] = f2bf(acc - bf2f(hb));
  }
}

// cat slices [2D,3D) = qf[b] + at[row]  and  [3D,4D) = ab2 tmp bit-copy
__global__ void cat_fill(const float* __restrict__ qf, const float* __restrict__ at,
                         const us* __restrict__ ab2h, const us* __restrict__ ab2l,
                         us* __restrict__ ch, us* __restrict__ cl) {
  int idx = blockIdx.x * 256 + threadIdx.x;
  if (idx >= Bn * NST * An * Dd) return;
  int b = idx / (NST * An * Dd);
  int row = idx / Dd;
  int j = idx - row * Dd;
  float v = qf[b * Dd + j] + at[idx];
  size_t o = (size_t)row * DPn + 2 * Dd + j;
  us hb = f2bf(v);
  ch[o] = hb;
  cl[o] = f2bf(v - bf2f(hb));
  size_t o3 = (size_t)row * DPn + 3 * Dd + j;
  ch[o3] = ab2h[idx];
  cl[o3] = ab2l[idx];
}

// ---------------------------------------------------------------------------
// GRU combine for ALL candidate rows. gABall [1024 x 4608]: cols [0,2304) =
// x-gates (wih), cols [2304,4608) = h-gates (whh). Pre-split bf16 output.
// Row layout: [0,128): s=0 rows (b,a). [128,Mtot): 128+(((b*7+s-1)*16+a)*16+c).
// ---------------------------------------------------------------------------
__global__ void combine_all(const float* __restrict__ gABall,
                            const float* __restrict__ gh0,
                            const float* __restrict__ inps,
                            const float* __restrict__ state0,
                            us* __restrict__ Hh, us* __restrict__ Hl) {
  const int D4 = Dd / 4;
  const int LDG = 4608;
  int idx = blockIdx.x * 256 + threadIdx.x;
  if (idx >= Mtot * D4) return;
  int row = idx / D4, j = (idx - row * D4) * 4;
  const float* gp;
  const float* ghp;
  const float* stp;
  if (row < 128) {
    int b = row >> 4, a = row & 15;
    gp = gABall + ((size_t)(b * NST) * An + a) * LDG;
    ghp = gh0;
    stp = state0;
  } else {
    int r = row - 128;
    int c = r & 15; r >>= 4;
    int a = r & 15; r >>= 4;
    int sm1 = r % 7, b = r / 7;
    size_t prev = (size_t)(b * NST + sm1) * An + c;
    gp = gABall + ((size_t)(b * NST + sm1 + 1) * An + a) * LDG;
    ghp = gABall + prev * LDG + GSn;
    stp = inps + prev * Dd;
  }
  float4 ir4 = *(const float4*)(gp + j);
  float4 iz4 = *(const float4*)(gp + Dd + j);
  float4 in4 = *(const float4*)(gp + 2 * Dd + j);
  float4 hr4 = *(const float4*)(ghp + j);
  float4 hz4 = *(const float4*)(ghp + Dd + j);
  float4 hn4 = *(const float4*)(ghp + 2 * Dd + j);
  float4 st4 = *(const float4*)(stp + j);
  float ir[4] = {ir4.x, ir4.y, ir4.z, ir4.w};
  float iz[4] = {iz4.x, iz4.y, iz4.z, iz4.w};
  float in_[4] = {in4.x, in4.y, in4.z, in4.w};
  float hr[4] = {hr4.x, hr4.y, hr4.z, hr4.w};
  float hz[4] = {hz4.x, hz4.y, hz4.z, hz4.w};
  float hn[4] = {hn4.x, hn4.y, hn4.z, hn4.w};
  float st[4] = {st4.x, st4.y, st4.z, st4.w};
  union { us u[4]; uint2 w; } oh, ol;
#pragma unroll
  for (int t = 0; t < 4; t++) {
    float rg = 1.f / (1.f + expf(-(ir[t] + hr[t])));
    float zg = 1.f / (1.f + expf(-(iz[t] + hz[t])));
    float ng = tanhf(in_[t] + rg * hn[t]);
    float v = (1.f - zg) * ng + zg * st[t];
    us hb = f2bf(v);
    oh.u[t] = hb;
    ol.u[t] = f2bf(v - bf2f(hb));
  }
  *(uint2*)&Hh[(size_t)row * Dd + j] = oh.w;
  *(uint2*)&Hl[(size_t)row * Dd + j] = ol.w;
}

// ---------------------------------------------------------------------------
// pick: walk the argmax chain over logit partials (NLT n-tiles).
// ---------------------------------------------------------------------------
__global__ __launch_bounds__(64) void pick_k(const float* __restrict__ Lpart,
                                             const float* __restrict__ b2v,
                                             float* __restrict__ out) {
  int b = blockIdx.x;
  int lane = threadIdx.x;
  int c = 0;
  float b2 = b2v[0];
  for (int s = 0; s < NST; s++) {
    int row;
    if (s == 0) row = b * 16 + (lane & 15);
    else row = 128 + (((b * 7 + (s - 1)) * 16 + (lane & 15)) * 16 + c);
    float v = 0.f;
#pragma unroll
    for (int t = 0; t < NLT; t++) v += Lpart[(size_t)t * Mtot + row];
    v += b2;
    if (lane < 16) out[(size_t)(b * NST + s) * An + lane] = v;
    float bv = (lane < 16) ? v : -1e30f;
    int bi = (lane < 16) ? lane : 999;
#pragma unroll
    for (int off = 1; off < 16; off <<= 1) {
      float ov = __shfl_xor(bv, off);
      int oi = __shfl_xor(bi, off);
      if (ov > bv || (ov == bv && oi < bi)) { bv = ov; bi = oi; }
    }
    c = __shfl(bi, 0);
  }
}

// ---------------------------------------------------------------------------
static inline void mm2(const us* Ah, const us* Al, int lda, const us* Bh, const us* Bl,
                       const float* bias, const float* bias2, int nsplit,
                       float* Cf, int ldc, us* Ch, us* Cl, int ldch,
                       int M, int N, int K, int relu, hipStream_t st) {
  dim3 g(N / 64, M / 64);
  mfma_nt<<<g, 256, 0, st>>>(Ah, Al, lda, Bh, Bl, bias, bias2, nsplit,
                             Cf, ldc, Ch, Cl, ldch, K, relu);
}
static inline void mm(const us* Ah, const us* Al, int lda, const us* Bh, const us* Bl,
                      const float* bias, float* Cf, int ldc, us* Ch, us* Cl, int ldch,
                      int M, int N, int K, int relu, hipStream_t st) {
  mm2(Ah, Al, lda, Bh, Bl, bias, bias, 1 << 30, Cf, ldc, Ch, Cl, ldch, M, N, K, relu, st);
}
static inline void sgemm(const float* A, const float* W, const float* bias, float* C,
                         int M, int N, int K, int lda, int ldc, int relu, hipStream_t st) {
  dim3 g((N + 63) / 64, (M + 63) / 64);
  gemm_s<<<g, 256, 0, st>>>(A, W, bias, C, M, N, K, lda, ldc, relu);
}
static inline void split(const float* x, us* h, us* l, int n, hipStream_t st) {
  int n4 = n >> 2;
  int blocks = (n4 + 255) / 256;
  if (blocks > 2048) blocks = 2048;
  split_k<<<blocks, 256, 0, st>>>(x, h, l, n4);
}
static inline Sub mksub(const us* Ah, const us* Al, const us* Bh, const us* Bl,
                        const float* bias, float* Cf, us* Ch, us* Cl,
                        int lda, int ldc, int ldch, int Nt) {
  Sub s; s.Ah = Ah; s.Al = Al; s.Bh = Bh; s.Bl = Bl; s.bias = bias;
  s.Cf = Cf; s.Ch = Ch; s.Cl = Cl; s.lda = lda; s.ldc = ldc; s.ldch = ldch; s.Nt = Nt;
  return s;
}

extern "C" void kernel_launch(void* const* d_in, const int* in_sizes, int n_in,
                              void* d_out, int out_size, void* d_ws, size_t ws_size,
                              hipStream_t stream) {
  const float* video     = (const float*)d_in[0];
  const float* script    = (const float*)d_in[1];
  const float* question  = (const float*)d_in[2];
  const float* a_texts   = (const float*)d_in[3];
  const float* a_buttons = (const float*)d_in[4];
  const float* v_w1 = (const float*)d_in[5];
  const float* v_b1 = (const float*)d_in[6];
  const float* v_w2 = (const float*)d_in[7];
  const float* v_b2 = (const float*)d_in[8];
  const float* t_w1 = (const float*)d_in[9];
  const float* t_b1 = (const float*)d_in[10];
  const float* t_w2 = (const float*)d_in[11];
  const float* t_b2 = (const float*)d_in[12];
  const float* pre_w1 = (const float*)d_in[13];
  const float* pre_b1 = (const float*)d_in[14];
  const float* pre_w2 = (const float*)d_in[15];
  const float* pre_b2 = (const float*)d_in[16];
  const float* s2v_win  = (const float*)d_in[17];
  const float* s2v_bin  = (const float*)d_in[18];
  const float* s2v_wout = (const float*)d_in[19];
  const float* s2v_bout = (const float*)d_in[20];
  const float* qa_win  = (const float*)d_in[21];
  const float* qa_bin  = (const float*)d_in[22];
  const float* qa_wout = (const float*)d_in[23];
  const float* qa_bout = (const float*)d_in[24];
  const float* gru_wih = (const float*)d_in[25];
  const float* gru_whh = (const float*)d_in[26];
  const float* gru_bih = (const float*)d_in[27];
  const float* gru_bhh = (const float*)d_in[28];
  const float* proj_w1 = (const float*)d_in[29];
  const float* proj_b1 = (const float*)d_in[30];
  const float* proj_w2 = (const float*)d_in[31];
  const float* proj_b2 = (const float*)d_in[32];
  const float* state0  = (const float*)d_in[33];
  (void)in_sizes; (void)n_in; (void)out_size; (void)ws_size;

  constexpr int W589  = 768 * 768;
  constexpr int W1769 = 2304 * 768;
  constexpr int W9437 = 3072 * 3072;
  constexpr int W2359 = 768 * 3072;
  constexpr int SMe   = 1024 * 768;
  constexpr int BIGe  = 4096 * 768;

  char* base = (char*)d_ws;
  char* RW1 = base;                   // 9,437,184 : phase-A weights -> gABall(head)
  char* RW2 = RW1 + 9437184;          // 9,437,184 : s2v/qa/pre_w2 weights -> gABall(tail)
  char* R1  = RW2 + 9437184;          // 28,311,552
  char* R2  = R1 + 28311552;          // 12,582,912
  char* X   = R2 + 12582912;          // 25,165,824
  char* P   = X + 25165824;           // abin + Hh/Hl tail overlap
  char* P2  = P + 6815744;            // persistents

  // RW1
  us* vw1h = (us*)RW1;        us* vw1l = vw1h + W589;
  us* vw2h = vw1l + W589;     us* vw2l = vw2h + W589;
  us* tw1h = vw2l + W589;     us* tw1l = tw1h + W589;
  us* tw2h = tw1l + W589;     us* tw2l = tw2h + W589;
  // RW2
  us* s2vwh = (us*)RW2;       us* s2vwl = s2vwh + W1769;
  us* s2voh = s2vwl + W1769;  us* s2vol = s2voh + W589;
  us* qawh  = (us*)RW2;       us* qawl  = qawh + W1769;
  us* qaoh  = qawl + W1769;   us* qaol  = qaoh + W589;
  us* pw2h  = (us*)RW2;       us* pw2l  = pw2h + W2359;
  float* gABall = (float*)RW1;          // [1024 x 4608] f32, spans RW1+RW2
  // R1: video path (phase A), then kvproj/qproj, then kv2/qp2/S2, then weights
  us* vidh = (us*)R1;         us* vidl = vidh + BIGe;      // R1[0..12.6MB)
  us* hidh = vidl + BIGe;     us* hidl = hidh + BIGe;      // R1[12.6..25.2MB)
  float* kvproj = (float*)R1;                              // 4096x1536 f32
  float* qproj  = kvproj + (size_t)4096 * 1536;            // R1+25.2MB, 3MB
  float* kv2 = (float*)R1;
  float* qp2 = (float*)(R1 + 6291456);
  float* S2  = (float*)(R1 + 9437184);
  us* pw1h = (us*)R1;         us* pw1l = pw1h + W9437;     // spans into R2
  us* gwALLh = (us*)R1;                                    // [4608x768]
  us* gwALLl = (us*)(R1 + 7077888);
  us* pjw1h  = (us*)(R1 + 14155776); us* pjw1l = pjw1h + W589;
  // R2
  us* vh = (us*)R2;           us* vl = vh + BIGe;
  us* aoh = (us*)(R2 + 3145728); us* aol = aoh + SMe;
  us* Hh = (us*)R2;           us* Hl = Hh + (size_t)Mtot * Dd;  // spans R2+X+P
  // X: phase-A script/ab temporaries (dead before S1), then S1/cat/preh
  us* inTh  = (us*)X;             us* inTl  = inTh + 2 * SMe;    // X[0..6.3MB)
  us* hid2h = (us*)(X + 6291456); us* hid2l = hid2h + 2 * SMe;   // X[6.3..12.6MB)
  us* abh1h = (us*)(X + 12582912); us* abh1l = abh1h + SMe;      // X[12.6..15.7MB)
  float* S1 = (float*)X;
  us* cath = (us*)X;          us* catl = cath + (size_t)1024 * DPn;
  us* prehh = (us*)(X + 12582912); us* prehl = prehh + (size_t)1024 * DPn;
  // P (overwritten by Hl tail after abin dead)
  us* abinh = (us*)P;         us* abinl = abinh + SMe;
  // P2 persistents
  us* sc2h   = (us*)P2;                       // 2048x768 split (script|a_texts)
  us* sc2l   = sc2h + 2 * SMe;
  float* scat_f = (float*)(P2 + 6291456);     // 2048x768 f32
  float* vatt   = (float*)(P2 + 12582912);
  float* inps_f = (float*)(P2 + 15728640);
  us* inpsh = (us*)(P2 + 18874368); us* inpsl = inpsh + SMe;
  float* qf    = (float*)(P2 + 22020096);
  float* qhid  = (float*)(P2 + 22044672);
  float* gh0   = (float*)(P2 + 22069248);
  float* Lpart = (float*)(P2 + 22085632);     // NLT x 14464 f32
  float* at_f  = scat_f + (size_t)1024 * Dd;  // rows 1024..2047
  us* sch = sc2h;  us* scl = sc2l;            // rows 0..1023
  // ab2 temp borrows inpsh slot (inps written only at pre2, after cat_fill)
  us* ab2h  = (us*)(P2 + 18874368); us* ab2l  = ab2h + SMe;

  // ---- phase A: weight splits + input splits ----
  split4_k<<<dim3(1024, 4), 256, 0, stream>>>(v_w1, vw1h, vw1l, W589,
                                              v_w2, vw2h, vw2l, W589,
                                              t_w1, tw1h, tw1l, W589,
                                              t_w2, tw2h, tw2l, W589);
  split(video, vidh, vidl, BIGe, stream);
  split4_k<<<dim3(1024, 3), 256, 0, stream>>>(script, inTh, inTl, SMe,
                                              a_texts, inTh + SMe, inTl + SMe, SMe,
                                              a_buttons, abinh, abinl, SMe,
                                              nullptr, nullptr, nullptr, 0);
  // B1: video-mm1 (64yt) + scat-mm1 (32yt) + ab-mm1 (16yt), all N=768 K=768 relu
  {
    Sub sv = mksub(vidh, vidl, vw1h, vw1l, v_b1, nullptr, hidh, hidl, Dd, 0, Dd, 12);
    Sub ss = mksub(inTh, inTl, tw1h, tw1l, t_b1, nullptr, hid2h, hid2l, Dd, 0, Dd, 12);
    Sub sa = mksub(abinh, abinl, vw1h, vw1l, v_b1, nullptr, abh1h, abh1l, Dd, 0, Dd, 12);
    mfma_ntb<<<dim3(12, 112), 256, 0, stream>>>(sv, ss, sa, 64, 96, Dd, 1);
  }
  sgemm(question, t_w1, t_b1, qhid, Bn, Dd, Dd, Dd, Dd, 1, stream);
  sgemm(qhid, t_w2, t_b2, qf, Bn, Dd, Dd, Dd, Dd, 0, stream);
  // B2: video-mm2 + scat-mm2 (+f32) + ab-mm2
  {
    Sub sv = mksub(hidh, hidl, vw2h, vw2l, v_b2, nullptr, vh, vl, Dd, 0, Dd, 12);
    Sub ss = mksub(hid2h, hid2l, tw2h, tw2l, t_b2, scat_f, sc2h, sc2l, Dd, Dd, Dd, 12);
    Sub sa = mksub(abh1h, abh1l, vw2h, vw2l, v_b2, nullptr, ab2h, ab2l, Dd, 0, Dd, 12);
    mfma_ntb<<<dim3(12, 112), 256, 0, stream>>>(sv, ss, sa, 64, 96, Dd, 0);
  }

  // ---- s2v attention (K/V merged: N=1536) ----
  split4_k<<<dim3(1024, 2), 256, 0, stream>>>(s2v_win, s2vwh, s2vwl, W1769,
                                              s2v_wout, s2voh, s2vol, W589,
                                              nullptr, nullptr, nullptr, 0,
                                              nullptr, nullptr, nullptr, 0);
  // B3: kvproj (64yt, Nt24) + qproj (16yt, Nt12)
  {
    Sub sk = mksub(vh, vl, s2vwh + (size_t)Dd * Dd, s2vwl + (size_t)Dd * Dd,
                   s2v_bin + Dd, kvproj, nullptr, nullptr, Dd, 1536, 0, 24);
    Sub sq = mksub(sch, scl, s2vwh, s2vwl, s2v_bin, qproj, nullptr, nullptr,
                   Dd, Dd, 0, 12);
    mfma_ntb<<<dim3(24, 80), 256, 0, stream>>>(sk, sq, sq, 64, 80, Dd, 0);
  }
  att_qk<<<dim3(Bn * NH, TSn / 32, TVn / 64), 256, 0, stream>>>(qproj, kvproj, S1,
                                                                TSn, TVn, 1, 1536, 0.125f);
  softmax_rows<<<Bn * NH * TSn, 256, 0, stream>>>(S1, TVn);
  att_pv<<<dim3(Bn * NH, TSn / 32), 256, 0, stream>>>(S1, kvproj + Dd, aoh, aol,
                                                      TSn, TVn, 1, 1536);

  // ---- phase B: cat assembly + qa attention ----
  split(qa_win, qawh, qawl, W1769, stream);          // overwrites s2vw (dead)
  cat_fill<<<(1024 * Dd + 255) / 256, 256, 0, stream>>>(qf, at_f, ab2h, ab2l,
                                                        cath, catl);
  // B4: vatt-out (16yt) + qp2 (16yt) + kv2 (16yt, Nt24)
  {
    Sub svat = mksub(aoh, aol, s2voh, s2vol, s2v_bout, vatt, nullptr, nullptr,
                     Dd, Dd, 0, 12);
    Sub sqp = mksub(cath + 2 * Dd, catl + 2 * Dd, qawh, qawl, qa_bin,
                    qp2, nullptr, nullptr, DPn, Dd, 0, 12);
    Sub skv = mksub(sch, scl, qawh + (size_t)Dd * Dd, qawl + (size_t)Dd * Dd,
                    qa_bin + Dd, kv2, nullptr, nullptr, Dd, 1536, 0, 24);
    mfma_ntb<<<dim3(24, 48), 256, 0, stream>>>(svat, sqp, skv, 16, 32, Dd, 0);
  }
  split(qa_wout, qaoh, qaol, W589, stream);          // overwrites s2vo (dead)
  att_qk<<<dim3(Bn * NST * NH, 1, TSn / 64), 256, 0, stream>>>(qp2, kv2, S2,
                                                               An, TSn, NST, 1536, 0.125f);
  softmax_rows<<<Bn * NST * NH * An, 256, 0, stream>>>(S2, TSn);
  att_pv<<<dim3(Bn * NST * NH, 1), 256, 0, stream>>>(S2, kv2 + Dd, aoh, aol,
                                                     An, TSn, NST, 1536);
  mm(aoh, aol, Dd, qaoh, qaol, qa_bout, nullptr, 0, cath + Dd, catl + Dd, DPn,
     1024, Dd, Dd, 0, stream);
  qv2_k<<<1024, 256, 0, stream>>>(S2, vatt, cath, catl);

  // ---- pre-MLP + merged GRU gates ----
  split(pre_w1, pw1h, pw1l, W9437, stream);
  mm(cath, catl, DPn, pw1h, pw1l, pre_b1, nullptr, 0, prehh, prehl, DPn,
     1024, DPn, DPn, 1, stream);
  split4_k<<<dim3(1024, 4), 256, 0, stream>>>(pre_w2, pw2h, pw2l, W2359,
                                              gru_wih, gwALLh, gwALLl, W1769,
                                              gru_whh, gwALLh + W1769, gwALLl + W1769, W1769,
                                              proj_w1, pjw1h, pjw1l, W589);
  mm(prehh, prehl, DPn, pw2h, pw2l, pre_b2, inps_f, Dd, inpsh, inpsl, Dd,
     1024, Dd, DPn, 0, stream);
  mm2(inpsh, inpsl, Dd, gwALLh, gwALLl, gru_bih, gru_bhh, GSn,
      gABall, 4608, nullptr, nullptr, 0, 1024, 4608, Dd, 0, stream);
  sgemm(state0, gru_whh, gru_bhh, gh0, 1, GSn, Dd, Dd, GSn, 0, stream);

  // ---- candidate enumeration + logits + argmax chain ----
  combine_all<<<(Mtot * (Dd / 4) + 255) / 256, 256, 0, stream>>>(gABall, gh0, inps_f,
                                                                 state0, Hh, Hl);
  mfma_logit128<<<dim3(NLT, Mtot / 128), 256, 0, stream>>>(Hh, Hl, pjw1h, pjw1l,
                                                           proj_b1, proj_w2, Lpart);
  pick_k<<<Bn, 64, 0, stream>>>(Lpart, proj_b2, (float*)d_out);
}

// Round 8
// 871.276 us; speedup vs baseline: 1.3051x; 1.2534x over previous
//
#include <hip/hip_runtime.h>
#include <hip/hip_bf16.h>
#include <math.h>

constexpr int Dd  = 768;
constexpr int NH  = 12;
constexpr int DHd = 64;
constexpr int Bn  = 8;
constexpr int TVn = 512;
constexpr int TSn = 128;
constexpr int NST = 8;
constexpr int An  = 16;
constexpr int DPn = 3072;
constexpr int GSn = 2304;
constexpr int Mtot = 14464;   // 128 (s=0) + 8*7*16*16 candidate rows; 113*128
constexpr int NLT = 6;        // logit n-tiles at 128-wide tiling (768/128)

typedef unsigned short us;
using short8   = __attribute__((ext_vector_type(8))) short;
using floatx16 = __attribute__((ext_vector_type(16))) float;

typedef __attribute__((address_space(1))) const unsigned char glb_b;
typedef __attribute__((address_space(3))) unsigned char lds_b;

// async global->LDS DMA, 16B per lane, dest = lptr + lane*16 (HW-linear)
__device__ inline void gload16(const void* g, void* l) {
  __builtin_amdgcn_global_load_lds((glb_b*)g, (lds_b*)l, 16, 0, 0);
}

__device__ inline us f2bf(float x) {
  union { float f; unsigned u; } a; a.f = x;
  return (us)((a.u + 0x7fffu + ((a.u >> 16) & 1u)) >> 16);
}
__device__ inline float bf2f(us h) {
  union { unsigned u; float f; } a; a.u = ((unsigned)h) << 16;
  return a.f;
}

// ---------------------------------------------------------------------------
// splits (float4-vectorized)
// ---------------------------------------------------------------------------
__global__ void split_k(const float* __restrict__ x, us* __restrict__ h,
                        us* __restrict__ l, int n4) {
  for (int i = blockIdx.x * 256 + threadIdx.x; i < n4; i += gridDim.x * 256) {
    float4 v = ((const float4*)x)[i];
    float vv[4] = {v.x, v.y, v.z, v.w};
    union { us u[4]; uint2 w; } hh, ll;
#pragma unroll
    for (int t = 0; t < 4; t++) {
      us hb = f2bf(vv[t]);
      hh.u[t] = hb;
      ll.u[t] = f2bf(vv[t] - bf2f(hb));
    }
    ((uint2*)h)[i] = hh.w;
    ((uint2*)l)[i] = ll.w;
  }
}

__global__ void split4_k(const float* s0, us* h0, us* l0, int n0,
                         const float* s1, us* h1, us* l1, int n1,
                         const float* s2, us* h2, us* l2, int n2,
                         const float* s3, us* h3, us* l3, int n3) {
  const float* s; us* h; us* l; int n;
  switch (blockIdx.y) {
    case 0: s = s0; h = h0; l = l0; n = n0; break;
    case 1: s = s1; h = h1; l = l1; n = n1; break;
    case 2: s = s2; h = h2; l = l2; n = n2; break;
    default: s = s3; h = h3; l = l3; n = n3; break;
  }
  int n4 = n >> 2;
  for (int i = blockIdx.x * 256 + threadIdx.x; i < n4; i += gridDim.x * 256) {
    float4 v = ((const float4*)s)[i];
    float vv[4] = {v.x, v.y, v.z, v.w};
    union { us u[4]; uint2 w; } hh, ll;
#pragma unroll
    for (int t = 0; t < 4; t++) {
      us hb = f2bf(vv[t]);
      hh.u[t] = hb;
      ll.u[t] = f2bf(vv[t] - bf2f(hb));
    }
    ((uint2*)h)[i] = hh.w;
    ((uint2*)l)[i] = ll.w;
  }
}

__device__ inline short8 lds8(const us* p) {
  const uint2* q = (const uint2*)p;
  uint2 a = q[0], b = q[1];
  union { unsigned u[4]; short8 v; } t;
  t.u[0] = a.x; t.u[1] = a.y; t.u[2] = b.x; t.u[3] = b.y;
  return t.v;
}

// ---------------------------------------------------------------------------
// bf16x3 MFMA NT GEMM — 64x64 tile, 4 waves, 3 acc chains, dbuf LDS,
// 1 barrier/iter, global_load_lds staging, src-side slot swizzle.
// ---------------------------------------------------------------------------
__global__ __launch_bounds__(256) void mfma_nt(
    const us* __restrict__ Ah, const us* __restrict__ Al, int lda,
    const us* __restrict__ Bh, const us* __restrict__ Bl,
    const float* __restrict__ bias, const float* __restrict__ bias2, int nsplit,
    float* __restrict__ Cf, int ldc,
    us* __restrict__ Ch, us* __restrict__ Cl, int ldch,
    int K, int relu) {
  __shared__ us Ash[2][64][32], Asl[2][64][32], Bsh[2][64][32], Bsl[2][64][32];
  const int tid = threadIdx.x;
  const int bm = blockIdx.y * 64, bn = blockIdx.x * 64;
  const int wave = tid >> 6, lane = tid & 63;
  const int mh = (wave & 1) * 32, nh = (wave >> 1) * 32;
  const int l31 = lane & 31, hi5 = lane >> 5;
  const int srow = tid >> 2;
  const int scol = (((tid & 3) ^ ((tid >> 3) & 3)) << 3);   // swizzled src col
  const int rc2 = (l31 >> 1) & 3;                           // read swizzle key
  const int wb = wave * 16;
  const us* pAh = Ah + (size_t)(bm + srow) * lda + scol;
  const us* pAl = Al + (size_t)(bm + srow) * lda + scol;
  const us* pBh = Bh + (size_t)(bn + srow) * K + scol;
  const us* pBl = Bl + (size_t)(bn + srow) * K + scol;

  floatx16 acc_hh, acc_hl, acc_lh;
#pragma unroll
  for (int i = 0; i < 16; i++) { acc_hh[i] = 0.f; acc_hl[i] = 0.f; acc_lh[i] = 0.f; }

  const int iters = K >> 5;
  gload16(pAh, &Ash[0][wb][0]);
  gload16(pAl, &Asl[0][wb][0]);
  gload16(pBh, &Bsh[0][wb][0]);
  gload16(pBl, &Bsl[0][wb][0]);
  int p = 0;
  for (int it = 0; it < iters; ++it) {
    __syncthreads();                       // drains DMA: buf[p] resident
    if (it + 1 < iters) {
      int ko = (it + 1) * 32;
      gload16(pAh + ko, &Ash[p ^ 1][wb][0]);
      gload16(pAl + ko, &Asl[p ^ 1][wb][0]);
      gload16(pBh + ko, &Bsh[p ^ 1][wb][0]);
      gload16(pBl + ko, &Bsl[p ^ 1][wb][0]);
    }
#pragma unroll
    for (int ks = 0; ks < 32; ks += 16) {
      int col = ((((ks >> 3) + hi5) ^ rc2) << 3);
      short8 fa_h = lds8(&Ash[p][mh + l31][col]);
      short8 fa_l = lds8(&Asl[p][mh + l31][col]);
      short8 fb_h = lds8(&Bsh[p][nh + l31][col]);
      short8 fb_l = lds8(&Bsl[p][nh + l31][col]);
      acc_hh = __builtin_amdgcn_mfma_f32_32x32x16_bf16(fa_h, fb_h, acc_hh, 0, 0, 0);
      acc_hl = __builtin_amdgcn_mfma_f32_32x32x16_bf16(fa_h, fb_l, acc_hl, 0, 0, 0);
      acc_lh = __builtin_amdgcn_mfma_f32_32x32x16_bf16(fa_l, fb_h, acc_lh, 0, 0, 0);
    }
    p ^= 1;
  }
  int n = bn + nh + l31;
  float bv = (n < nsplit) ? bias[n] : bias2[n - nsplit];
#pragma unroll
  for (int r = 0; r < 16; r++) {
    int m = bm + mh + (r & 3) + 8 * (r >> 2) + 4 * hi5;
    float v = acc_hh[r] + acc_hl[r] + acc_lh[r] + bv;
    if (relu) v = fmaxf(v, 0.f);
    if (Cf) Cf[(size_t)m * ldc + n] = v;
    if (Ch) {
      us hb = f2bf(v);
      Ch[(size_t)m * ldch + n] = hb;
      Cl[(size_t)m * ldch + n] = f2bf(v - bf2f(hb));
    }
  }
}

// ---------------------------------------------------------------------------
// Batched variant: up to 4 sub-GEMMs share one launch (y-tile ranges).
// Tiny GEMMs (question MLP, gh0) ride along on big grids instead of running
// as <40-block solo launches.
// ---------------------------------------------------------------------------
struct Sub {
  const us* Ah; const us* Al; const us* Bh; const us* Bl;
  const float* bias; float* Cf; us* Ch; us* Cl;
  int lda, ldc, ldch, Nt;
};

__global__ __launch_bounds__(256) void mfma_ntb(Sub s0, Sub s1, Sub s2, Sub s3,
                                                int c1, int c2, int c3,
                                                int K, int relu) {
  Sub s; int yt = blockIdx.y;
  if (yt < c1) { s = s0; }
  else if (yt < c2) { s = s1; yt -= c1; }
  else if (yt < c3) { s = s2; yt -= c2; }
  else { s = s3; yt -= c3; }
  if ((int)blockIdx.x >= s.Nt) return;
  __shared__ us Ash[2][64][32], Asl[2][64][32], Bsh[2][64][32], Bsl[2][64][32];
  const int tid = threadIdx.x;
  const int bm = yt * 64, bn = blockIdx.x * 64;
  const int wave = tid >> 6, lane = tid & 63;
  const int mh = (wave & 1) * 32, nh = (wave >> 1) * 32;
  const int l31 = lane & 31, hi5 = lane >> 5;
  const int srow = tid >> 2;
  const int scol = (((tid & 3) ^ ((tid >> 3) & 3)) << 3);
  const int rc2 = (l31 >> 1) & 3;
  const int wb = wave * 16;
  const us* pAh = s.Ah + (size_t)(bm + srow) * s.lda + scol;
  const us* pAl = s.Al + (size_t)(bm + srow) * s.lda + scol;
  const us* pBh = s.Bh + (size_t)(bn + srow) * K + scol;
  const us* pBl = s.Bl + (size_t)(bn + srow) * K + scol;

  floatx16 acc_hh, acc_hl, acc_lh;
#pragma unroll
  for (int i = 0; i < 16; i++) { acc_hh[i] = 0.f; acc_hl[i] = 0.f; acc_lh[i] = 0.f; }

  const int iters = K >> 5;
  gload16(pAh, &Ash[0][wb][0]);
  gload16(pAl, &Asl[0][wb][0]);
  gload16(pBh, &Bsh[0][wb][0]);
  gload16(pBl, &Bsl[0][wb][0]);
  int p = 0;
  for (int it = 0; it < iters; ++it) {
    __syncthreads();
    if (it + 1 < iters) {
      int ko = (it + 1) * 32;
      gload16(pAh + ko, &Ash[p ^ 1][wb][0]);
      gload16(pAl + ko, &Asl[p ^ 1][wb][0]);
      gload16(pBh + ko, &Bsh[p ^ 1][wb][0]);
      gload16(pBl + ko, &Bsl[p ^ 1][wb][0]);
    }
#pragma unroll
    for (int ks = 0; ks < 32; ks += 16) {
      int col = ((((ks >> 3) + hi5) ^ rc2) << 3);
      short8 fa_h = lds8(&Ash[p][mh + l31][col]);
      short8 fa_l = lds8(&Asl[p][mh + l31][col]);
      short8 fb_h = lds8(&Bsh[p][nh + l31][col]);
      short8 fb_l = lds8(&Bsl[p][nh + l31][col]);
      acc_hh = __builtin_amdgcn_mfma_f32_32x32x16_bf16(fa_h, fb_h, acc_hh, 0, 0, 0);
      acc_hl = __builtin_amdgcn_mfma_f32_32x32x16_bf16(fa_h, fb_l, acc_hl, 0, 0, 0);
      acc_lh = __builtin_amdgcn_mfma_f32_32x32x16_bf16(fa_l, fb_h, acc_lh, 0, 0, 0);
    }
    p ^= 1;
  }
  int n = bn + nh + l31;
  float bv = s.bias[n];
#pragma unroll
  for (int r = 0; r < 16; r++) {
    int m = bm + mh + (r & 3) + 8 * (r >> 2) + 4 * hi5;
    float v = acc_hh[r] + acc_hl[r] + acc_lh[r] + bv;
    if (relu) v = fmaxf(v, 0.f);
    if (s.Cf) s.Cf[(size_t)m * s.ldc + n] = v;
    if (s.Ch) {
      us hb = f2bf(v);
      s.Ch[(size_t)m * s.ldch + n] = hb;
      s.Cl[(size_t)m * s.ldch + n] = f2bf(v - bf2f(hb));
    }
  }
}

// ---------------------------------------------------------------------------
// logit GEMM, 128x128 tile (678 blocks), gload_lds staging, XCD-aware
// bijective chunked swizzle (each XCD owns consecutive m-tiles with all 6
// n-tiles -> A fetched into one L2, reused 6x). Cross chains share one
// accumulator. Epilogue: relu(acc+b1[n])*w2[n] -> Lpart[ntile][m].
// ---------------------------------------------------------------------------
__global__ __launch_bounds__(256, 2) void mfma_logit128(
    const us* __restrict__ Ah, const us* __restrict__ Al,
    const us* __restrict__ Bh, const us* __restrict__ Bl,
    const float* __restrict__ bias1, const float* __restrict__ w2,
    float* __restrict__ Lpart) {
  __shared__ us Ash[2][128][32], Asl[2][128][32], Bsh[2][128][32], Bsl[2][128][32];
  __shared__ float lpart[128];
  const int K = Dd;
  const int tid = threadIdx.x;
  const int nwg = NLT * (Mtot / 128);             // 678
  const int lin = blockIdx.y * NLT + blockIdx.x;  // hw dispatch order (x fastest)
  const int xcd = lin & 7, loc = lin >> 3;
  const int q = nwg / 8, r = nwg % 8;             // 84, 6
  const int pos = (xcd < r) ? xcd * (q + 1) + loc
                            : r * (q + 1) + (xcd - r) * q + loc;
  const int bxn = pos % NLT, bym = pos / NLT;
  const int bm = bym * 128, bn = bxn * 128;
  const int wave = tid >> 6, lane = tid & 63;
  const int mh = (wave & 1) * 64, nh = (wave >> 1) * 64;
  const int l31 = lane & 31, hi5 = lane >> 5;
  const int srow = tid >> 2;
  const int scol = (((tid & 3) ^ ((tid >> 3) & 3)) << 3);
  const int rc2 = (l31 >> 1) & 3;
  const int wb = wave * 16;
  const us* pAh = Ah + (size_t)(bm + srow) * K + scol;
  const us* pAl = Al + (size_t)(bm + srow) * K + scol;
  const us* pBh = Bh + (size_t)(bn + srow) * K + scol;
  const us* pBl = Bl + (size_t)(bn + srow) * K + scol;
  const size_t strA = (size_t)64 * K, strB = (size_t)64 * K;
  if (tid < 128) lpart[tid] = 0.f;

  floatx16 acc_hh[2][2], acc_x[2][2];
#pragma unroll
  for (int i = 0; i < 2; i++)
#pragma unroll
    for (int j = 0; j < 2; j++)
#pragma unroll
      for (int rr = 0; rr < 16; rr++) { acc_hh[i][j][rr] = 0.f; acc_x[i][j][rr] = 0.f; }

  const int iters = K >> 5;
  gload16(pAh,        &Ash[0][wb][0]);
  gload16(pAh + strA, &Ash[0][wb + 64][0]);
  gload16(pAl,        &Asl[0][wb][0]);
  gload16(pAl + strA, &Asl[0][wb + 64][0]);
  gload16(pBh,        &Bsh[0][wb][0]);
  gload16(pBh + strB, &Bsh[0][wb + 64][0]);
  gload16(pBl,        &Bsl[0][wb][0]);
  gload16(pBl + strB, &Bsl[0][wb + 64][0]);
  int p = 0;
  for (int it = 0; it < iters; ++it) {
    __syncthreads();
    if (it + 1 < iters) {
      int ko = (it + 1) * 32;
      gload16(pAh + ko,        &Ash[p ^ 1][wb][0]);
      gload16(pAh + strA + ko, &Ash[p ^ 1][wb + 64][0]);
      gload16(pAl + ko,        &Asl[p ^ 1][wb][0]);
      gload16(pAl + strA + ko, &Asl[p ^ 1][wb + 64][0]);
      gload16(pBh + ko,        &Bsh[p ^ 1][wb][0]);
      gload16(pBh + strB + ko, &Bsh[p ^ 1][wb + 64][0]);
      gload16(pBl + ko,        &Bsl[p ^ 1][wb][0]);
      gload16(pBl + strB + ko, &Bsl[p ^ 1][wb + 64][0]);
    }
#pragma unroll
    for (int ks = 0; ks < 32; ks += 16) {
      int col = ((((ks >> 3) + hi5) ^ rc2) << 3);
      short8 fah[2], fal[2], fbh[2], fbl[2];
#pragma unroll
      for (int f = 0; f < 2; f++) {
        fah[f] = lds8(&Ash[p][mh + f * 32 + l31][col]);
        fal[f] = lds8(&Asl[p][mh + f * 32 + l31][col]);
        fbh[f] = lds8(&Bsh[p][nh + f * 32 + l31][col]);
        fbl[f] = lds8(&Bsl[p][nh + f * 32 + l31][col]);
      }
#pragma unroll
      for (int fm = 0; fm < 2; fm++)
#pragma unroll
        for (int fn = 0; fn < 2; fn++) {
          acc_hh[fm][fn] = __builtin_amdgcn_mfma_f32_32x32x16_bf16(fah[fm], fbh[fn], acc_hh[fm][fn], 0, 0, 0);
          acc_x[fm][fn]  = __builtin_amdgcn_mfma_f32_32x32x16_bf16(fah[fm], fbl[fn], acc_x[fm][fn], 0, 0, 0);
          acc_x[fm][fn]  = __builtin_amdgcn_mfma_f32_32x32x16_bf16(fal[fm], fbh[fn], acc_x[fm][fn], 0, 0, 0);
        }
    }
    p ^= 1;
  }
  float b1[2], wn[2];
#pragma unroll
  for (int fn = 0; fn < 2; fn++) {
    int n = bn + nh + fn * 32 + l31;
    b1[fn] = bias1[n];
    wn[fn] = w2[n];
  }
#pragma unroll
  for (int fm = 0; fm < 2; fm++) {
#pragma unroll
    for (int rr = 0; rr < 16; rr++) {
      int mloc = mh + fm * 32 + (rr & 3) + 8 * (rr >> 2) + 4 * hi5;
      float v = 0.f;
#pragma unroll
      for (int fn = 0; fn < 2; fn++) {
        float vv = acc_hh[fm][fn][rr] + acc_x[fm][fn][rr] + b1[fn];
        v += fmaxf(vv, 0.f) * wn[fn];
      }
      v += __shfl_xor(v, 1);
      v += __shfl_xor(v, 2);
      v += __shfl_xor(v, 4);
      v += __shfl_xor(v, 8);
      v += __shfl_xor(v, 16);
      if (l31 == 0) atomicAdd(&lpart[mloc], v);
    }
  }
  __syncthreads();
  if (tid < 128) Lpart[(size_t)bxn * Mtot + bm + tid] = lpart[tid];
}

// ---------------------------------------------------------------------------
// attention (f32), float4-vectorized LDS
// ---------------------------------------------------------------------------
__global__ __launch_bounds__(256) void att_qk(const float* __restrict__ qp,
                                              const float* __restrict__ kp,
                                              float* __restrict__ Sout,
                                              int Tq, int Tk, int kdiv, int ldk,
                                              float scale) {
  int g = blockIdx.x;
  int h = g % NH;
  int qrow0 = (g / NH) * Tq;
  int krow0 = (g / (NH * kdiv)) * Tk;
  int q0 = blockIdx.y * 32;
  int k0 = blockIdx.z * 64;
  __shared__ float Qs[32][68];
  __shared__ float KsT[64][72];   // transposed: [d][k]
  int tid = threadIdx.x;
  {
    int row = tid >> 3, db = (tid & 7) * 8;
    int qr = q0 + row;
    float4 v0 = {0, 0, 0, 0}, v1 = {0, 0, 0, 0};
    if (qr < Tq) {
      const float* p = qp + (size_t)(qrow0 + qr) * Dd + h * DHd + db;
      v0 = *(const float4*)p;
      v1 = *(const float4*)(p + 4);
    }
    *(float4*)&Qs[row][db] = v0;
    *(float4*)&Qs[row][db + 4] = v1;
  }
#pragma unroll
  for (int half = 0; half < 2; half++) {
    int row = (tid >> 3) + half * 32, db = (tid & 7) * 8;
    int kr = k0 + row;
    float4 v0 = {0, 0, 0, 0}, v1 = {0, 0, 0, 0};
    if (kr < Tk) {
      const float* p = kp + (size_t)(krow0 + kr) * ldk + h * DHd + db;
      v0 = *(const float4*)p;
      v1 = *(const float4*)(p + 4);
    }
    KsT[db + 0][row] = v0.x; KsT[db + 1][row] = v0.y;
    KsT[db + 2][row] = v0.z; KsT[db + 3][row] = v0.w;
    KsT[db + 4][row] = v1.x; KsT[db + 5][row] = v1.y;
    KsT[db + 6][row] = v1.z; KsT[db + 7][row] = v1.w;
  }
  __syncthreads();
  int q = tid >> 3, kg = tid & 7;
  float acc[8] = {};
  for (int d = 0; d < DHd; d++) {
    float qv = Qs[q][d];
    float4 k0v = *(const float4*)&KsT[d][kg * 8];
    float4 k1v = *(const float4*)&KsT[d][kg * 8 + 4];
    acc[0] += qv * k0v.x; acc[1] += qv * k0v.y;
    acc[2] += qv * k0v.z; acc[3] += qv * k0v.w;
    acc[4] += qv * k1v.x; acc[5] += qv * k1v.y;
    acc[6] += qv * k1v.z; acc[7] += qv * k1v.w;
  }
  if (q0 + q < Tq) {
    size_t basep = ((size_t)g * Tq + q0 + q) * Tk + k0 + kg * 8;
#pragma unroll
    for (int j = 0; j < 8; j++) Sout[basep + j] = acc[j] * scale;
  }
}

// P@V with fused bf16-split output (Outh/Outl)
__global__ __launch_bounds__(256) void att_pv(const float* __restrict__ P,
                                              const float* __restrict__ vp,
                                              us* __restrict__ Outh,
                                              us* __restrict__ Outl,
                                              int Tq, int Tk, int kdiv, int ldv) {
  int g = blockIdx.x;
  int h = g % NH;
  int qrow0 = (g / NH) * Tq;
  int krow0 = (g / (NH * kdiv)) * Tk;
  int q0 = blockIdx.y * 32;
  __shared__ float Ps[32][68];
  __shared__ float Vs[64][72];
  int tid = threadIdx.x;
  int q = tid >> 3, dg = tid & 7;
  float acc[8] = {};
  for (int k0 = 0; k0 < Tk; k0 += 64) {
    {
      int row = tid >> 3, cb = (tid & 7) * 8;
      int qr = q0 + row;
      float4 v0 = {0, 0, 0, 0}, v1 = {0, 0, 0, 0};
      if (qr < Tq) {
        const float* p = P + ((size_t)g * Tq + qr) * Tk + k0 + cb;
        v0 = *(const float4*)p;
        v1 = *(const float4*)(p + 4);
      }
      *(float4*)&Ps[row][cb] = v0;
      *(float4*)&Ps[row][cb + 4] = v1;
    }
#pragma unroll
    for (int half = 0; half < 2; half++) {
      int row = (tid >> 3) + half * 32, db = (tid & 7) * 8;
      const float* p = vp + (size_t)(krow0 + k0 + row) * ldv + h * DHd + db;
      *(float4*)&Vs[row][db] = *(const float4*)p;
      *(float4*)&Vs[row][db + 4] = *(const float4*)(p + 4);
    }
    __syncthreads();
#pragma unroll 4
    for (int kk4 = 0; kk4 < 16; kk4++) {
      float4 pv = *(const float4*)&Ps[q][kk4 * 4];
      float pe[4] = {pv.x, pv.y, pv.z, pv.w};
#pragma unroll
      for (int e = 0; e < 4; e++) {
        int kk = kk4 * 4 + e;
        float4 v0 = *(const float4*)&Vs[kk][dg * 8];
        float4 v1 = *(const float4*)&Vs[kk][dg * 8 + 4];
        acc[0] += pe[e] * v0.x; acc[1] += pe[e] * v0.y;
        acc[2] += pe[e] * v0.z; acc[3] += pe[e] * v0.w;
        acc[4] += pe[e] * v1.x; acc[5] += pe[e] * v1.y;
        acc[6] += pe[e] * v1.z; acc[7] += pe[e] * v1.w;
      }
    }
    __syncthreads();
  }
  if (q0 + q < Tq) {
    size_t basep = (size_t)(qrow0 + q0 + q) * Dd + h * DHd + dg * 8;
    union { us u[8]; uint4 v; } ph, pl;
#pragma unroll
    for (int j = 0; j < 8; j++) {
      us hb = f2bf(acc[j]);
      ph.u[j] = hb;
      pl.u[j] = f2bf(acc[j] - bf2f(hb));
    }
    *(uint4*)&Outh[basep] = ph.v;
    *(uint4*)&Outl[basep] = pl.v;
  }
}

__global__ __launch_bounds__(256) void softmax_rows(float* __restrict__ X, int len) {
  int row = blockIdx.x;
  float* p = X + (size_t)row * len;
  int tid = threadIdx.x;
  __shared__ float red[4];
  __shared__ float red2[4];
  float lmax = -1e30f;
  for (int j = tid; j < len; j += 256) lmax = fmaxf(lmax, p[j]);
  for (int off = 32; off; off >>= 1) lmax = fmaxf(lmax, __shfl_down(lmax, off));
  if ((tid & 63) == 0) red[tid >> 6] = lmax;
  __syncthreads();
  if (tid == 0) red[0] = fmaxf(fmaxf(red[0], red[1]), fmaxf(red[2], red[3]));
  __syncthreads();
  float m = red[0];
  float lsum = 0.f;
  for (int j = tid; j < len; j += 256) {
    float e = expf(p[j] - m);
    p[j] = e;
    lsum += e;
  }
  for (int off = 32; off; off >>= 1) lsum += __shfl_down(lsum, off);
  if ((tid & 63) == 0) red2[tid >> 6] = lsum;
  __syncthreads();
  if (tid == 0) red2[0] = red2[0] + red2[1] + red2[2] + red2[3];
  __syncthreads();
  float inv = 1.f / red2[0];
  for (int j = tid; j < len; j += 256) p[j] *= inv;
}

// fused head-mean + qv = W @ vatt -> cat slice [0,D)
__global__ __launch_bounds__(256) void qv2_k(const float* __restrict__ S2,
                                             const float* __restrict__ vatt,
                                             us* __restrict__ ch, us* __restrict__ cl) {
  int row = blockIdx.x;
  int b = row / (NST * An);
  int bs = row / An;
  int a = row % An;
  __shared__ float wm[TSn];
  int tid = threadIdx.x;
  if (tid < TSn) {
    float acc = 0.f;
    for (int h = 0; h < NH; h++)
      acc += S2[(((size_t)bs * NH + h) * An + a) * TSn + tid];
    wm[tid] = acc * (1.f / NH);
  }
  __syncthreads();
  for (int j = tid; j < Dd; j += 256) {
    float acc = 0.f;
    for (int k = 0; k < TSn; k++)
      acc += wm[k] * vatt[((size_t)b * TSn + k) * Dd + j];
    size_t o = (size_t)row * DPn + j;
    us hb = f2bf(acc);
    ch[o] = hb;
    cl[o] = f2bf(acc - bf2f(hb));
  }
}

// cat slices [2D,3D) = qf[b] + at[row]  and  [3D,4D) = ab2 tmp bit-copy
__global__ void cat_fill(const float* __restrict__ qf, const float* __restrict__ at,
                         const us* __restrict__ ab2h, const us* __restrict__ ab2l,
                         us* __restrict__ ch, us* __restrict__ cl) {
  int idx = blockIdx.x * 256 + threadIdx.x;
  if (idx >= Bn * NST * An * Dd) return;
  int b = idx / (NST * An * Dd);
  int row = idx / Dd;
  int j = idx - row * Dd;
  float v = qf[b * Dd + j] + at[idx];
  size_t o = (size_t)row * DPn + 2 * Dd + j;
  us hb = f2bf(v);
  ch[o] = hb;
  cl[o] = f2bf(v - bf2f(hb));
  size_t o3 = (size_t)row * DPn + 3 * Dd + j;
  ch[o3] = ab2h[idx];
  cl[o3] = ab2l[idx];
}

// ---------------------------------------------------------------------------
// GRU combine for ALL candidate rows. gABall [1024 x 4608]: cols [0,2304) =
// x-gates (wih), cols [2304,4608) = h-gates (whh). Pre-split bf16 output.
// ---------------------------------------------------------------------------
__global__ void combine_all(const float* __restrict__ gABall,
                            const float* __restrict__ gh0,
                            const float* __restrict__ inps,
                            const float* __restrict__ state0,
                            us* __restrict__ Hh, us* __restrict__ Hl) {
  const int D4 = Dd / 4;
  const int LDG = 4608;
  int idx = blockIdx.x * 256 + threadIdx.x;
  if (idx >= Mtot * D4) return;
  int row = idx / D4, j = (idx - row * D4) * 4;
  const float* gp;
  const float* ghp;
  const float* stp;
  if (row < 128) {
    int b = row >> 4, a = row & 15;
    gp = gABall + ((size_t)(b * NST) * An + a) * LDG;
    ghp = gh0;
    stp = state0;
  } else {
    int r = row - 128;
    int c = r & 15; r >>= 4;
    int a = r & 15; r >>= 4;
    int sm1 = r % 7, b = r / 7;
    size_t prev = (size_t)(b * NST + sm1) * An + c;
    gp = gABall + ((size_t)(b * NST + sm1 + 1) * An + a) * LDG;
    ghp = gABall + prev * LDG + GSn;
    stp = inps + prev * Dd;
  }
  float4 ir4 = *(const float4*)(gp + j);
  float4 iz4 = *(const float4*)(gp + Dd + j);
  float4 in4 = *(const float4*)(gp + 2 * Dd + j);
  float4 hr4 = *(const float4*)(ghp + j);
  float4 hz4 = *(const float4*)(ghp + Dd + j);
  float4 hn4 = *(const float4*)(ghp + 2 * Dd + j);
  float4 st4 = *(const float4*)(stp + j);
  float ir[4] = {ir4.x, ir4.y, ir4.z, ir4.w};
  float iz[4] = {iz4.x, iz4.y, iz4.z, iz4.w};
  float in_[4] = {in4.x, in4.y, in4.z, in4.w};
  float hr[4] = {hr4.x, hr4.y, hr4.z, hr4.w};
  float hz[4] = {hz4.x, hz4.y, hz4.z, hz4.w};
  float hn[4] = {hn4.x, hn4.y, hn4.z, hn4.w};
  float st[4] = {st4.x, st4.y, st4.z, st4.w};
  union { us u[4]; uint2 w; } oh, ol;
#pragma unroll
  for (int t = 0; t < 4; t++) {
    float rg = 1.f / (1.f + expf(-(ir[t] + hr[t])));
    float zg = 1.f / (1.f + expf(-(iz[t] + hz[t])));
    float ng = tanhf(in_[t] + rg * hn[t]);
    float v = (1.f - zg) * ng + zg * st[t];
    us hb = f2bf(v);
    oh.u[t] = hb;
    ol.u[t] = f2bf(v - bf2f(hb));
  }
  *(uint2*)&Hh[(size_t)row * Dd + j] = oh.w;
  *(uint2*)&Hl[(size_t)row * Dd + j] = ol.w;
}

// ---------------------------------------------------------------------------
// pick: walk the argmax chain over logit partials (NLT n-tiles).
// ---------------------------------------------------------------------------
__global__ __launch_bounds__(64) void pick_k(const float* __restrict__ Lpart,
                                             const float* __restrict__ b2v,
                                             float* __restrict__ out) {
  int b = blockIdx.x;
  int lane = threadIdx.x;
  int c = 0;
  float b2 = b2v[0];
  for (int s = 0; s < NST; s++) {
    int row;
    if (s == 0) row = b * 16 + (lane & 15);
    else row = 128 + (((b * 7 + (s - 1)) * 16 + (lane & 15)) * 16 + c);
    float v = 0.f;
#pragma unroll
    for (int t = 0; t < NLT; t++) v += Lpart[(size_t)t * Mtot + row];
    v += b2;
    if (lane < 16) out[(size_t)(b * NST + s) * An + lane] = v;
    float bv = (lane < 16) ? v : -1e30f;
    int bi = (lane < 16) ? lane : 999;
#pragma unroll
    for (int off = 1; off < 16; off <<= 1) {
      float ov = __shfl_xor(bv, off);
      int oi = __shfl_xor(bi, off);
      if (ov > bv || (ov == bv && oi < bi)) { bv = ov; bi = oi; }
    }
    c = __shfl(bi, 0);
  }
}

// ---------------------------------------------------------------------------
static inline void mm2(const us* Ah, const us* Al, int lda, const us* Bh, const us* Bl,
                       const float* bias, const float* bias2, int nsplit,
                       float* Cf, int ldc, us* Ch, us* Cl, int ldch,
                       int M, int N, int K, int relu, hipStream_t st) {
  dim3 g(N / 64, M / 64);
  mfma_nt<<<g, 256, 0, st>>>(Ah, Al, lda, Bh, Bl, bias, bias2, nsplit,
                             Cf, ldc, Ch, Cl, ldch, K, relu);
}
static inline void mm(const us* Ah, const us* Al, int lda, const us* Bh, const us* Bl,
                      const float* bias, float* Cf, int ldc, us* Ch, us* Cl, int ldch,
                      int M, int N, int K, int relu, hipStream_t st) {
  mm2(Ah, Al, lda, Bh, Bl, bias, bias, 1 << 30, Cf, ldc, Ch, Cl, ldch, M, N, K, relu, st);
}
static inline void split(const float* x, us* h, us* l, int n, hipStream_t st) {
  int n4 = n >> 2;
  int blocks = (n4 + 255) / 256;
  if (blocks > 2048) blocks = 2048;
  split_k<<<blocks, 256, 0, st>>>(x, h, l, n4);
}
static inline Sub mksub(const us* Ah, const us* Al, const us* Bh, const us* Bl,
                        const float* bias, float* Cf, us* Ch, us* Cl,
                        int lda, int ldc, int ldch, int Nt) {
  Sub s; s.Ah = Ah; s.Al = Al; s.Bh = Bh; s.Bl = Bl; s.bias = bias;
  s.Cf = Cf; s.Ch = Ch; s.Cl = Cl; s.lda = lda; s.ldc = ldc; s.ldch = ldch; s.Nt = Nt;
  return s;
}

extern "C" void kernel_launch(void* const* d_in, const int* in_sizes, int n_in,
                              void* d_out, int out_size, void* d_ws, size_t ws_size,
                              hipStream_t stream) {
  const float* video     = (const float*)d_in[0];
  const float* script    = (const float*)d_in[1];
  const float* question  = (const float*)d_in[2];
  const float* a_texts   = (const float*)d_in[3];
  const float* a_buttons = (const float*)d_in[4];
  const float* v_w1 = (const float*)d_in[5];
  const float* v_b1 = (const float*)d_in[6];
  const float* v_w2 = (const float*)d_in[7];
  const float* v_b2 = (const float*)d_in[8];
  const float* t_w1 = (const float*)d_in[9];
  const float* t_b1 = (const float*)d_in[10];
  const float* t_w2 = (const float*)d_in[11];
  const float* t_b2 = (const float*)d_in[12];
  const float* pre_w1 = (const float*)d_in[13];
  const float* pre_b1 = (const float*)d_in[14];
  const float* pre_w2 = (const float*)d_in[15];
  const float* pre_b2 = (const float*)d_in[16];
  const float* s2v_win  = (const float*)d_in[17];
  const float* s2v_bin  = (const float*)d_in[18];
  const float* s2v_wout = (const float*)d_in[19];
  const float* s2v_bout = (const float*)d_in[20];
  const float* qa_win  = (const float*)d_in[21];
  const float* qa_bin  = (const float*)d_in[22];
  const float* qa_wout = (const float*)d_in[23];
  const float* qa_bout = (const float*)d_in[24];
  const float* gru_wih = (const float*)d_in[25];
  const float* gru_whh = (const float*)d_in[26];
  const float* gru_bih = (const float*)d_in[27];
  const float* gru_bhh = (const float*)d_in[28];
  const float* proj_w1 = (const float*)d_in[29];
  const float* proj_b1 = (const float*)d_in[30];
  const float* proj_w2 = (const float*)d_in[31];
  const float* proj_b2 = (const float*)d_in[32];
  const float* state0  = (const float*)d_in[33];
  (void)in_sizes; (void)n_in; (void)out_size; (void)ws_size;

  constexpr int W589  = 768 * 768;
  constexpr int W1769 = 2304 * 768;
  constexpr int W9437 = 3072 * 3072;
  constexpr int W2359 = 768 * 3072;
  constexpr int SMe   = 1024 * 768;
  constexpr int BIGe  = 4096 * 768;
  constexpr int PADe  = 64 * 768;      // one 64-row padded tile

  char* base = (char*)d_ws;
  char* RW1 = base;                   // 9,437,184 : phase-A weights -> gABall(head)
  char* RW2 = RW1 + 9437184;          // 9,437,184 : s2v/qa/pre_w2 weights -> gABall(tail)
  char* R1  = RW2 + 9437184;          // 28,311,552
  char* R2  = R1 + 28311552;          // 12,582,912
  char* X   = R2 + 12582912;          // 25,165,824
  char* P   = X + 25165824;           // abin + pads + Hh/Hl tail overlap
  char* P2  = P + 6815744;            // persistents

  // RW1
  us* vw1h = (us*)RW1;        us* vw1l = vw1h + W589;
  us* vw2h = vw1l + W589;     us* vw2l = vw2h + W589;
  us* tw1h = vw2l + W589;     us* tw1l = tw1h + W589;
  us* tw2h = tw1l + W589;     us* tw2l = tw2h + W589;
  // RW2
  us* s2vwh = (us*)RW2;       us* s2vwl = s2vwh + W1769;
  us* s2voh = s2vwl + W1769;  us* s2vol = s2voh + W589;
  us* qawh  = (us*)RW2;       us* qawl  = qawh + W1769;
  us* qaoh  = qawl + W1769;   us* qaol  = qaoh + W589;
  us* pw2h  = (us*)RW2;       us* pw2l  = pw2h + W2359;
  float* gABall = (float*)RW1;          // [1024 x 4608] f32, spans RW1+RW2
  // R1: video path (phase A), then kvproj/qproj, then kv2/qp2/S2, then weights
  us* vidh = (us*)R1;         us* vidl = vidh + BIGe;      // R1[0..12.6MB)
  us* hidh = vidl + BIGe;     us* hidl = hidh + BIGe;      // R1[12.6..25.2MB)
  float* kvproj = (float*)R1;                              // 4096x1536 f32
  float* qproj  = kvproj + (size_t)4096 * 1536;            // R1+25.2MB, 3MB
  float* kv2 = (float*)R1;
  float* qp2 = (float*)(R1 + 6291456);
  float* S2  = (float*)(R1 + 9437184);
  us* pw1h = (us*)R1;         us* pw1l = pw1h + W9437;     // spans into R2
  us* gwALLh = (us*)R1;                                    // [4608x768]
  us* gwALLl = (us*)(R1 + 7077888);
  us* pjw1h  = (us*)(R1 + 14155776); us* pjw1l = pjw1h + W589;
  float* gh0pad = (float*)(R1 + 16515072);  // 64x2304 f32 (over dead pw1h tail)
  // R2
  us* vh = (us*)R2;           us* vl = vh + BIGe;
  us* aoh = (us*)(R2 + 3145728); us* aol = aoh + SMe;
  us* Hh = (us*)R2;           us* Hl = Hh + (size_t)Mtot * Dd;  // spans R2+X+P
  // X: phase-A script/ab temporaries (dead before S1), then S1/cat/preh
  us* inTh  = (us*)X;             us* inTl  = inTh + 2 * SMe;    // X[0..6.3MB)
  us* hid2h = (us*)(X + 6291456); us* hid2l = hid2h + 2 * SMe;   // X[6.3..12.6MB)
  us* abh1h = (us*)(X + 12582912); us* abh1l = abh1h + SMe;      // X[12.6..15.7MB)
  float* S1 = (float*)X;
  us* cath = (us*)X;          us* catl = cath + (size_t)1024 * DPn;
  us* prehh = (us*)(X + 12582912); us* prehl = prehh + (size_t)1024 * DPn;
  // P: abin [0..3.1MB); padded tiny-GEMM tiles in the [3.1..6.8MB) hole
  // (all dead before combine_all's Hl tail reaches P)
  us* abinh = (us*)P;         us* abinl = abinh + SMe;
  us* qpadh = (us*)(P + 3145728);   us* qpadl = qpadh + PADe;   // question 64x768
  us* qhidh = qpadl + PADe;         us* qhidl = qhidh + PADe;   // q-MLP hidden
  us* spadh = qhidl + PADe;         us* spadl = spadh + PADe;   // state0 64x768
  float* qff = (float*)(spadl + PADe);                          // 64x768 f32
  // P2 persistents
  us* sc2h   = (us*)P2;                       // 2048x768 split (script|a_texts)
  us* sc2l   = sc2h + 2 * SMe;
  float* scat_f = (float*)(P2 + 6291456);     // 2048x768 f32
  float* vatt   = (float*)(P2 + 12582912);
  float* inps_f = (float*)(P2 + 15728640);
  us* inpsh = (us*)(P2 + 18874368); us* inpsl = inpsh + SMe;
  float* Lpart = (float*)(P2 + 22085632);     // NLT x 14464 f32
  float* at_f  = scat_f + (size_t)1024 * Dd;  // rows 1024..2047
  us* sch = sc2h;  us* scl = sc2l;            // rows 0..1023
  // ab2 temp borrows inpsh slot (inps written only at pre2, after cat_fill)
  us* ab2h  = (us*)(P2 + 18874368); us* ab2l  = ab2h + SMe;

  // ---- phase A: weight splits + input splits ----
  split4_k<<<dim3(1024, 4), 256, 0, stream>>>(v_w1, vw1h, vw1l, W589,
                                              v_w2, vw2h, vw2l, W589,
                                              t_w1, tw1h, tw1l, W589,
                                              t_w2, tw2h, tw2l, W589);
  split4_k<<<dim3(1024, 4), 256, 0, stream>>>(script, inTh, inTl, SMe,
                                              a_texts, inTh + SMe, inTl + SMe, SMe,
                                              a_buttons, abinh, abinl, SMe,
                                              video, vidh, vidl, BIGe);
  split4_k<<<dim3(8, 2), 256, 0, stream>>>(question, qpadh, qpadl, Bn * Dd,
                                           state0, spadh, spadl, Dd,
                                           nullptr, nullptr, nullptr, 0,
                                           nullptr, nullptr, nullptr, 0);
  // B1: video-mm1 (64yt) + scat-mm1 (32yt) + ab-mm1 (16yt) + q-mm1 (1yt)
  {
    Sub sv = mksub(vidh, vidl, vw1h, vw1l, v_b1, nullptr, hidh, hidl, Dd, 0, Dd, 12);
    Sub ss = mksub(inTh, inTl, tw1h, tw1l, t_b1, nullptr, hid2h, hid2l, Dd, 0, Dd, 12);
    Sub sa = mksub(abinh, abinl, vw1h, vw1l, v_b1, nullptr, abh1h, abh1l, Dd, 0, Dd, 12);
    Sub sq = mksub(qpadh, qpadl, tw1h, tw1l, t_b1, nullptr, qhidh, qhidl, Dd, 0, Dd, 12);
    mfma_ntb<<<dim3(12, 113), 256, 0, stream>>>(sv, ss, sa, sq, 64, 96, 112, Dd, 1);
  }
  // B2: video-mm2 + scat-mm2 (+f32) + ab-mm2 + q-mm2 (f32 out)
  {
    Sub sv = mksub(hidh, hidl, vw2h, vw2l, v_b2, nullptr, vh, vl, Dd, 0, Dd, 12);
    Sub ss = mksub(hid2h, hid2l, tw2h, tw2l, t_b2, scat_f, sc2h, sc2l, Dd, Dd, Dd, 12);
    Sub sa = mksub(abh1h, abh1l, vw2h, vw2l, v_b2, nullptr, ab2h, ab2l, Dd, 0, Dd, 12);
    Sub sq = mksub(qhidh, qhidl, tw2h, tw2l, t_b2, qff, nullptr, nullptr, Dd, Dd, 0, 12);
    mfma_ntb<<<dim3(12, 113), 256, 0, stream>>>(sv, ss, sa, sq, 64, 96, 112, Dd, 0);
  }

  // ---- s2v attention (K/V merged: N=1536) ----
  split4_k<<<dim3(1024, 2), 256, 0, stream>>>(s2v_win, s2vwh, s2vwl, W1769,
                                              s2v_wout, s2voh, s2vol, W589,
                                              nullptr, nullptr, nullptr, 0,
                                              nullptr, nullptr, nullptr, 0);
  // B3: kvproj (64yt, Nt24) + qproj (16yt, Nt12)
  {
    Sub sk = mksub(vh, vl, s2vwh + (size_t)Dd * Dd, s2vwl + (size_t)Dd * Dd,
                   s2v_bin + Dd, kvproj, nullptr, nullptr, Dd, 1536, 0, 24);
    Sub sq = mksub(sch, scl, s2vwh, s2vwl, s2v_bin, qproj, nullptr, nullptr,
                   Dd, Dd, 0, 12);
    mfma_ntb<<<dim3(24, 80), 256, 0, stream>>>(sk, sq, sq, sq, 64, 80, 80, Dd, 0);
  }
  att_qk<<<dim3(Bn * NH, TSn / 32, TVn / 64), 256, 0, stream>>>(qproj, kvproj, S1,
                                                                TSn, TVn, 1, 1536, 0.125f);
  softmax_rows<<<Bn * NH * TSn, 256, 0, stream>>>(S1, TVn);
  att_pv<<<dim3(Bn * NH, TSn / 32), 256, 0, stream>>>(S1, kvproj + Dd, aoh, aol,
                                                      TSn, TVn, 1, 1536);

  // ---- phase B: cat assembly + qa attention ----
  split(qa_win, qawh, qawl, W1769, stream);          // overwrites s2vw (dead)
  cat_fill<<<(1024 * Dd + 255) / 256, 256, 0, stream>>>(qff, at_f, ab2h, ab2l,
                                                        cath, catl);
  // B4: vatt-out (16yt) + qp2 (16yt) + kv2 (16yt, Nt24)
  {
    Sub svat = mksub(aoh, aol, s2voh, s2vol, s2v_bout, vatt, nullptr, nullptr,
                     Dd, Dd, 0, 12);
    Sub sqp = mksub(cath + 2 * Dd, catl + 2 * Dd, qawh, qawl, qa_bin,
                    qp2, nullptr, nullptr, DPn, Dd, 0, 12);
    Sub skv = mksub(sch, scl, qawh + (size_t)Dd * Dd, qawl + (size_t)Dd * Dd,
                    qa_bin + Dd, kv2, nullptr, nullptr, Dd, 1536, 0, 24);
    mfma_ntb<<<dim3(24, 48), 256, 0, stream>>>(svat, sqp, skv, skv, 16, 32, 48, Dd, 0);
  }
  split(qa_wout, qaoh, qaol, W589, stream);          // overwrites s2vo (dead)
  att_qk<<<dim3(Bn * NST * NH, 1, TSn / 64), 256, 0, stream>>>(qp2, kv2, S2,
                                                               An, TSn, NST, 1536, 0.125f);
  softmax_rows<<<Bn * NST * NH * An, 256, 0, stream>>>(S2, TSn);
  att_pv<<<dim3(Bn * NST * NH, 1), 256, 0, stream>>>(S2, kv2 + Dd, aoh, aol,
                                                     An, TSn, NST, 1536);
  mm(aoh, aol, Dd, qaoh, qaol, qa_bout, nullptr, 0, cath + Dd, catl + Dd, DPn,
     1024, Dd, Dd, 0, stream);
  qv2_k<<<1024, 256, 0, stream>>>(S2, vatt, cath, catl);

  // ---- pre-MLP + merged GRU gates (gh0 rides along) ----
  split(pre_w1, pw1h, pw1l, W9437, stream);
  mm(cath, catl, DPn, pw1h, pw1l, pre_b1, nullptr, 0, prehh, prehl, DPn,
     1024, DPn, DPn, 1, stream);
  split4_k<<<dim3(1024, 4), 256, 0, stream>>>(pre_w2, pw2h, pw2l, W2359,
                                              gru_wih, gwALLh, gwALLl, W1769,
                                              gru_whh, gwALLh + W1769, gwALLl + W1769, W1769,
                                              proj_w1, pjw1h, pjw1l, W589);
  mm(prehh, prehl, DPn, pw2h, pw2l, pre_b2, inps_f, Dd, inpsh, inpsl, Dd,
     1024, Dd, DPn, 0, stream);
  // GRU gates as 3-sub batch: x-gates (16yt) + h-gates (16yt) + gh0 pad (1yt)
  {
    Sub g0 = mksub(inpsh, inpsl, gwALLh, gwALLl, gru_bih,
                   gABall, nullptr, nullptr, Dd, 4608, 0, 36);
    Sub g1 = mksub(inpsh, inpsl, gwALLh + W1769, gwALLl + W1769, gru_bhh,
                   gABall + GSn, nullptr, nullptr, Dd, 4608, 0, 36);
    Sub gh = mksub(spadh, spadl, gwALLh + W1769, gwALLl + W1769, gru_bhh,
                   gh0pad, nullptr, nullptr, Dd, GSn, 0, 36);
    mfma_ntb<<<dim3(36, 33), 256, 0, stream>>>(g0, g1, gh, gh, 16, 32, 33, Dd, 0);
  }

  // ---- candidate enumeration + logits + argmax chain ----
  combine_all<<<(Mtot * (Dd / 4) + 255) / 256, 256, 0, stream>>>(gABall, gh0pad, inps_f,
                                                                 state0, Hh, Hl);
  mfma_logit128<<<dim3(NLT, Mtot / 128), 256, 0, stream>>>(Hh, Hl, pjw1h, pjw1l,
                                                           proj_b1, proj_w2, Lpart);
  pick_k<<<Bn, 64, 0, stream>>>(Lpart, proj_b2, (float*)d_out);
}

// Round 9
// 852.349 us; speedup vs baseline: 1.3340x; 1.0222x over previous
//
#include <hip/hip_runtime.h>
#include <hip/hip_bf16.h>
#include <math.h>

constexpr int Dd  = 768;
constexpr int NH  = 12;
constexpr int DHd = 64;
constexpr int Bn  = 8;
constexpr int TVn = 512;
constexpr int TSn = 128;
constexpr int NST = 8;
constexpr int An  = 16;
constexpr int DPn = 3072;
constexpr int GSn = 2304;
constexpr int Mtot = 14464;   // 128 (s=0) + 8*7*16*16 candidate rows; 113*128
constexpr int NLT = 6;        // logit n-tiles at 128-wide tiling (768/128)

typedef unsigned short us;
using short8   = __attribute__((ext_vector_type(8))) short;
using floatx16 = __attribute__((ext_vector_type(16))) float;

typedef __attribute__((address_space(1))) const unsigned char glb_b;
typedef __attribute__((address_space(3))) unsigned char lds_b;

// async global->LDS DMA, 16B per lane, dest = lptr + lane*16 (HW-linear)
__device__ inline void gload16(const void* g, void* l) {
  __builtin_amdgcn_global_load_lds((glb_b*)g, (lds_b*)l, 16, 0, 0);
}

__device__ inline us f2bf(float x) {
  union { float f; unsigned u; } a; a.f = x;
  return (us)((a.u + 0x7fffu + ((a.u >> 16) & 1u)) >> 16);
}
__device__ inline float bf2f(us h) {
  union { unsigned u; float f; } a; a.u = ((unsigned)h) << 16;
  return a.f;
}

// ---------------------------------------------------------------------------
// splits (float4-vectorized)
// ---------------------------------------------------------------------------
__global__ void split_k(const float* __restrict__ x, us* __restrict__ h,
                        us* __restrict__ l, int n4) {
  for (int i = blockIdx.x * 256 + threadIdx.x; i < n4; i += gridDim.x * 256) {
    float4 v = ((const float4*)x)[i];
    float vv[4] = {v.x, v.y, v.z, v.w};
    union { us u[4]; uint2 w; } hh, ll;
#pragma unroll
    for (int t = 0; t < 4; t++) {
      us hb = f2bf(vv[t]);
      hh.u[t] = hb;
      ll.u[t] = f2bf(vv[t] - bf2f(hb));
    }
    ((uint2*)h)[i] = hh.w;
    ((uint2*)l)[i] = ll.w;
  }
}

__global__ void split4_k(const float* s0, us* h0, us* l0, int n0,
                         const float* s1, us* h1, us* l1, int n1,
                         const float* s2, us* h2, us* l2, int n2,
                         const float* s3, us* h3, us* l3, int n3) {
  const float* s; us* h; us* l; int n;
  switch (blockIdx.y) {
    case 0: s = s0; h = h0; l = l0; n = n0; break;
    case 1: s = s1; h = h1; l = l1; n = n1; break;
    case 2: s = s2; h = h2; l = l2; n = n2; break;
    default: s = s3; h = h3; l = l3; n = n3; break;
  }
  int n4 = n >> 2;
  for (int i = blockIdx.x * 256 + threadIdx.x; i < n4; i += gridDim.x * 256) {
    float4 v = ((const float4*)s)[i];
    float vv[4] = {v.x, v.y, v.z, v.w};
    union { us u[4]; uint2 w; } hh, ll;
#pragma unroll
    for (int t = 0; t < 4; t++) {
      us hb = f2bf(vv[t]);
      hh.u[t] = hb;
      ll.u[t] = f2bf(vv[t] - bf2f(hb));
    }
    ((uint2*)h)[i] = hh.w;
    ((uint2*)l)[i] = ll.w;
  }
}

__device__ inline short8 lds8(const us* p) {
  const uint2* q = (const uint2*)p;
  uint2 a = q[0], b = q[1];
  union { unsigned u[4]; short8 v; } t;
  t.u[0] = a.x; t.u[1] = a.y; t.u[2] = b.x; t.u[3] = b.y;
  return t.v;
}

// ---------------------------------------------------------------------------
// bf16x3 MFMA NT GEMM — 64x64 tile, 4 waves, 3 acc chains, dbuf LDS,
// 1 barrier/iter, global_load_lds staging, src-side slot swizzle.
// ---------------------------------------------------------------------------
__global__ __launch_bounds__(256) void mfma_nt(
    const us* __restrict__ Ah, const us* __restrict__ Al, int lda,
    const us* __restrict__ Bh, const us* __restrict__ Bl,
    const float* __restrict__ bias, const float* __restrict__ bias2, int nsplit,
    float* __restrict__ Cf, int ldc,
    us* __restrict__ Ch, us* __restrict__ Cl, int ldch,
    int K, int relu) {
  __shared__ us Ash[2][64][32], Asl[2][64][32], Bsh[2][64][32], Bsl[2][64][32];
  const int tid = threadIdx.x;
  const int bm = blockIdx.y * 64, bn = blockIdx.x * 64;
  const int wave = tid >> 6, lane = tid & 63;
  const int mh = (wave & 1) * 32, nh = (wave >> 1) * 32;
  const int l31 = lane & 31, hi5 = lane >> 5;
  const int srow = tid >> 2;
  const int scol = (((tid & 3) ^ ((tid >> 3) & 3)) << 3);   // swizzled src col
  const int rc2 = (l31 >> 1) & 3;                           // read swizzle key
  const int wb = wave * 16;
  const us* pAh = Ah + (size_t)(bm + srow) * lda + scol;
  const us* pAl = Al + (size_t)(bm + srow) * lda + scol;
  const us* pBh = Bh + (size_t)(bn + srow) * K + scol;
  const us* pBl = Bl + (size_t)(bn + srow) * K + scol;

  floatx16 acc_hh, acc_hl, acc_lh;
#pragma unroll
  for (int i = 0; i < 16; i++) { acc_hh[i] = 0.f; acc_hl[i] = 0.f; acc_lh[i] = 0.f; }

  const int iters = K >> 5;
  gload16(pAh, &Ash[0][wb][0]);
  gload16(pAl, &Asl[0][wb][0]);
  gload16(pBh, &Bsh[0][wb][0]);
  gload16(pBl, &Bsl[0][wb][0]);
  int p = 0;
  for (int it = 0; it < iters; ++it) {
    __syncthreads();                       // drains DMA: buf[p] resident
    if (it + 1 < iters) {
      int ko = (it + 1) * 32;
      gload16(pAh + ko, &Ash[p ^ 1][wb][0]);
      gload16(pAl + ko, &Asl[p ^ 1][wb][0]);
      gload16(pBh + ko, &Bsh[p ^ 1][wb][0]);
      gload16(pBl + ko, &Bsl[p ^ 1][wb][0]);
    }
#pragma unroll
    for (int ks = 0; ks < 32; ks += 16) {
      int col = ((((ks >> 3) + hi5) ^ rc2) << 3);
      short8 fa_h = lds8(&Ash[p][mh + l31][col]);
      short8 fa_l = lds8(&Asl[p][mh + l31][col]);
      short8 fb_h = lds8(&Bsh[p][nh + l31][col]);
      short8 fb_l = lds8(&Bsl[p][nh + l31][col]);
      acc_hh = __builtin_amdgcn_mfma_f32_32x32x16_bf16(fa_h, fb_h, acc_hh, 0, 0, 0);
      acc_hl = __builtin_amdgcn_mfma_f32_32x32x16_bf16(fa_h, fb_l, acc_hl, 0, 0, 0);
      acc_lh = __builtin_amdgcn_mfma_f32_32x32x16_bf16(fa_l, fb_h, acc_lh, 0, 0, 0);
    }
    p ^= 1;
  }
  int n = bn + nh + l31;
  float bv = (n < nsplit) ? bias[n] : bias2[n - nsplit];
#pragma unroll
  for (int r = 0; r < 16; r++) {
    int m = bm + mh + (r & 3) + 8 * (r >> 2) + 4 * hi5;
    float v = acc_hh[r] + acc_hl[r] + acc_lh[r] + bv;
    if (relu) v = fmaxf(v, 0.f);
    if (Cf) Cf[(size_t)m * ldc + n] = v;
    if (Ch) {
      us hb = f2bf(v);
      Ch[(size_t)m * ldch + n] = hb;
      Cl[(size_t)m * ldch + n] = f2bf(v - bf2f(hb));
    }
  }
}

// ---------------------------------------------------------------------------
// Batched variant: up to 4 sub-GEMMs share one launch (y-tile ranges).
// ---------------------------------------------------------------------------
struct Sub {
  const us* Ah; const us* Al; const us* Bh; const us* Bl;
  const float* bias; float* Cf; us* Ch; us* Cl;
  int lda, ldc, ldch, Nt;
};

__global__ __launch_bounds__(256) void mfma_ntb(Sub s0, Sub s1, Sub s2, Sub s3,
                                                int c1, int c2, int c3,
                                                int K, int relu) {
  Sub s; int yt = blockIdx.y;
  if (yt < c1) { s = s0; }
  else if (yt < c2) { s = s1; yt -= c1; }
  else if (yt < c3) { s = s2; yt -= c2; }
  else { s = s3; yt -= c3; }
  if ((int)blockIdx.x >= s.Nt) return;
  __shared__ us Ash[2][64][32], Asl[2][64][32], Bsh[2][64][32], Bsl[2][64][32];
  const int tid = threadIdx.x;
  const int bm = yt * 64, bn = blockIdx.x * 64;
  const int wave = tid >> 6, lane = tid & 63;
  const int mh = (wave & 1) * 32, nh = (wave >> 1) * 32;
  const int l31 = lane & 31, hi5 = lane >> 5;
  const int srow = tid >> 2;
  const int scol = (((tid & 3) ^ ((tid >> 3) & 3)) << 3);
  const int rc2 = (l31 >> 1) & 3;
  const int wb = wave * 16;
  const us* pAh = s.Ah + (size_t)(bm + srow) * s.lda + scol;
  const us* pAl = s.Al + (size_t)(bm + srow) * s.lda + scol;
  const us* pBh = s.Bh + (size_t)(bn + srow) * K + scol;
  const us* pBl = s.Bl + (size_t)(bn + srow) * K + scol;

  floatx16 acc_hh, acc_hl, acc_lh;
#pragma unroll
  for (int i = 0; i < 16; i++) { acc_hh[i] = 0.f; acc_hl[i] = 0.f; acc_lh[i] = 0.f; }

  const int iters = K >> 5;
  gload16(pAh, &Ash[0][wb][0]);
  gload16(pAl, &Asl[0][wb][0]);
  gload16(pBh, &Bsh[0][wb][0]);
  gload16(pBl, &Bsl[0][wb][0]);
  int p = 0;
  for (int it = 0; it < iters; ++it) {
    __syncthreads();
    if (it + 1 < iters) {
      int ko = (it + 1) * 32;
      gload16(pAh + ko, &Ash[p ^ 1][wb][0]);
      gload16(pAl + ko, &Asl[p ^ 1][wb][0]);
      gload16(pBh + ko, &Bsh[p ^ 1][wb][0]);
      gload16(pBl + ko, &Bsl[p ^ 1][wb][0]);
    }
#pragma unroll
    for (int ks = 0; ks < 32; ks += 16) {
      int col = ((((ks >> 3) + hi5) ^ rc2) << 3);
      short8 fa_h = lds8(&Ash[p][mh + l31][col]);
      short8 fa_l = lds8(&Asl[p][mh + l31][col]);
      short8 fb_h = lds8(&Bsh[p][nh + l31][col]);
      short8 fb_l = lds8(&Bsl[p][nh + l31][col]);
      acc_hh = __builtin_amdgcn_mfma_f32_32x32x16_bf16(fa_h, fb_h, acc_hh, 0, 0, 0);
      acc_hl = __builtin_amdgcn_mfma_f32_32x32x16_bf16(fa_h, fb_l, acc_hl, 0, 0, 0);
      acc_lh = __builtin_amdgcn_mfma_f32_32x32x16_bf16(fa_l, fb_h, acc_lh, 0, 0, 0);
    }
    p ^= 1;
  }
  int n = bn + nh + l31;
  float bv = s.bias[n];
#pragma unroll
  for (int r = 0; r < 16; r++) {
    int m = bm + mh + (r & 3) + 8 * (r >> 2) + 4 * hi5;
    float v = acc_hh[r] + acc_hl[r] + acc_lh[r] + bv;
    if (relu) v = fmaxf(v, 0.f);
    if (s.Cf) s.Cf[(size_t)m * s.ldc + n] = v;
    if (s.Ch) {
      us hb = f2bf(v);
      s.Ch[(size_t)m * s.ldch + n] = hb;
      s.Cl[(size_t)m * s.ldch + n] = f2bf(v - bf2f(hb));
    }
  }
}

// ---------------------------------------------------------------------------
// logit GEMM, 128x128 tile (678 blocks), gload_lds staging, XCD-aware
// bijective chunked swizzle. Cross chains share one accumulator.
// Epilogue: relu(acc+b1[n])*w2[n] -> Lpart[ntile][m].
// ---------------------------------------------------------------------------
__global__ __launch_bounds__(256, 2) void mfma_logit128(
    const us* __restrict__ Ah, const us* __restrict__ Al,
    const us* __restrict__ Bh, const us* __restrict__ Bl,
    const float* __restrict__ bias1, const float* __restrict__ w2,
    float* __restrict__ Lpart) {
  __shared__ us Ash[2][128][32], Asl[2][128][32], Bsh[2][128][32], Bsl[2][128][32];
  __shared__ float lpart[128];
  const int K = Dd;
  const int tid = threadIdx.x;
  const int nwg = NLT * (Mtot / 128);             // 678
  const int lin = blockIdx.y * NLT + blockIdx.x;  // hw dispatch order (x fastest)
  const int xcd = lin & 7, loc = lin >> 3;
  const int q = nwg / 8, r = nwg % 8;             // 84, 6
  const int pos = (xcd < r) ? xcd * (q + 1) + loc
                            : r * (q + 1) + (xcd - r) * q + loc;
  const int bxn = pos % NLT, bym = pos / NLT;
  const int bm = bym * 128, bn = bxn * 128;
  const int wave = tid >> 6, lane = tid & 63;
  const int mh = (wave & 1) * 64, nh = (wave >> 1) * 64;
  const int l31 = lane & 31, hi5 = lane >> 5;
  const int srow = tid >> 2;
  const int scol = (((tid & 3) ^ ((tid >> 3) & 3)) << 3);
  const int rc2 = (l31 >> 1) & 3;
  const int wb = wave * 16;
  const us* pAh = Ah + (size_t)(bm + srow) * K + scol;
  const us* pAl = Al + (size_t)(bm + srow) * K + scol;
  const us* pBh = Bh + (size_t)(bn + srow) * K + scol;
  const us* pBl = Bl + (size_t)(bn + srow) * K + scol;
  const size_t strA = (size_t)64 * K, strB = (size_t)64 * K;
  if (tid < 128) lpart[tid] = 0.f;

  floatx16 acc_hh[2][2], acc_x[2][2];
#pragma unroll
  for (int i = 0; i < 2; i++)
#pragma unroll
    for (int j = 0; j < 2; j++)
#pragma unroll
      for (int rr = 0; rr < 16; rr++) { acc_hh[i][j][rr] = 0.f; acc_x[i][j][rr] = 0.f; }

  const int iters = K >> 5;
  gload16(pAh,        &Ash[0][wb][0]);
  gload16(pAh + strA, &Ash[0][wb + 64][0]);
  gload16(pAl,        &Asl[0][wb][0]);
  gload16(pAl + strA, &Asl[0][wb + 64][0]);
  gload16(pBh,        &Bsh[0][wb][0]);
  gload16(pBh + strB, &Bsh[0][wb + 64][0]);
  gload16(pBl,        &Bsl[0][wb][0]);
  gload16(pBl + strB, &Bsl[0][wb + 64][0]);
  int p = 0;
  for (int it = 0; it < iters; ++it) {
    __syncthreads();
    if (it + 1 < iters) {
      int ko = (it + 1) * 32;
      gload16(pAh + ko,        &Ash[p ^ 1][wb][0]);
      gload16(pAh + strA + ko, &Ash[p ^ 1][wb + 64][0]);
      gload16(pAl + ko,        &Asl[p ^ 1][wb][0]);
      gload16(pAl + strA + ko, &Asl[p ^ 1][wb + 64][0]);
      gload16(pBh + ko,        &Bsh[p ^ 1][wb][0]);
      gload16(pBh + strB + ko, &Bsh[p ^ 1][wb + 64][0]);
      gload16(pBl + ko,        &Bsl[p ^ 1][wb][0]);
      gload16(pBl + strB + ko, &Bsl[p ^ 1][wb + 64][0]);
    }
#pragma unroll
    for (int ks = 0; ks < 32; ks += 16) {
      int col = ((((ks >> 3) + hi5) ^ rc2) << 3);
      short8 fah[2], fal[2], fbh[2], fbl[2];
#pragma unroll
      for (int f = 0; f < 2; f++) {
        fah[f] = lds8(&Ash[p][mh + f * 32 + l31][col]);
        fal[f] = lds8(&Asl[p][mh + f * 32 + l31][col]);
        fbh[f] = lds8(&Bsh[p][nh + f * 32 + l31][col]);
        fbl[f] = lds8(&Bsl[p][nh + f * 32 + l31][col]);
      }
#pragma unroll
      for (int fm = 0; fm < 2; fm++)
#pragma unroll
        for (int fn = 0; fn < 2; fn++) {
          acc_hh[fm][fn] = __builtin_amdgcn_mfma_f32_32x32x16_bf16(fah[fm], fbh[fn], acc_hh[fm][fn], 0, 0, 0);
          acc_x[fm][fn]  = __builtin_amdgcn_mfma_f32_32x32x16_bf16(fah[fm], fbl[fn], acc_x[fm][fn], 0, 0, 0);
          acc_x[fm][fn]  = __builtin_amdgcn_mfma_f32_32x32x16_bf16(fal[fm], fbh[fn], acc_x[fm][fn], 0, 0, 0);
        }
    }
    p ^= 1;
  }
  float b1[2], wn[2];
#pragma unroll
  for (int fn = 0; fn < 2; fn++) {
    int n = bn + nh + fn * 32 + l31;
    b1[fn] = bias1[n];
    wn[fn] = w2[n];
  }
#pragma unroll
  for (int fm = 0; fm < 2; fm++) {
#pragma unroll
    for (int rr = 0; rr < 16; rr++) {
      int mloc = mh + fm * 32 + (rr & 3) + 8 * (rr >> 2) + 4 * hi5;
      float v = 0.f;
#pragma unroll
      for (int fn = 0; fn < 2; fn++) {
        float vv = acc_hh[fm][fn][rr] + acc_x[fm][fn][rr] + b1[fn];
        v += fmaxf(vv, 0.f) * wn[fn];
      }
      v += __shfl_xor(v, 1);
      v += __shfl_xor(v, 2);
      v += __shfl_xor(v, 4);
      v += __shfl_xor(v, 8);
      v += __shfl_xor(v, 16);
      if (l31 == 0) atomicAdd(&lpart[mloc], v);
    }
  }
  __syncthreads();
  if (tid < 128) Lpart[(size_t)bxn * Mtot + bm + tid] = lpart[tid];
}

// ---------------------------------------------------------------------------
// attention QK (f32), float4-vectorized LDS
// ---------------------------------------------------------------------------
__global__ __launch_bounds__(256) void att_qk(const float* __restrict__ qp,
                                              const float* __restrict__ kp,
                                              float* __restrict__ Sout,
                                              int Tq, int Tk, int kdiv, int ldk,
                                              float scale) {
  int g = blockIdx.x;
  int h = g % NH;
  int qrow0 = (g / NH) * Tq;
  int krow0 = (g / (NH * kdiv)) * Tk;
  int q0 = blockIdx.y * 32;
  int k0 = blockIdx.z * 64;
  __shared__ float Qs[32][68];
  __shared__ float KsT[64][72];   // transposed: [d][k]
  int tid = threadIdx.x;
  {
    int row = tid >> 3, db = (tid & 7) * 8;
    int qr = q0 + row;
    float4 v0 = {0, 0, 0, 0}, v1 = {0, 0, 0, 0};
    if (qr < Tq) {
      const float* p = qp + (size_t)(qrow0 + qr) * Dd + h * DHd + db;
      v0 = *(const float4*)p;
      v1 = *(const float4*)(p + 4);
    }
    *(float4*)&Qs[row][db] = v0;
    *(float4*)&Qs[row][db + 4] = v1;
  }
#pragma unroll
  for (int half = 0; half < 2; half++) {
    int row = (tid >> 3) + half * 32, db = (tid & 7) * 8;
    int kr = k0 + row;
    float4 v0 = {0, 0, 0, 0}, v1 = {0, 0, 0, 0};
    if (kr < Tk) {
      const float* p = kp + (size_t)(krow0 + kr) * ldk + h * DHd + db;
      v0 = *(const float4*)p;
      v1 = *(const float4*)(p + 4);
    }
    KsT[db + 0][row] = v0.x; KsT[db + 1][row] = v0.y;
    KsT[db + 2][row] = v0.z; KsT[db + 3][row] = v0.w;
    KsT[db + 4][row] = v1.x; KsT[db + 5][row] = v1.y;
    KsT[db + 6][row] = v1.z; KsT[db + 7][row] = v1.w;
  }
  __syncthreads();
  int q = tid >> 3, kg = tid & 7;
  float acc[8] = {};
  for (int d = 0; d < DHd; d++) {
    float qv = Qs[q][d];
    float4 k0v = *(const float4*)&KsT[d][kg * 8];
    float4 k1v = *(const float4*)&KsT[d][kg * 8 + 4];
    acc[0] += qv * k0v.x; acc[1] += qv * k0v.y;
    acc[2] += qv * k0v.z; acc[3] += qv * k0v.w;
    acc[4] += qv * k1v.x; acc[5] += qv * k1v.y;
    acc[6] += qv * k1v.z; acc[7] += qv * k1v.w;
  }
  if (q0 + q < Tq) {
    size_t basep = ((size_t)g * Tq + q0 + q) * Tk + k0 + kg * 8;
#pragma unroll
    for (int j = 0; j < 8; j++) Sout[basep + j] = acc[j] * scale;
  }
}

// ---------------------------------------------------------------------------
// P@V with FUSED row softmax (phase 1: online max/sum per row; phase 2:
// exp-normalize on load) and fused bf16-split output. Replaces separate
// softmax_rows launches. wrnorm=1 writes normalized probs back to P (needed
// when a later kernel consumes softmaxed scores, e.g. qv2's head-mean).
// ---------------------------------------------------------------------------
__global__ __launch_bounds__(256) void att_pv_sm(float* __restrict__ P,
                                                 const float* __restrict__ vp,
                                                 us* __restrict__ Outh,
                                                 us* __restrict__ Outl,
                                                 int Tq, int Tk, int kdiv, int ldv,
                                                 int wrnorm) {
  int g = blockIdx.x;
  int h = g % NH;
  int qrow0 = (g / NH) * Tq;
  int krow0 = (g / (NH * kdiv)) * Tk;
  int q0 = blockIdx.y * 32;
  __shared__ float Ps[32][68];
  __shared__ float Vs[64][72];
  __shared__ float mrow[32], sinv[32];
  int tid = threadIdx.x;
  int q = tid >> 3, dg = tid & 7;
  // phase 1: per-row online max & sum over Tk (8 lanes per row)
  {
    int qr = q0 + q;
    float m = -1e30f, s = 0.f;
    if (qr < Tq) {
      const float* pr = P + ((size_t)g * Tq + qr) * Tk;
      for (int c = dg * 8; c < Tk; c += 64) {
        float4 v0 = *(const float4*)(pr + c);
        float4 v1 = *(const float4*)(pr + c + 4);
        float cm = fmaxf(fmaxf(fmaxf(v0.x, v0.y), fmaxf(v0.z, v0.w)),
                         fmaxf(fmaxf(v1.x, v1.y), fmaxf(v1.z, v1.w)));
        float mn = fmaxf(m, cm);
        s = s * expf(m - mn)
            + expf(v0.x - mn) + expf(v0.y - mn) + expf(v0.z - mn) + expf(v0.w - mn)
            + expf(v1.x - mn) + expf(v1.y - mn) + expf(v1.z - mn) + expf(v1.w - mn);
        m = mn;
      }
    }
#pragma unroll
    for (int off = 1; off < 8; off <<= 1) {
      float mo = __shfl_xor(m, off);
      float so = __shfl_xor(s, off);
      float mn = fmaxf(m, mo);
      s = s * expf(m - mn) + so * expf(mo - mn);
      m = mn;
    }
    if (dg == 0 && q0 + q < Tq) { mrow[q] = m; sinv[q] = 1.f / s; }
  }
  __syncthreads();
  float acc[8] = {};
  for (int k0 = 0; k0 < Tk; k0 += 64) {
    {
      int row = tid >> 3, cb = (tid & 7) * 8;
      int qr = q0 + row;
      float4 v0 = {0, 0, 0, 0}, v1 = {0, 0, 0, 0};
      if (qr < Tq) {
        float* p = P + ((size_t)g * Tq + qr) * Tk + k0 + cb;
        v0 = *(const float4*)p;
        v1 = *(const float4*)(p + 4);
        float mm = mrow[row], iv = sinv[row];
        v0.x = expf(v0.x - mm) * iv; v0.y = expf(v0.y - mm) * iv;
        v0.z = expf(v0.z - mm) * iv; v0.w = expf(v0.w - mm) * iv;
        v1.x = expf(v1.x - mm) * iv; v1.y = expf(v1.y - mm) * iv;
        v1.z = expf(v1.z - mm) * iv; v1.w = expf(v1.w - mm) * iv;
        if (wrnorm) { *(float4*)p = v0; *(float4*)(p + 4) = v1; }
      }
      *(float4*)&Ps[row][cb] = v0;
      *(float4*)&Ps[row][cb + 4] = v1;
    }
#pragma unroll
    for (int half = 0; half < 2; half++) {
      int row = (tid >> 3) + half * 32, db = (tid & 7) * 8;
      const float* p = vp + (size_t)(krow0 + k0 + row) * ldv + h * DHd + db;
      *(float4*)&Vs[row][db] = *(const float4*)p;
      *(float4*)&Vs[row][db + 4] = *(const float4*)(p + 4);
    }
    __syncthreads();
#pragma unroll 4
    for (int kk4 = 0; kk4 < 16; kk4++) {
      float4 pv = *(const float4*)&Ps[q][kk4 * 4];
      float pe[4] = {pv.x, pv.y, pv.z, pv.w};
#pragma unroll
      for (int e = 0; e < 4; e++) {
        int kk = kk4 * 4 + e;
        float4 v0 = *(const float4*)&Vs[kk][dg * 8];
        float4 v1 = *(const float4*)&Vs[kk][dg * 8 + 4];
        acc[0] += pe[e] * v0.x; acc[1] += pe[e] * v0.y;
        acc[2] += pe[e] * v0.z; acc[3] += pe[e] * v0.w;
        acc[4] += pe[e] * v1.x; acc[5] += pe[e] * v1.y;
        acc[6] += pe[e] * v1.z; acc[7] += pe[e] * v1.w;
      }
    }
    __syncthreads();
  }
  if (q0 + q < Tq) {
    size_t basep = (size_t)(qrow0 + q0 + q) * Dd + h * DHd + dg * 8;
    union { us u[8]; uint4 v; } ph, pl;
#pragma unroll
    for (int j = 0; j < 8; j++) {
      us hb = f2bf(acc[j]);
      ph.u[j] = hb;
      pl.u[j] = f2bf(acc[j] - bf2f(hb));
    }
    *(uint4*)&Outh[basep] = ph.v;
    *(uint4*)&Outl[basep] = pl.v;
  }
}

// fused head-mean + qv = W @ vatt -> cat slice [0,D)
__global__ __launch_bounds__(256) void qv2_k(const float* __restrict__ S2,
                                             const float* __restrict__ vatt,
                                             us* __restrict__ ch, us* __restrict__ cl) {
  int row = blockIdx.x;
  int b = row / (NST * An);
  int bs = row / An;
  int a = row % An;
  __shared__ float wm[TSn];
  int tid = threadIdx.x;
  if (tid < TSn) {
    float acc = 0.f;
    for (int h = 0; h < NH; h++)
      acc += S2[(((size_t)bs * NH + h) * An + a) * TSn + tid];
    wm[tid] = acc * (1.f / NH);
  }
  __syncthreads();
  for (int j = tid; j < Dd; j += 256) {
    float acc = 0.f;
    for (int k = 0; k < TSn; k++)
      acc += wm[k] * vatt[((size_t)b * TSn + k) * Dd + j];
    size_t o = (size_t)row * DPn + j;
    us hb = f2bf(acc);
    ch[o] = hb;
    cl[o] = f2bf(acc - bf2f(hb));
  }
}

// cat slices [2D,3D) = qf[b] + at[row]  and  [3D,4D) = ab2 tmp bit-copy
__global__ void cat_fill(const float* __restrict__ qf, const float* __restrict__ at,
                         const us* __restrict__ ab2h, const us* __restrict__ ab2l,
                         us* __restrict__ ch, us* __restrict__ cl) {
  int idx = blockIdx.x * 256 + threadIdx.x;
  if (idx >= Bn * NST * An * Dd) return;
  int b = idx / (NST * An * Dd);
  int row = idx / Dd;
  int j = idx - row * Dd;
  float v = qf[b * Dd + j] + at[idx];
  size_t o = (size_t)row * DPn + 2 * Dd + j;
  us hb = f2bf(v);
  ch[o] = hb;
  cl[o] = f2bf(v - bf2f(hb));
  size_t o3 = (size_t)row * DPn + 3 * Dd + j;
  ch[o3] = ab2h[idx];
  cl[o3] = ab2l[idx];
}

// ---------------------------------------------------------------------------
// GRU combine for ALL candidate rows. gABall [1024 x 4608]: cols [0,2304) =
// x-gates (wih), cols [2304,4608) = h-gates (whh). Pre-split bf16 output.
// ---------------------------------------------------------------------------
__global__ void combine_all(const float* __restrict__ gABall,
                            const float* __restrict__ gh0,
                            const float* __restrict__ inps,
                            const float* __restrict__ state0,
                            us* __restrict__ Hh, us* __restrict__ Hl) {
  const int D4 = Dd / 4;
  const int LDG = 4608;
  int idx = blockIdx.x * 256 + threadIdx.x;
  if (idx >= Mtot * D4) return;
  int row = idx / D4, j = (idx - row * D4) * 4;
  const float* gp;
  const float* ghp;
  const float* stp;
  if (row < 128) {
    int b = row >> 4, a = row & 15;
    gp = gABall + ((size_t)(b * NST) * An + a) * LDG;
    ghp = gh0;
    stp = state0;
  } else {
    int r = row - 128;
    int c = r & 15; r >>= 4;
    int a = r & 15; r >>= 4;
    int sm1 = r % 7, b = r / 7;
    size_t prev = (size_t)(b * NST + sm1) * An + c;
    gp = gABall + ((size_t)(b * NST + sm1 + 1) * An + a) * LDG;
    ghp = gABall + prev * LDG + GSn;
    stp = inps + prev * Dd;
  }
  float4 ir4 = *(const float4*)(gp + j);
  float4 iz4 = *(const float4*)(gp + Dd + j);
  float4 in4 = *(const float4*)(gp + 2 * Dd + j);
  float4 hr4 = *(const float4*)(ghp + j);
  float4 hz4 = *(const float4*)(ghp + Dd + j);
  float4 hn4 = *(const float4*)(ghp + 2 * Dd + j);
  float4 st4 = *(const float4*)(stp + j);
  float ir[4] = {ir4.x, ir4.y, ir4.z, ir4.w};
  float iz[4] = {iz4.x, iz4.y, iz4.z, iz4.w};
  float in_[4] = {in4.x, in4.y, in4.z, in4.w};
  float hr[4] = {hr4.x, hr4.y, hr4.z, hr4.w};
  float hz[4] = {hz4.x, hz4.y, hz4.z, hz4.w};
  float hn[4] = {hn4.x, hn4.y, hn4.z, hn4.w};
  float st[4] = {st4.x, st4.y, st4.z, st4.w};
  union { us u[4]; uint2 w; } oh, ol;
#pragma unroll
  for (int t = 0; t < 4; t++) {
    float rg = 1.f / (1.f + expf(-(ir[t] + hr[t])));
    float zg = 1.f / (1.f + expf(-(iz[t] + hz[t])));
    float ng = tanhf(in_[t] + rg * hn[t]);
    float v = (1.f - zg) * ng + zg * st[t];
    us hb = f2bf(v);
    oh.u[t] = hb;
    ol.u[t] = f2bf(v - bf2f(hb));
  }
  *(uint2*)&Hh[(size_t)row * Dd + j] = oh.w;
  *(uint2*)&Hl[(size_t)row * Dd + j] = ol.w;
}

// ---------------------------------------------------------------------------
// pick: walk the argmax chain over logit partials (NLT n-tiles).
// ---------------------------------------------------------------------------
__global__ __launch_bounds__(64) void pick_k(const float* __restrict__ Lpart,
                                             const float* __restrict__ b2v,
                                             float* __restrict__ out) {
  int b = blockIdx.x;
  int lane = threadIdx.x;
  int c = 0;
  float b2 = b2v[0];
  for (int s = 0; s < NST; s++) {
    int row;
    if (s == 0) row = b * 16 + (lane & 15);
    else row = 128 + (((b * 7 + (s - 1)) * 16 + (lane & 15)) * 16 + c);
    float v = 0.f;
#pragma unroll
    for (int t = 0; t < NLT; t++) v += Lpart[(size_t)t * Mtot + row];
    v += b2;
    if (lane < 16) out[(size_t)(b * NST + s) * An + lane] = v;
    float bv = (lane < 16) ? v : -1e30f;
    int bi = (lane < 16) ? lane : 999;
#pragma unroll
    for (int off = 1; off < 16; off <<= 1) {
      float ov = __shfl_xor(bv, off);
      int oi = __shfl_xor(bi, off);
      if (ov > bv || (ov == bv && oi < bi)) { bv = ov; bi = oi; }
    }
    c = __shfl(bi, 0);
  }
}

// ---------------------------------------------------------------------------
static inline void mm2(const us* Ah, const us* Al, int lda, const us* Bh, const us* Bl,
                       const float* bias, const float* bias2, int nsplit,
                       float* Cf, int ldc, us* Ch, us* Cl, int ldch,
                       int M, int N, int K, int relu, hipStream_t st) {
  dim3 g(N / 64, M / 64);
  mfma_nt<<<g, 256, 0, st>>>(Ah, Al, lda, Bh, Bl, bias, bias2, nsplit,
                             Cf, ldc, Ch, Cl, ldch, K, relu);
}
static inline void mm(const us* Ah, const us* Al, int lda, const us* Bh, const us* Bl,
                      const float* bias, float* Cf, int ldc, us* Ch, us* Cl, int ldch,
                      int M, int N, int K, int relu, hipStream_t st) {
  mm2(Ah, Al, lda, Bh, Bl, bias, bias, 1 << 30, Cf, ldc, Ch, Cl, ldch, M, N, K, relu, st);
}
static inline void split(const float* x, us* h, us* l, int n, hipStream_t st) {
  int n4 = n >> 2;
  int blocks = (n4 + 255) / 256;
  if (blocks > 2048) blocks = 2048;
  split_k<<<blocks, 256, 0, st>>>(x, h, l, n4);
}
static inline Sub mksub(const us* Ah, const us* Al, const us* Bh, const us* Bl,
                        const float* bias, float* Cf, us* Ch, us* Cl,
                        int lda, int ldc, int ldch, int Nt) {
  Sub s; s.Ah = Ah; s.Al = Al; s.Bh = Bh; s.Bl = Bl; s.bias = bias;
  s.Cf = Cf; s.Ch = Ch; s.Cl = Cl; s.lda = lda; s.ldc = ldc; s.ldch = ldch; s.Nt = Nt;
  return s;
}

extern "C" void kernel_launch(void* const* d_in, const int* in_sizes, int n_in,
                              void* d_out, int out_size, void* d_ws, size_t ws_size,
                              hipStream_t stream) {
  const float* video     = (const float*)d_in[0];
  const float* script    = (const float*)d_in[1];
  const float* question  = (const float*)d_in[2];
  const float* a_texts   = (const float*)d_in[3];
  const float* a_buttons = (const float*)d_in[4];
  const float* v_w1 = (const float*)d_in[5];
  const float* v_b1 = (const float*)d_in[6];
  const float* v_w2 = (const float*)d_in[7];
  const float* v_b2 = (const float*)d_in[8];
  const float* t_w1 = (const float*)d_in[9];
  const float* t_b1 = (const float*)d_in[10];
  const float* t_w2 = (const float*)d_in[11];
  const float* t_b2 = (const float*)d_in[12];
  const float* pre_w1 = (const float*)d_in[13];
  const float* pre_b1 = (const float*)d_in[14];
  const float* pre_w2 = (const float*)d_in[15];
  const float* pre_b2 = (const float*)d_in[16];
  const float* s2v_win  = (const float*)d_in[17];
  const float* s2v_bin  = (const float*)d_in[18];
  const float* s2v_wout = (const float*)d_in[19];
  const float* s2v_bout = (const float*)d_in[20];
  const float* qa_win  = (const float*)d_in[21];
  const float* qa_bin  = (const float*)d_in[22];
  const float* qa_wout = (const float*)d_in[23];
  const float* qa_bout = (const float*)d_in[24];
  const float* gru_wih = (const float*)d_in[25];
  const float* gru_whh = (const float*)d_in[26];
  const float* gru_bih = (const float*)d_in[27];
  const float* gru_bhh = (const float*)d_in[28];
  const float* proj_w1 = (const float*)d_in[29];
  const float* proj_b1 = (const float*)d_in[30];
  const float* proj_w2 = (const float*)d_in[31];
  const float* proj_b2 = (const float*)d_in[32];
  const float* state0  = (const float*)d_in[33];
  (void)in_sizes; (void)n_in; (void)out_size; (void)ws_size;

  constexpr int W589  = 768 * 768;
  constexpr int W1769 = 2304 * 768;
  constexpr int W9437 = 3072 * 3072;
  constexpr int W2359 = 768 * 3072;
  constexpr int SMe   = 1024 * 768;
  constexpr int BIGe  = 4096 * 768;
  constexpr int PADe  = 64 * 768;      // one 64-row padded tile

  char* base = (char*)d_ws;
  char* RW1 = base;                   // 9,437,184 : phase-A weights -> gABall(head)
  char* RW2 = RW1 + 9437184;          // 9,437,184 : s2v/qa/pre_w2 weights -> gABall(tail)
  char* R1  = RW2 + 9437184;          // 28,311,552
  char* R2  = R1 + 28311552;          // 12,582,912
  char* X   = R2 + 12582912;          // 25,165,824
  char* P   = X + 25165824;           // abin + pads + qao + Hh/Hl tail overlap
  char* P2  = P + 6815744;            // persistents

  // RW1
  us* vw1h = (us*)RW1;        us* vw1l = vw1h + W589;
  us* vw2h = vw1l + W589;     us* vw2l = vw2h + W589;
  us* tw1h = vw2l + W589;     us* tw1l = tw1h + W589;
  us* tw2h = tw1l + W589;     us* tw2l = tw2h + W589;
  // RW2
  us* s2vwh = (us*)RW2;       us* s2vwl = s2vwh + W1769;
  us* s2voh = s2vwl + W1769;  us* s2vol = s2voh + W589;
  us* qawh  = (us*)RW2;       us* qawl  = qawh + W1769;
  us* pw2h  = (us*)RW2;       us* pw2l  = pw2h + W2359;
  float* gABall = (float*)RW1;          // [1024 x 4608] f32, spans RW1+RW2
  // R1: video path (phase A), then kvproj/qproj, then kv2/qp2/S2, then weights
  us* vidh = (us*)R1;         us* vidl = vidh + BIGe;      // R1[0..12.6MB)
  us* hidh = vidl + BIGe;     us* hidl = hidh + BIGe;      // R1[12.6..25.2MB)
  float* kvproj = (float*)R1;                              // 4096x1536 f32
  float* qproj  = kvproj + (size_t)4096 * 1536;            // R1+25.2MB, 3MB
  float* kv2 = (float*)R1;
  float* qp2 = (float*)(R1 + 6291456);
  float* S2  = (float*)(R1 + 9437184);
  us* pw1h = (us*)R1;         us* pw1l = pw1h + W9437;     // spans into R2
  us* gwALLh = (us*)R1;                                    // [4608x768]
  us* gwALLl = (us*)(R1 + 7077888);
  us* pjw1h  = (us*)(R1 + 14155776); us* pjw1l = pjw1h + W589;
  float* gh0pad = (float*)(R1 + 16515072);  // 64x2304 f32 (over dead pw1h tail)
  // R2
  us* vh = (us*)R2;           us* vl = vh + BIGe;
  us* aoh = (us*)(R2 + 3145728); us* aol = aoh + SMe;
  us* Hh = (us*)R2;           us* Hl = Hh + (size_t)Mtot * Dd;  // spans R2+X+P
  // X: phase-A script/ab temporaries (dead before S1), then S1/cat/preh
  us* inTh  = (us*)X;             us* inTl  = inTh + 2 * SMe;    // X[0..6.3MB)
  us* hid2h = (us*)(X + 6291456); us* hid2l = hid2h + 2 * SMe;   // X[6.3..12.6MB)
  us* abh1h = (us*)(X + 12582912); us* abh1l = abh1h + SMe;      // X[12.6..15.7MB)
  float* S1 = (float*)X;
  us* cath = (us*)X;          us* catl = cath + (size_t)1024 * DPn;
  us* prehh = (us*)(X + 12582912); us* prehl = prehh + (size_t)1024 * DPn;
  // P: abin [0..3.1MB); pads + qff + qao in the [3.1..6.3MB) hole
  // (all dead before combine_all's Hl tail reaches P)
  us* abinh = (us*)P;         us* abinl = abinh + SMe;
  us* qpadh = (us*)(P + 3145728);   us* qpadl = qpadh + PADe;   // question 64x768
  us* qhidh = qpadl + PADe;         us* qhidl = qhidh + PADe;   // q-MLP hidden
  us* spadh = qhidl + PADe;         us* spadl = spadh + PADe;   // state0 64x768
  float* qff = (float*)(spadl + PADe);                          // 64x768 f32
  us* qaoh = (us*)(P + 3932160);    us* qaol = qaoh + W589;     // qa_wout split
  // P2 persistents
  us* sc2h   = (us*)P2;                       // 2048x768 split (script|a_texts)
  us* sc2l   = sc2h + 2 * SMe;
  float* scat_f = (float*)(P2 + 6291456);     // 2048x768 f32
  float* vatt   = (float*)(P2 + 12582912);
  float* inps_f = (float*)(P2 + 15728640);
  us* inpsh = (us*)(P2 + 18874368); us* inpsl = inpsh + SMe;
  float* Lpart = (float*)(P2 + 22085632);     // NLT x 14464 f32
  float* at_f  = scat_f + (size_t)1024 * Dd;  // rows 1024..2047
  us* sch = sc2h;  us* scl = sc2l;            // rows 0..1023
  // ab2 temp borrows inpsh slot (inps written only at pre2, after cat_fill)
  us* ab2h  = (us*)(P2 + 18874368); us* ab2l  = ab2h + SMe;

  // ---- phase A: weight splits + input splits ----
  split4_k<<<dim3(1024, 4), 256, 0, stream>>>(v_w1, vw1h, vw1l, W589,
                                              v_w2, vw2h, vw2l, W589,
                                              t_w1, tw1h, tw1l, W589,
                                              t_w2, tw2h, tw2l, W589);
  split4_k<<<dim3(1024, 4), 256, 0, stream>>>(script, inTh, inTl, SMe,
                                              a_texts, inTh + SMe, inTl + SMe, SMe,
                                              a_buttons, abinh, abinl, SMe,
                                              video, vidh, vidl, BIGe);
  split4_k<<<dim3(8, 2), 256, 0, stream>>>(question, qpadh, qpadl, Bn * Dd,
                                           state0, spadh, spadl, Dd,
                                           nullptr, nullptr, nullptr, 0,
                                           nullptr, nullptr, nullptr, 0);
  // B1: video-mm1 (64yt) + scat-mm1 (32yt) + ab-mm1 (16yt) + q-mm1 (1yt)
  {
    Sub sv = mksub(vidh, vidl, vw1h, vw1l, v_b1, nullptr, hidh, hidl, Dd, 0, Dd, 12);
    Sub ss = mksub(inTh, inTl, tw1h, tw1l, t_b1, nullptr, hid2h, hid2l, Dd, 0, Dd, 12);
    Sub sa = mksub(abinh, abinl, vw1h, vw1l, v_b1, nullptr, abh1h, abh1l, Dd, 0, Dd, 12);
    Sub sq = mksub(qpadh, qpadl, tw1h, tw1l, t_b1, nullptr, qhidh, qhidl, Dd, 0, Dd, 12);
    mfma_ntb<<<dim3(12, 113), 256, 0, stream>>>(sv, ss, sa, sq, 64, 96, 112, Dd, 1);
  }
  // B2: video-mm2 + scat-mm2 (+f32) + ab-mm2 + q-mm2 (f32 out)
  {
    Sub sv = mksub(hidh, hidl, vw2h, vw2l, v_b2, nullptr, vh, vl, Dd, 0, Dd, 12);
    Sub ss = mksub(hid2h, hid2l, tw2h, tw2l, t_b2, scat_f, sc2h, sc2l, Dd, Dd, Dd, 12);
    Sub sa = mksub(abh1h, abh1l, vw2h, vw2l, v_b2, nullptr, ab2h, ab2l, Dd, 0, Dd, 12);
    Sub sq = mksub(qhidh, qhidl, tw2h, tw2l, t_b2, qff, nullptr, nullptr, Dd, Dd, 0, 12);
    mfma_ntb<<<dim3(12, 113), 256, 0, stream>>>(sv, ss, sa, sq, 64, 96, 112, Dd, 0);
  }

  // ---- s2v attention (K/V merged: N=1536) ----
  split4_k<<<dim3(1024, 2), 256, 0, stream>>>(s2v_win, s2vwh, s2vwl, W1769,
                                              s2v_wout, s2voh, s2vol, W589,
                                              nullptr, nullptr, nullptr, 0,
                                              nullptr, nullptr, nullptr, 0);
  // B3: kvproj (64yt, Nt24) + qproj (16yt, Nt12)
  {
    Sub sk = mksub(vh, vl, s2vwh + (size_t)Dd * Dd, s2vwl + (size_t)Dd * Dd,
                   s2v_bin + Dd, kvproj, nullptr, nullptr, Dd, 1536, 0, 24);
    Sub sq = mksub(sch, scl, s2vwh, s2vwl, s2v_bin, qproj, nullptr, nullptr,
                   Dd, Dd, 0, 12);
    mfma_ntb<<<dim3(24, 80), 256, 0, stream>>>(sk, sq, sq, sq, 64, 80, 80, Dd, 0);
  }
  att_qk<<<dim3(Bn * NH, TSn / 32, TVn / 64), 256, 0, stream>>>(qproj, kvproj, S1,
                                                                TSn, TVn, 1, 1536, 0.125f);
  att_pv_sm<<<dim3(Bn * NH, TSn / 32), 256, 0, stream>>>(S1, kvproj + Dd, aoh, aol,
                                                         TSn, TVn, 1, 1536, 0);

  // ---- phase B: cat assembly + qa attention ----
  split4_k<<<dim3(1024, 2), 256, 0, stream>>>(qa_win, qawh, qawl, W1769,
                                              qa_wout, qaoh, qaol, W589,
                                              nullptr, nullptr, nullptr, 0,
                                              nullptr, nullptr, nullptr, 0);
  cat_fill<<<(1024 * Dd + 255) / 256, 256, 0, stream>>>(qff, at_f, ab2h, ab2l,
                                                        cath, catl);
  // B4: vatt-out (16yt) + qp2 (16yt) + kv2 (16yt, Nt24)
  {
    Sub svat = mksub(aoh, aol, s2voh, s2vol, s2v_bout, vatt, nullptr, nullptr,
                     Dd, Dd, 0, 12);
    Sub sqp = mksub(cath + 2 * Dd, catl + 2 * Dd, qawh, qawl, qa_bin,
                    qp2, nullptr, nullptr, DPn, Dd, 0, 12);
    Sub skv = mksub(sch, scl, qawh + (size_t)Dd * Dd, qawl + (size_t)Dd * Dd,
                    qa_bin + Dd, kv2, nullptr, nullptr, Dd, 1536, 0, 24);
    mfma_ntb<<<dim3(24, 48), 256, 0, stream>>>(svat, sqp, skv, skv, 16, 32, 48, Dd, 0);
  }
  att_qk<<<dim3(Bn * NST * NH, 1, TSn / 64), 256, 0, stream>>>(qp2, kv2, S2,
                                                               An, TSn, NST, 1536, 0.125f);
  att_pv_sm<<<dim3(Bn * NST * NH, 1), 256, 0, stream>>>(S2, kv2 + Dd, aoh, aol,
                                                        An, TSn, NST, 1536, 1);
  mm(aoh, aol, Dd, qaoh, qaol, qa_bout, nullptr, 0, cath + Dd, catl + Dd, DPn,
     1024, Dd, Dd, 0, stream);
  qv2_k<<<1024, 256, 0, stream>>>(S2, vatt, cath, catl);

  // ---- pre-MLP + merged GRU gates (gh0 rides along) ----
  split(pre_w1, pw1h, pw1l, W9437, stream);
  mm(cath, catl, DPn, pw1h, pw1l, pre_b1, nullptr, 0, prehh, prehl, DPn,
     1024, DPn, DPn, 1, stream);
  split4_k<<<dim3(1024, 4), 256, 0, stream>>>(pre_w2, pw2h, pw2l, W2359,
                                              gru_wih, gwALLh, gwALLl, W1769,
                                              gru_whh, gwALLh + W1769, gwALLl + W1769, W1769,
                                              proj_w1, pjw1h, pjw1l, W589);
  mm(prehh, prehl, DPn, pw2h, pw2l, pre_b2, inps_f, Dd, inpsh, inpsl, Dd,
     1024, Dd, DPn, 0, stream);
  // GRU gates as 3-sub batch: x-gates (16yt) + h-gates (16yt) + gh0 pad (1yt)
  {
    Sub g0 = mksub(inpsh, inpsl, gwALLh, gwALLl, gru_bih,
                   gABall, nullptr, nullptr, Dd, 4608, 0, 36);
    Sub g1 = mksub(inpsh, inpsl, gwALLh + W1769, gwALLl + W1769, gru_bhh,
                   gABall + GSn, nullptr, nullptr, Dd, 4608, 0, 36);
    Sub gh = mksub(spadh, spadl, gwALLh + W1769, gwALLl + W1769, gru_bhh,
                   gh0pad, nullptr, nullptr, Dd, GSn, 0, 36);
    mfma_ntb<<<dim3(36, 33), 256, 0, stream>>>(g0, g1, gh, gh, 16, 32, 33, Dd, 0);
  }

  // ---- candidate enumeration + logits + argmax chain ----
  combine_all<<<(Mtot * (Dd / 4) + 255) / 256, 256, 0, stream>>>(gABall, gh0pad, inps_f,
                                                                 state0, Hh, Hl);
  mfma_logit128<<<dim3(NLT, Mtot / 128), 256, 0, stream>>>(Hh, Hl, pjw1h, pjw1l,
                                                           proj_b1, proj_w2, Lpart);
  pick_k<<<Bn, 64, 0, stream>>>(Lpart, proj_b2, (float*)d_out);
}